// Round 9
// baseline (10705.503 us; speedup 1.0000x reference)
//
#include <hip/hip_runtime.h>
#include <math.h>

#define NB  8
#define NPX 16384   // 128*128
#define PPX 1024    // 32*32

// f32 LAPACK machine constants (SLAMCH) used for branch tolerances
#define EPS32   5.9604644775390625e-8   // 2^-24 (slamch 'E')
#define EPS232  (EPS32*EPS32)
#define SAFMIN32 1.1754943508222875e-38

// ---------------- workspace layout (bytes), phase-aliased ----------------
static constexpr size_t OFF_VT   = 0;                    // f32 [8][256][256] 2MB (lives across phases)
static constexpr size_t U        = 0x200000;
static constexpr size_t OFF_GRAM = U;                    // f64 [8][256][256] 4MB
static constexpr size_t OFF_A    = U + 0x400000;         // f64 [8][256][256] 4MB reflectors
static constexpr size_t OFF_QT   = U + 0x800000;         // f64 [8][256][256] 4MB QT[col][row] (tridiag eigvecs, transposed)
static constexpr size_t OFF_SG   = U + 0xC00000;         // f64 [8][256][256] 4MB S scratch
static constexpr size_t OFF_QN   = U + 0x1000000;        // f64 [8][256][256] 4MB QNT scratch
static constexpr size_t OFF_D    = U + 0x1400000;        // f64 [8][256]
static constexpr size_t OFF_E    = U + 0x1404000;        // f64 [8][256]
static constexpr size_t OFF_TAU  = U + 0x1408000;        // f64 [8][256]
static constexpr size_t OFF_DW   = U + 0x140C000;        // f64 [8][256] working eigenvalues
static constexpr size_t OFF_META = U + 0x1410000;        // int [8][8][520]  K,K2,indxp[256],permf[256]
// phase2 aliases (phase1 dead in order: GRAM after tridiag, A/QT after backxf, SG/QN/META after merges):
static constexpr size_t OFF_XP   = U;                    // f32 [8][256][1024] 8MB
static constexpr size_t OFF_QKV  = U + 0x800000;         // f32 [8][672][1024] 21MB
static constexpr size_t OFF_POOL = U + 0x1D00000;        // f32 [8][224][1024] 7MB
static constexpr size_t OFF_OWT  = U + 0x2400000;        // f32 [224][256]

// ================= gram = X X^T (f64 accumulate) =================
__global__ __launch_bounds__(256) void k_gram(const float* __restrict__ x, double* __restrict__ gram) {
  int jt = blockIdx.x, it = blockIdx.y, b = blockIdx.z;
  __shared__ float xi[32][129], xj[32][129];
  const float* xb = x + (size_t)b*256*NPX;
  int t = threadIdx.x;
  int ci = t & 31, cjg = t >> 5;
  double acc[4] = {0.0,0.0,0.0,0.0};
  for (int n0 = 0; n0 < NPX; n0 += 128) {
    for (int q = 0; q < 16; ++q) {
      int idx = t + q*256;
      int r = idx >> 7, cc = idx & 127;
      xi[r][cc] = xb[(size_t)(it*32 + r)*NPX + n0 + cc];
      xj[r][cc] = xb[(size_t)(jt*32 + r)*NPX + n0 + cc];
    }
    __syncthreads();
    for (int p = 0; p < 128; ++p) {
      double a = (double)xi[ci][p];
      #pragma unroll
      for (int k = 0; k < 4; ++k) acc[k] += a * (double)xj[cjg + 8*k][p];
    }
    __syncthreads();
  }
  #pragma unroll
  for (int k = 0; k < 4; ++k)
    gram[((size_t)b*256 + it*32 + ci)*256 + jt*32 + cjg + 8*k] = acc[k];
}

__device__ __forceinline__ double blkSum16(double v, double* tmp, int t, int nw) {
  #pragma unroll
  for (int m = 1; m <= 32; m <<= 1) v += __shfl_xor(v, m);
  __syncthreads();
  if ((t & 63) == 0) tmp[t >> 6] = v;
  __syncthreads();
  double s = 0.0;
  for (int w = 0; w < nw; ++w) s += tmp[w];
  return s;
}

// ================= Householder tridiagonalization (dsytd2 'L', f64, 1024 threads) =================
// Rows >= TCUT live in LDS for the whole factorization (traffic cut ~48%); reflectors are
// written through to global A for the back-transform. rowNext captures the next pivot row
// during the rank-2 update, removing one global round-trip per step. Bit-identical math.
#define TCUT 184
__global__ __launch_bounds__(1024) void k_tridiag(const double* __restrict__ gram, double* __restrict__ A,
        double* __restrict__ d_g, double* __restrict__ e_g, double* __restrict__ tau_g) {
  int b = blockIdx.x, t = threadIdx.x;
  int g = t >> 8, c = t & 255;
  const double* gb = gram + (size_t)b*65536;
  double* Ab = A + (size_t)b*65536;
  __shared__ double Atail[(256 - TCUT)*256];   // 72 rows = 147456 B
  __shared__ double vL[256], wL[256], rowNext[256];
  __shared__ double wpart[4][256];
  __shared__ double tmp[16];
  for (int q = g; q < 256; q += 4) {
    double v = gb[q*256 + c];
    if (q < TCUT) Ab[q*256 + c] = v;
    else          Atail[(q - TCUT)*256 + c] = v;
  }
  if (g == 0) rowNext[c] = gb[c];   // row 0
  __syncthreads();
  for (int i = 0; i < 255; ++i) {
    // norm of row i cols i+2.. (from rowNext), alpha = col i+1; d[i] = col i
    double part = 0.0;
    int rx = i + 2 + t;
    if (rx < 256) { double v = rowNext[rx]; part = v*v; }
    double xn2 = blkSum16(part, tmp, t, 16);
    double alpha = rowNext[i + 1];
    double beta, tauv, scale;
    if (xn2 == 0.0) { beta = alpha; tauv = 0.0; scale = 0.0; }
    else {
      beta  = -copysign(sqrt(alpha*alpha + xn2), alpha);   // dlarfg
      tauv  = (beta - alpha)/beta;
      scale = 1.0/(alpha - beta);
    }
    if (t == 0) {
      e_g[b*256 + i] = beta; tau_g[b*256 + i] = tauv; vL[i+1] = 1.0;
      d_g[b*256 + i] = rowNext[i];
    }
    if (rx < 256) {
      double v = rowNext[rx] * scale;
      vL[rx] = v;
      Ab[i*256 + rx] = v;                 // reflector write-through (backxf reads global A)
    }
    __syncthreads();
    if (tauv != 0.0) {                    // uniform branch
      int cc = i + 1 + c;
      double w = 0.0;
      if (cc < 256) {
        for (int r = i + 1 + g; r < 256; r += 4) {
          double av = (r >= TCUT) ? Atail[(r - TCUT)*256 + cc] : Ab[r*256 + cc];
          w += av * vL[r];
        }
      }
      wpart[g][c] = w;
      __syncthreads();
      double wfull = 0.0, part2 = 0.0;
      if (g == 0 && cc < 256) {
        wfull = (wpart[0][c] + wpart[1][c] + wpart[2][c] + wpart[3][c]) * tauv;
        part2 = vL[cc] * wfull;
      }
      double dot = blkSum16(part2, tmp, t, 16);
      double coef = -0.5*tauv*dot;
      if (g == 0 && cc < 256) wL[cc] = wfull + coef*vL[cc];
      __syncthreads();
      if (cc < 256) {
        double vc = vL[cc], wc = wL[cc];
        for (int r = i + 1 + g; r < 256; r += 4) {
          double av = (r >= TCUT) ? Atail[(r - TCUT)*256 + cc] : Ab[r*256 + cc];
          double nv = av - vL[r]*wc - wL[r]*vc;
          if (r >= TCUT) Atail[(r - TCUT)*256 + cc] = nv; else Ab[r*256 + cc] = nv;
          if (r == i + 1) rowNext[cc] = nv;   // only g==0, k==0 lands here
        }
      }
      __syncthreads();
    } else {
      // no update this step: refresh rowNext from the (unchanged) row i+1
      if (g == 0) rowNext[c] = (i + 1 >= TCUT) ? Atail[(i + 1 - TCUT)*256 + c] : Ab[(i + 1)*256 + c];
      __syncthreads();
    }
  }
  if (t == 0) {
    d_g[b*256 + 255] = Atail[(255 - TCUT)*256 + 255];
    e_g[b*256 + 255] = 0.0;
  }
}

// ================= LAPACK helpers =================
__device__ __forceinline__ void dlartg_(double f, double g, double& c, double& s, double& r) {
  if (g == 0.0) { c = 1.0; s = 0.0; r = f; }
  else if (f == 0.0) { c = 0.0; s = (g > 0.0) ? 1.0 : -1.0; r = fabs(g); }
  else {
    double d = sqrt(f*f + g*g);
    r = (f >= 0.0) ? d : -d;
    c = f / r;
    s = g / r;
  }
}

__device__ void dlaev2_(double a, double b, double cc, double& rt1, double& rt2, double& cs1, double& sn1) {
  double sm = a + cc, df = a - cc;
  double adf = fabs(df), tb = b + b, ab = fabs(tb);
  double acmx, acmn;
  if (fabs(a) > fabs(cc)) { acmx = a; acmn = cc; } else { acmx = cc; acmn = a; }
  double rt;
  if (adf > ab)      rt = adf*sqrt(1.0 + (ab/adf)*(ab/adf));
  else if (adf < ab) rt = ab*sqrt(1.0 + (adf/ab)*(adf/ab));
  else               rt = ab*sqrt(2.0);
  int sgn1;
  if (sm < 0.0)      { rt1 = 0.5*(sm - rt); sgn1 = -1; rt2 = (acmx/rt1)*acmn - (b/rt1)*b; }
  else if (sm > 0.0) { rt1 = 0.5*(sm + rt); sgn1 = 1;  rt2 = (acmx/rt1)*acmn - (b/rt1)*b; }
  else               { rt1 = 0.5*rt; rt2 = -0.5*rt; sgn1 = 1; }
  double cs; int sgn2;
  if (df >= 0.0) { cs = df + rt; sgn2 = 1; } else { cs = df - rt; sgn2 = -1; }
  double acs = fabs(cs);
  if (acs > ab) {
    double ct = -tb/cs;
    sn1 = 1.0/sqrt(1.0 + ct*ct);
    cs1 = ct*sn1;
  } else {
    if (ab == 0.0) { cs1 = 1.0; sn1 = 0.0; }
    else {
      double tn = -cs/tb;
      cs1 = 1.0/sqrt(1.0 + tn*tn);
      sn1 = tn*cs1;
    }
  }
  if (sgn1 == sgn2) { double tn = cs1; cs1 = -sn1; sn1 = tn; }
}

// faithful dsteqr('I') on an n<=16 block, f64 arithmetic with f32 tolerances
__device__ void steqr_leaf(int n, double* d, double* e, double* q, int ldq) {
  const double eps = EPS32, eps2 = EPS232, safmin = SAFMIN32;
  int nmaxit = n*30, jtot = 0;
  int l1 = 0;
  while (l1 < n) {
    if (l1 > 0) e[l1-1] = 0.0;
    int m;
    for (m = l1; m < n-1; ++m) {
      double tst = fabs(e[m]);
      if (tst == 0.0) break;
      if (tst <= (sqrt(fabs(d[m]))*sqrt(fabs(d[m+1])))*eps) { e[m] = 0.0; break; }
    }
    int l = l1, lend = m;
    l1 = m + 1;
    if (lend == l) continue;
    if (fabs(d[lend]) < fabs(d[l])) { int tsw = l; l = lend; lend = tsw; }
    if (lend > l) {
      while (true) {
        int mm;
        for (mm = l; mm < lend; ++mm) {
          double tst = e[mm]*e[mm];
          if (tst <= (eps2*fabs(d[mm]))*fabs(d[mm+1]) + safmin) break;
        }
        if (mm < lend) e[mm] = 0.0;
        double p = d[l];
        if (mm == l) { l = l + 1; if (l > lend) break; continue; }
        if (mm == l+1) {
          double rt1, rt2, c, s;
          dlaev2_(d[l], e[l], d[l+1], rt1, rt2, c, s);
          for (int i = 0; i < n; ++i) {
            double t1 = q[i*ldq + l+1], t0 = q[i*ldq + l];
            q[i*ldq + l+1] = c*t1 - s*t0;
            q[i*ldq + l]   = s*t1 + c*t0;
          }
          d[l] = rt1; d[l+1] = rt2; e[l] = 0.0;
          l += 2; if (l > lend) break; continue;
        }
        if (jtot == nmaxit) break;
        jtot++;
        double g = (d[l+1] - p)/(2.0*e[l]);
        double r = sqrt(g*g + 1.0);
        g = d[mm] - p + e[l]/(g + copysign(r, g));
        double s = 1.0, c = 1.0; p = 0.0;
        double csv[16], snv[16];
        for (int i = mm-1; i >= l; --i) {
          double f = s*e[i], bb = c*e[i];
          dlartg_(g, f, c, s, r);
          if (i != mm-1) e[i+1] = r;
          g = d[i+1] - p;
          r = (d[i] - g)*s + 2.0*c*bb;
          p = s*r;
          d[i+1] = g + p;
          g = c*r - bb;
          csv[i] = c; snv[i] = -s;
        }
        for (int i = mm-1; i >= l; --i) {
          double cc2 = csv[i], ss2 = snv[i];
          for (int k = 0; k < n; ++k) {
            double t1 = q[k*ldq + i+1], t0 = q[k*ldq + i];
            q[k*ldq + i+1] = cc2*t1 - ss2*t0;
            q[k*ldq + i]   = ss2*t1 + cc2*t0;
          }
        }
        d[l] -= p; e[l] = g;
      }
    } else {
      while (true) {
        int mm;
        for (mm = l; mm > lend; --mm) {
          double tst = e[mm-1]*e[mm-1];
          if (tst <= (eps2*fabs(d[mm]))*fabs(d[mm-1]) + safmin) break;
        }
        if (mm > lend) e[mm-1] = 0.0;
        double p = d[l];
        if (mm == l) { l = l - 1; if (l < lend) break; continue; }
        if (mm == l-1) {
          double rt1, rt2, c, s;
          dlaev2_(d[l-1], e[l-1], d[l], rt1, rt2, c, s);
          for (int i = 0; i < n; ++i) {
            double t1 = q[i*ldq + l], t0 = q[i*ldq + l-1];
            q[i*ldq + l]   = c*t1 - s*t0;
            q[i*ldq + l-1] = s*t1 + c*t0;
          }
          d[l-1] = rt1; d[l] = rt2; e[l-1] = 0.0;
          l -= 2; if (l < lend) break; continue;
        }
        if (jtot == nmaxit) break;
        jtot++;
        double g = (d[l-1] - p)/(2.0*e[l-1]);
        double r = sqrt(g*g + 1.0);
        g = d[mm] - p + e[l-1]/(g + copysign(r, g));
        double s = 1.0, c = 1.0; p = 0.0;
        double csv[16], snv[16];
        for (int i = mm; i <= l-1; ++i) {
          double f = s*e[i], bb = c*e[i];
          dlartg_(g, f, c, s, r);
          if (i != mm) e[i-1] = r;
          g = d[i] - p;
          r = (d[i+1] - g)*s + 2.0*c*bb;
          p = s*r;
          d[i] = g + p;
          g = c*r - bb;
          csv[i] = c; snv[i] = s;
        }
        for (int i = mm; i <= l-1; ++i) {
          double cc2 = csv[i], ss2 = snv[i];
          for (int k = 0; k < n; ++k) {
            double t1 = q[k*ldq + i+1], t0 = q[k*ldq + i];
            q[k*ldq + i+1] = cc2*t1 - ss2*t0;
            q[k*ldq + i]   = ss2*t1 + cc2*t0;
          }
        }
        d[l] -= p; e[l-1] = g;
      }
    }
  }
  for (int ii = 1; ii < n; ++ii) {
    int k = ii - 1; double p = d[k];
    for (int j = ii; j < n; ++j) if (d[j] < p) { k = j; p = d[j]; }
    if (k != ii-1) {
      d[k] = d[ii-1]; d[ii-1] = p;
      for (int r = 0; r < n; ++r) { double tq = q[r*ldq + ii-1]; q[r*ldq + ii-1] = q[r*ldq + k]; q[r*ldq + k] = tq; }
    }
  }
}

__global__ __launch_bounds__(256) void k_zeroq(double* __restrict__ QT) {
  size_t i = (size_t)blockIdx.x*256 + threadIdx.x;
  size_t total = (size_t)NB*65536;
  for (; i < total; i += (size_t)gridDim.x*256) QT[i] = 0.0;
}

// ================= leaves: tears + 16x ssteqr(16), write TRANSPOSED (QT[eigvec][component]) =================
__global__ __launch_bounds__(64) void k_leaves(const double* __restrict__ d_g, const double* __restrict__ e_g,
        double* __restrict__ QT, double* __restrict__ DW) {
  int b = blockIdx.x, t = threadIdx.x;
  __shared__ double dL[256], eL[256];
  __shared__ double ql[16*272];   // 16 leaves x [16][17]
  for (int i = t; i < 256; i += 64) { dL[i] = d_g[b*256 + i]; eL[i] = e_g[b*256 + i]; }
  __syncthreads();
  if (t == 0) {
    for (int cut = 16; cut < 256; cut += 16) {
      double a = fabs(eL[cut-1]);
      dL[cut-1] -= a; dL[cut] -= a;
    }
  }
  __syncthreads();
  if (t < 16) {
    double* q = &ql[t*272];
    for (int i = 0; i < 16; ++i)
      for (int j = 0; j < 16; ++j) q[i*17 + j] = (i == j) ? 1.0 : 0.0;
    steqr_leaf(16, dL + 16*t, eL + 16*t, q, 17);
  }
  __syncthreads();
  for (int idx = t; idx < 4096; idx += 64) {
    int lf = idx >> 8, i = (idx >> 4) & 15, j = idx & 15;
    QT[(size_t)b*65536 + (size_t)(lf*16 + j)*256 + lf*16 + i] = ql[lf*272 + i*17 + j];
  }
  for (int i = t; i < 256; i += 64) DW[b*256 + i] = dL[i];
}

// ================= merge phase 1: scan + rotations + secular + S (dlaed1/2/3 faithful) =================
__global__ __launch_bounds__(256) void k_mscan(int n1, const double* __restrict__ e_g,
        double* __restrict__ QT, double* __restrict__ DW, double* __restrict__ SG, int* __restrict__ META) {
  int mrg = blockIdx.x, b = blockIdx.y, t = threadIdx.x;
  int nn = 2*n1, r0 = mrg*nn;
  double* Q = QT + (size_t)b*65536;
  double* Sg = SG + (size_t)b*65536;
  int* meta = META + ((b*8 + mrg)*520);
  __shared__ double dloc[256], zloc[256], dlam[256], wv[256], w2[256], tauv[256], zh[256], dfin[256];
  __shared__ int indx[256], indxp[256], permf[256];
  __shared__ double rotc[256], rots[256];
  __shared__ short rotp[256], rotq[256];
  __shared__ int KK[3];
  __shared__ double sc[2];
  double rho_raw = e_g[b*256 + r0 + n1 - 1];
  if (t < nn) {
    dloc[t] = DW[b*256 + r0 + t];
    double zv = Q[(size_t)(r0 + t)*256 + r0 + ((t < n1) ? (n1 - 1) : n1)];
    if (t >= n1 && rho_raw < 0.0) zv = -zv;      // dlaed2
    zloc[t] = zv * 0.70710678118654752440;
  }
  __syncthreads();
  if (t == 0) {
    int i = 0, jj = n1, pos = 0;
    while (i < n1 && jj < nn) { if (dloc[i] <= dloc[jj]) indx[pos++] = i++; else indx[pos++] = jj++; }
    while (i < n1) indx[pos++] = i++;
    while (jj < nn) indx[pos++] = jj++;
    double maxd = 0.0, maxz = 0.0;
    for (int q2 = 0; q2 < nn; ++q2) { maxd = fmax(maxd, fabs(dloc[q2])); maxz = fmax(maxz, fabs(zloc[q2])); }
    double rho = fabs(2.0*rho_raw);
    double tol = 8.0*EPS32*fmax(maxd, maxz);
    int K = 0, K2 = nn, nrot = 0, pj = -1, j = 0;
    for (; j < nn; ++j) {
      int nj = indx[j];
      if (rho*fabs(zloc[nj]) <= tol) { K2--; indxp[K2] = nj; }
      else { pj = nj; break; }
    }
    if (pj >= 0) {
      for (++j; j < nn; ++j) {
        int nj = indx[j];
        if (rho*fabs(zloc[nj]) <= tol) { K2--; indxp[K2] = nj; }
        else {
          double s = zloc[pj], c = zloc[nj];
          double tau = sqrt(c*c + s*s);
          double tdf = dloc[nj] - dloc[pj];
          c /= tau; s = -s/tau;
          if (fabs(tdf*c*s) <= tol) {
            zloc[nj] = tau; zloc[pj] = 0.0;
            rotp[nrot] = (short)pj; rotq[nrot] = (short)nj; rotc[nrot] = c; rots[nrot] = s; nrot++;
            double tt2 = dloc[pj]*c*c + dloc[nj]*s*s;
            dloc[nj] = dloc[pj]*s*s + dloc[nj]*c*c;
            dloc[pj] = tt2;
            K2--;
            int ii2 = 1;
            while (K2 + ii2 <= nn - 1 && dloc[pj] < dloc[indxp[K2 + ii2]]) { indxp[K2+ii2-1] = indxp[K2+ii2]; ii2++; }
            indxp[K2+ii2-1] = pj;
            pj = nj;
          } else {
            dlam[K] = dloc[pj]; wv[K] = zloc[pj]; indxp[K] = pj; K++;
            pj = nj;
          }
        }
      }
      dlam[K] = dloc[pj]; wv[K] = zloc[pj]; indxp[K] = pj; K++;
    }
    double sumw2 = 0.0;
    for (int q2 = 0; q2 < K; ++q2) sumw2 += wv[q2]*wv[q2];
    KK[0] = K; KK[1] = K2; KK[2] = nrot; sc[0] = rho; sc[1] = sumw2;
  }
  __syncthreads();
  int K = KK[0], K2 = KK[1], nrot = KK[2];
  double rho = sc[0], sumw2 = sc[1];
  if (t < nn) {
    for (int k = 0; k < nrot; ++k) {
      int p = rotp[k], q = rotq[k];
      double c = rotc[k], s = rots[k];
      size_t ip = (size_t)(r0 + p)*256 + r0 + t;
      size_t iq = (size_t)(r0 + q)*256 + r0 + t;
      double xq = Q[ip], yq = Q[iq];
      Q[ip] = c*xq + s*yq;
      Q[iq] = c*yq - s*xq;
    }
  }
  if (t < K) w2[t] = rho*wv[t]*wv[t];
  __syncthreads();
  if (t < K) {
    double dj = dlam[t];
    double hi0 = (t < K-1) ? (dlam[t+1] - dj) : rho*sumw2;
    double lo = 0.0, hi = hi0;
    for (int it = 0; it < 64; ++it) {
      double mid = 0.5*(lo + hi);
      double f = 1.0;
      for (int j2 = 0; j2 < K; ++j2) f += w2[j2]/((dlam[j2] - dj) - mid);
      if (f < 0.0) lo = mid; else hi = mid;
    }
    double tl = 0.5*(lo + hi);
    if (tl <= 0.0) tl = hi0*1e-300;
    tauv[t] = tl;
  }
  __syncthreads();
  if (t < K) {
    double dt2 = dlam[t], p = tauv[t];
    for (int i = 0; i < K; ++i) { if (i == t) continue; double del = dlam[i] - dt2; p *= (del + tauv[i])/del; }
    zh[t] = copysign(sqrt(fabs(p)), wv[t]);
  }
  __syncthreads();
  if (t < K) {
    double dj = dlam[t], tj = tauv[t];
    double nrm = 0.0;
    for (int i = 0; i < K; ++i) { double sij = zh[i]/((dlam[i] - dj) - tj); nrm += sij*sij; }
    double inv = 1.0/sqrt(nrm);
    for (int i = 0; i < K; ++i) Sg[(size_t)(r0 + i)*256 + t] = (zh[i]/((dlam[i] - dj) - tj))*inv;
  }
  __syncthreads();
  if (t == 0) {
    int i = 0, p = nn - 1, f = 0;
    while (f < nn) {
      bool takesec;
      if (i < K && p >= K2) takesec = ((dlam[i] + tauv[i]) <= dloc[indxp[p]]);
      else takesec = (i < K);
      if (takesec) { dfin[f] = dlam[i] + tauv[i]; permf[f] = i; i++; }
      else         { dfin[f] = dloc[indxp[p]];    permf[f] = K + (p - K2); p--; }
      f++;
    }
    for (f = 0; f < nn; ++f) DW[b*256 + r0 + f] = dfin[f];
    meta[0] = K; meta[1] = K2;
  }
  __syncthreads();
  if (t < nn) { meta[2 + t] = indxp[t]; meta[258 + t] = permf[t]; }
}

// ================= merge phase 2: QNT[j][r] = sum_i S[i][j] * QT[indxp[i]][r] (LDS-tiled) + deflated copy =================
__global__ __launch_bounds__(256) void k_mgemm(int n1, int nmrg, const double* __restrict__ QT,
        const double* __restrict__ SG, const int* __restrict__ META, double* __restrict__ QNT) {
  int nn = 2*n1;
  int jt = blockIdx.x, rt = blockIdx.y;
  int z = blockIdx.z;
  int mrg = z % nmrg, b = z / nmrg;
  int r0 = mrg*nn;
  int t = threadIdx.x;
  const int* meta = META + ((b*8 + mrg)*520);
  __shared__ int sindxp[256];
  __shared__ double Gs[32][66];
  __shared__ double Ss[32][33];
  const double* Q = QT + (size_t)b*65536;
  const double* Sg = SG + (size_t)b*65536;
  double* Qn = QNT + (size_t)b*65536;
  int K = meta[0], K2 = meta[1];
  if (t < nn) sindxp[t] = meta[2 + t];
  __syncthreads();
  int jl = t >> 6, rl = t & 63;
  int r = rt*64 + rl;
  double acc[8];
  #pragma unroll
  for (int q = 0; q < 8; ++q) acc[q] = 0.0;
  if (jt*32 < K) {
    for (int i0 = 0; i0 < K; i0 += 32) {
      #pragma unroll
      for (int w = 0; w < 8; ++w) {
        int idx = t + 256*w;
        int ii = idx >> 6, rr = idx & 63;
        double v = 0.0;
        if (i0 + ii < K && rt*64 + rr < nn)
          v = Q[(size_t)(r0 + sindxp[i0 + ii])*256 + r0 + rt*64 + rr];
        Gs[ii][rr] = v;
      }
      #pragma unroll
      for (int w = 0; w < 4; ++w) {
        int idx = t + 256*w;
        int ii2 = idx >> 5, jj = idx & 31;
        double v = 0.0;
        if (i0 + ii2 < K)
          v = Sg[(size_t)(r0 + i0 + ii2)*256 + jt*32 + jj];
        Ss[ii2][jj] = v;
      }
      __syncthreads();
      int kmax = (K - i0 < 32) ? (K - i0) : 32;
      for (int ii = 0; ii < kmax; ++ii) {
        double gv = Gs[ii][rl];
        #pragma unroll
        for (int q = 0; q < 8; ++q) acc[q] += Ss[ii][jl + 4*q] * gv;
      }
      __syncthreads();
    }
  }
  if (r < nn) {
    #pragma unroll
    for (int q = 0; q < 8; ++q) {
      int j = jt*32 + jl + 4*q;
      if (j < K) Qn[(size_t)(r0 + j)*256 + r0 + r] = acc[q];
      else if (j < nn) {
        int p = K2 + (j - K);
        Qn[(size_t)(r0 + j)*256 + r0 + r] = Q[(size_t)(r0 + sindxp[p])*256 + r0 + r];
      }
    }
  }
}

// ================= merge phase 3: permute rows back into QT =================
__global__ __launch_bounds__(256) void k_mperm(int n1, const double* __restrict__ QNT,
        const int* __restrict__ META, double* __restrict__ QT) {
  int mrg = blockIdx.x, b = blockIdx.y, t = threadIdx.x;
  int nn = 2*n1, r0 = mrg*nn;
  const int* meta = META + ((b*8 + mrg)*520);
  __shared__ int pf[256];
  if (t < nn) pf[t] = meta[258 + t];
  __syncthreads();
  if (t < nn) {
    for (int f = 0; f < nn; ++f)
      QT[(size_t)b*65536 + (size_t)(r0 + f)*256 + r0 + t] =
        QNT[(size_t)b*65536 + (size_t)(r0 + pf[f])*256 + r0 + t];
  }
}

// ================= back-transform, LDS-tiled: 16 eigvecs/block, emit Vt (f32) directly =================
__global__ __launch_bounds__(256) void k_backxf(const double* __restrict__ A, const double* __restrict__ tau_g,
        const double* __restrict__ QT, float* __restrict__ Vt) {
  int g = blockIdx.x, b = blockIdx.y;
  int t = threadIdx.x;
  int e = t >> 4, l = t & 15;
  __shared__ double zt[16][264];
  __shared__ double vL[256];
  __shared__ double tauL[256];
  const double* Ab = A + (size_t)b*65536;
  const double* Qb = QT + (size_t)b*65536 + (size_t)g*16*256;
  #pragma unroll
  for (int w = 0; w < 16; ++w) {
    int idx = t + 256*w;
    int ee = idx >> 8, rr = idx & 255;
    zt[ee][rr] = Qb[(size_t)ee*256 + rr];
  }
  tauL[t] = tau_g[b*256 + t];
  __syncthreads();
  for (int s = 253; s >= 0; --s) {
    if (t == 0) vL[s+1] = 1.0;
    int rx = s + 2 + t;
    if (rx < 256) vL[rx] = Ab[s*256 + rx];
    __syncthreads();
    double tauv = tauL[s];
    if (tauv != 0.0) {
      double acc = 0.0;
      for (int rr = s + 1 + l; rr < 256; rr += 16) acc += vL[rr]*zt[e][rr];
      acc += __shfl_xor(acc, 1);
      acc += __shfl_xor(acc, 2);
      acc += __shfl_xor(acc, 4);
      acc += __shfl_xor(acc, 8);
      double tw = tauv*acc;
      for (int rr = s + 1 + l; rr < 256; rr += 16) zt[e][rr] -= tw*vL[rr];
    }
    __syncthreads();
  }
  float* vtb = Vt + ((size_t)b*256 + (size_t)g*16)*256;
  #pragma unroll
  for (int w = 0; w < 16; ++w) {
    int idx = t + 256*w;
    int ee = idx >> 8, rr = idx & 255;
    vtb[(size_t)ee*256 + rr] = (float)zt[ee][rr];
  }
}

// ================= x_proj = V x, + x, fused maxpool + noise output =================
__global__ __launch_bounds__(256) void k_xproj(const float* __restrict__ x, const float* __restrict__ Vt,
        float* __restrict__ xp, float* __restrict__ noise_out) {
  int R = blockIdx.x, ct = blockIdx.y, b = blockIdx.z;
  int t = threadIdx.x;
  int cl = t >> 3, l8 = t & 7;
  __shared__ float vsh[32][20];
  __shared__ float xs[16][520];
  const float* xb = x + (size_t)b*256*NPX;
  int s0 = R*512;
  float acc[64];
  #pragma unroll
  for (int p = 0; p < 64; ++p) acc[p] = 0.0f;
  for (int d0 = 0; d0 < 256; d0 += 16) {
    for (int q = t; q < 512; q += 256) {
      int c = q >> 4, dd = q & 15;
      vsh[c][dd] = Vt[((size_t)b*256 + ct*32 + c)*256 + d0 + dd];
    }
    for (int q = t; q < 8192; q += 256) {
      int dd = q >> 9, px = q & 511;
      xs[dd][px] = xb[(size_t)(d0 + dd)*NPX + s0 + px];
    }
    __syncthreads();
    for (int dd = 0; dd < 16; ++dd) {
      float a = vsh[cl][dd];
      const float* xr = &xs[dd][l8];
      #pragma unroll
      for (int p = 0; p < 64; ++p) acc[p] += a*xr[8*p];
    }
    __syncthreads();
  }
  int cg = ct*32 + cl;
  const float* xc = xb + (size_t)cg*NPX + s0;
  float vmax[16];
  #pragma unroll
  for (int j = 0; j < 16; ++j) vmax[j] = -3.0e38f;
  bool isnz = (ct == 0);
  #pragma unroll
  for (int p = 0; p < 64; ++p) {
    int px = l8 + 8*p;
    float val = acc[p] + xc[px];
    vmax[p & 15] = fmaxf(vmax[p & 15], val);
    if (isnz) noise_out[((size_t)b*32 + cl)*NPX + s0 + px] = val;
  }
  #pragma unroll
  for (int j = 0; j < 16; ++j) {
    float v = vmax[j];
    v = fmaxf(v, __shfl_xor(v, 1));
    v = fmaxf(v, __shfl_xor(v, 2));
    vmax[j] = v;
  }
  if ((l8 & 3) == 0) {
    int halfsel = l8 >> 2;
    #pragma unroll
    for (int j = 0; j < 16; ++j)
      xp[((size_t)b*256 + cg)*PPX + R*32 + 2*j + halfsel] = vmax[j];
  }
}

// ================= qkv 1x1 conv (672 needed rows) =================
__global__ __launch_bounds__(256) void k_qkv(const float* __restrict__ xp, const float* __restrict__ wq,
        const float* __restrict__ bq, float* __restrict__ qkvm) {
  int pt = blockIdx.x, ot = blockIdx.y, b = blockIdx.z;
  int t = threadIdx.x;
  int ol = t & 31, pg = t >> 5;
  __shared__ float wsh[32][9];
  __shared__ float xsh[8][260];
  float acc[32];
  #pragma unroll
  for (int j = 0; j < 32; ++j) acc[j] = 0.0f;
  for (int ic0 = 0; ic0 < 256; ic0 += 8) {
    {
      int o = t >> 3, j = t & 7;
      int orow = ot*32 + o;
      int reg = orow/224, rem = orow - reg*224;
      int wrow = 32 + rem + 256*reg;
      wsh[o][j] = wq[(size_t)wrow*256 + ic0 + j];
    }
    for (int q = t; q < 2048; q += 256) {
      int ic = q >> 8, px = q & 255;
      xsh[ic][px] = xp[((size_t)b*256 + ic0 + ic)*PPX + pt*256 + px];
    }
    __syncthreads();
    for (int ic = 0; ic < 8; ++ic) {
      float a = wsh[ol][ic];
      const float* xr = &xsh[ic][pg];
      #pragma unroll
      for (int j = 0; j < 32; ++j) acc[j] += a*xr[8*j];
    }
    __syncthreads();
  }
  int orow = ot*32 + ol;
  int reg = orow/224, rem = orow - reg*224;
  float bv = bq[32 + rem + 256*reg];
  #pragma unroll
  for (int j = 0; j < 32; ++j)
    qkvm[((size_t)b*672 + orow)*PPX + pt*256 + pg + 8*j] = acc[j] + bv;
}

// ================= attention =================
__global__ __launch_bounds__(256) void k_attn(const float* __restrict__ qkvm, const float* __restrict__ emb,
        const float* __restrict__ xp, float* __restrict__ pool) {
  int rt = blockIdx.x, n = blockIdx.y, b = blockIdx.z;
  int t = threadIdx.x;
  int rl = t >> 5, pg = t & 31;
  __shared__ float S[8][1032];
  __shared__ float qsh[8][33];
  __shared__ float kv[4224];
  const float* qb = qkvm + (size_t)b*672*PPX;
  int rg0 = rt*8;
  {
    int rg = rg0 + rl;
    float qv = qb[(size_t)(32*n + (rg >> 5))*PPX + ((rg & 31) << 5) + pg];
    float ev = emb[(((size_t)n*8 + b)*1024 + rg)*32 + pg];
    qsh[rl][pg] = (qv + ev)*0.17677669529663688f;
  }
  __syncthreads();
  const float* kb = qb + (size_t)(224 + 32*n)*PPX;
  for (int p0 = 0; p0 < 1024; p0 += 128) {
    for (int q = t; q < 4096; q += 256) {
      int c = q >> 7, pp = q & 127;
      kv[c*132 + pp] = kb[(size_t)c*PPX + p0 + pp];
    }
    __syncthreads();
    float a0 = 0, a1 = 0, a2 = 0, a3 = 0;
    for (int c = 0; c < 32; ++c) {
      float qv = qsh[rl][c];
      const float* kr = &kv[c*132 + pg];
      a0 += qv*kr[0]; a1 += qv*kr[32]; a2 += qv*kr[64]; a3 += qv*kr[96];
    }
    S[rl][p0 + pg]      = a0;
    S[rl][p0 + pg + 32] = a1;
    S[rl][p0 + pg + 64] = a2;
    S[rl][p0 + pg + 96] = a3;
    __syncthreads();
  }
  float mx = -3.0e38f;
  for (int j = 0; j < 32; ++j) mx = fmaxf(mx, S[rl][pg + 32*j]);
  #pragma unroll
  for (int m = 1; m <= 16; m <<= 1) mx = fmaxf(mx, __shfl_xor(mx, m));
  float sum = 0.0f;
  for (int j = 0; j < 32; ++j) {
    float e = expf(S[rl][pg + 32*j] - mx);
    S[rl][pg + 32*j] = e;
    sum += e;
  }
  #pragma unroll
  for (int m = 1; m <= 16; m <<= 1) sum += __shfl_xor(sum, m);
  float inv = 1.0f/sum;
  for (int j = 0; j < 32; ++j) S[rl][pg + 32*j] *= inv;
  __syncthreads();
  const float* vb = qb + (size_t)(448 + 32*n)*PPX;
  float acc = 0.0f;
  for (int p0 = 0; p0 < 1024; p0 += 128) {
    for (int q = t; q < 4096; q += 256) {
      int pp = q >> 5, c = q & 31;
      int p = p0 + pp;
      kv[pp*33 + c] = vb[(size_t)(p >> 5)*PPX + ((p & 31) << 5) + c];
    }
    __syncthreads();
    for (int pp = 0; pp < 128; ++pp) acc += S[rl][p0 + pp]*kv[pp*33 + pg];
    __syncthreads();
  }
  int rg = rg0 + rl;
  int ch = 32*n + (rg >> 5);
  size_t sp = (size_t)((rg & 31) << 5) + pg;
  pool[((size_t)b*224 + ch)*PPX + sp] = acc + xp[((size_t)b*256 + 32 + ch)*PPX + sp];
}

__global__ void k_owt(const float* __restrict__ ow, float* __restrict__ owt) {
  int t = blockIdx.x*256 + threadIdx.x;
  if (t < 256*224) {
    int oc = t/224, ch = t - oc*224;
    owt[(size_t)ch*256 + oc] = ow[t];
  }
}

// ================= bilinear + sim gating + final conv =================
__global__ __launch_bounds__(256) void k_final(const float* __restrict__ pool, const float* __restrict__ noise,
        const float* __restrict__ sim_w, const float* __restrict__ owt, float* __restrict__ out) {
  int tt = blockIdx.x, b = blockIdx.y;
  int t = threadIdx.x;
  int h = tt >> 3, w0 = (tt & 7)*16;
  __shared__ float xa[224][20];
  __shared__ float nsc[224][20];
  __shared__ float nz[32][20];
  __shared__ float scl[16];
  for (int q = t; q < 512; q += 256) {
    int c = q >> 4, px = q & 15;
    nz[c][px] = noise[((size_t)b*32 + c)*NPX + h*128 + w0 + px];
  }
  float hs = h*0.25f - 0.375f;
  float hf = floorf(hs);
  int h0 = (int)hf;
  float fh = hs - hf;
  int h0c = min(max(h0, 0), 31);
  int h1c = min(max(h0 + 1, 0), 31);
  __syncthreads();
  for (int q = t; q < 3584; q += 256) {
    int c = q >> 4, px = q & 15;
    int w = w0 + px;
    float wsrc = w*0.25f - 0.375f;
    float wf = floorf(wsrc);
    int W0 = (int)wf;
    float fw = wsrc - wf;
    int w0c = min(max(W0, 0), 31);
    int w1c = min(max(W0 + 1, 0), 31);
    const float* pb = pool + ((size_t)b*224 + c)*PPX;
    float v00 = pb[h0c*32 + w0c], v01 = pb[h0c*32 + w1c];
    float v10 = pb[h1c*32 + w0c], v11 = pb[h1c*32 + w1c];
    xa[c][px] = (1.0f - fh)*((1.0f - fw)*v00 + fw*v01) + fh*((1.0f - fw)*v10 + fw*v11);
    float np = 0.0f;
    #pragma unroll
    for (int j = 0; j < 32; ++j) np += sim_w[c*32 + j]*nz[j][px];
    nsc[c][px] = np;
  }
  __syncthreads();
  {
    int px = t >> 4, kk = t & 15;
    float s1 = 0, s2 = 0, s3 = 0;
    for (int c = kk; c < 224; c += 16) {
      float a = xa[c][px], p = nsc[c][px];
      s1 += a*a; s2 += p*p; s3 += a*p;
    }
    #pragma unroll
    for (int m = 1; m <= 8; m <<= 1) {
      s1 += __shfl_xor(s1, m);
      s2 += __shfl_xor(s2, m);
      s3 += __shfl_xor(s3, m);
    }
    if (kk == 0) {
      float n1 = fmaxf(sqrtf(s1), 1e-12f);
      float n2 = fmaxf(sqrtf(s2), 1e-12f);
      float sim = (s3/(n1*n2) + 1.0f)*0.5f;
      scl[px] = 1.0f - sim;
    }
  }
  __syncthreads();
  {
    float accp[16];
    #pragma unroll
    for (int px = 0; px < 16; ++px) accp[px] = 0.0f;
    for (int c = 0; c < 224; ++c) {
      float wv = owt[(size_t)c*256 + t];
      #pragma unroll
      for (int px = 0; px < 16; ++px) accp[px] += wv*xa[c][px];
    }
    size_t obase = ((size_t)b*256 + t)*NPX + (size_t)h*128 + w0;
    #pragma unroll
    for (int px = 0; px < 16; ++px) out[obase + px] = accp[px]*scl[px];
  }
  if (b == 0 && tt == 0 && t == 0) out[(size_t)33554432] = 8.0f;   // AVG_K
}

extern "C" void kernel_launch(void* const* d_in, const int* in_sizes, int n_in,
                              void* d_out, int out_size, void* d_ws, size_t ws_size,
                              hipStream_t stream) {
  (void)in_sizes; (void)n_in; (void)out_size; (void)ws_size;
  const float* x     = (const float*)d_in[0];
  const float* qkv_w = (const float*)d_in[1];
  const float* qkv_b = (const float*)d_in[2];
  const float* emb   = (const float*)d_in[3];
  const float* sim_w = (const float*)d_in[4];
  const float* out_w = (const float*)d_in[5];
  float* out = (float*)d_out;
  char* ws = (char*)d_ws;
  double* gram = (double*)(ws + OFF_GRAM);
  double* A    = (double*)(ws + OFF_A);
  double* QT   = (double*)(ws + OFF_QT);
  double* SG   = (double*)(ws + OFF_SG);
  double* QNT  = (double*)(ws + OFF_QN);
  double* d_a  = (double*)(ws + OFF_D);
  double* e_a  = (double*)(ws + OFF_E);
  double* tau_a= (double*)(ws + OFF_TAU);
  double* DW   = (double*)(ws + OFF_DW);
  int*    META = (int*)   (ws + OFF_META);
  float*  Vt   = (float*) (ws + OFF_VT);
  float*  xp   = (float*) (ws + OFF_XP);
  float*  qkvm = (float*) (ws + OFF_QKV);
  float*  pool = (float*) (ws + OFF_POOL);
  float*  owt  = (float*) (ws + OFF_OWT);
  float*  noise_out = out + 33554433;

  k_gram   <<<dim3(8,8,8),   256,  0, stream>>>(x, gram);
  k_tridiag<<<dim3(8),       1024, 0, stream>>>(gram, A, d_a, e_a, tau_a);
  k_zeroq  <<<dim3(512),     256,  0, stream>>>(QT);
  k_leaves <<<dim3(8),       64,   0, stream>>>(d_a, e_a, QT, DW);
  // merge levels: n1 = 16, 32, 64, 128; nmrg = 8, 4, 2, 1
  {
    const int n1s[4]   = {16, 32, 64, 128};
    const int nmrgs[4] = {8, 4, 2, 1};
    for (int lv = 0; lv < 4; ++lv) {
      int n1 = n1s[lv], nmrg = nmrgs[lv], nn = 2*n1;
      k_mscan<<<dim3(nmrg, 8), 256, 0, stream>>>(n1, e_a, QT, DW, SG, META);
      k_mgemm<<<dim3(nn/32, (nn + 63)/64, nmrg*8), 256, 0, stream>>>(n1, nmrg, QT, SG, META, QNT);
      k_mperm<<<dim3(nmrg, 8), 256, 0, stream>>>(n1, QNT, META, QT);
    }
  }
  k_backxf <<<dim3(16,8),    256, 0, stream>>>(A, tau_a, QT, Vt);
  k_xproj  <<<dim3(32,8,8),  256, 0, stream>>>(x, Vt, xp, noise_out);
  k_qkv    <<<dim3(4,21,8),  256, 0, stream>>>(xp, qkv_w, qkv_b, qkvm);
  k_attn   <<<dim3(128,7,8), 256, 0, stream>>>(qkvm, emb, xp, pool);
  k_owt    <<<dim3(224),     256, 0, stream>>>(out_w, owt);
  k_final  <<<dim3(1024,8),  256, 0, stream>>>(pool, noise_out, sim_w, owt, out);
}

// Round 10
// 9369.942 us; speedup vs baseline: 1.1425x; 1.1425x over previous
//
#include <hip/hip_runtime.h>
#include <math.h>

#define NB  8
#define NPX 16384   // 128*128
#define PPX 1024    // 32*32
#define PNB 32      // dlatrd panel width

// f32 LAPACK machine constants (SLAMCH) used for branch tolerances
#define EPS32   5.9604644775390625e-8   // 2^-24 (slamch 'E')
#define EPS232  (EPS32*EPS32)
#define SAFMIN32 1.1754943508222875e-38

// ---------------- workspace layout (bytes), phase-aliased ----------------
static constexpr size_t OFF_VT   = 0;                    // f32 [8][256][256] 2MB (lives across phases)
static constexpr size_t U        = 0x200000;
static constexpr size_t OFF_A    = U + 0x400000;         // f64 [8][256][256] 4MB gram -> in-place tridiag / reflectors
static constexpr size_t OFF_QT   = U + 0x800000;         // f64 [8][256][256] 4MB QT[col][row]
static constexpr size_t OFF_SG   = U + 0xC00000;         // f64 [8][256][256] 4MB S scratch
static constexpr size_t OFF_QN   = U + 0x1000000;        // f64 [8][256][256] 4MB QNT scratch
static constexpr size_t OFF_D    = U + 0x1400000;        // f64 [8][256]
static constexpr size_t OFF_E    = U + 0x1404000;        // f64 [8][256]
static constexpr size_t OFF_TAU  = U + 0x1408000;        // f64 [8][256]
static constexpr size_t OFF_DW   = U + 0x140C000;        // f64 [8][256]
static constexpr size_t OFF_META = U + 0x1410000;        // int [8][8][520]
static constexpr size_t OFF_VG   = U + 0x1500000;        // f64 [8][256][32] 512KB panel V
static constexpr size_t OFF_WG   = U + 0x1580000;        // f64 [8][256][32] 512KB panel W
// phase2 aliases (phase1 dead in order: A after backxf, QT after backxf, SG/QN/META/VG/WG after merges):
static constexpr size_t OFF_XP   = U;                    // f32 [8][256][1024] 8MB
static constexpr size_t OFF_QKV  = U + 0x800000;         // f32 [8][672][1024] 21MB
static constexpr size_t OFF_POOL = U + 0x1D00000;        // f32 [8][224][1024] 7MB
static constexpr size_t OFF_OWT  = U + 0x2400000;        // f32 [224][256]

// ================= gram = X X^T (f64 accumulate), writes straight into A =================
__global__ __launch_bounds__(256) void k_gram(const float* __restrict__ x, double* __restrict__ gram) {
  int jt = blockIdx.x, it = blockIdx.y, b = blockIdx.z;
  __shared__ float xi[32][129], xj[32][129];
  const float* xb = x + (size_t)b*256*NPX;
  int t = threadIdx.x;
  int ci = t & 31, cjg = t >> 5;
  double acc[4] = {0.0,0.0,0.0,0.0};
  for (int n0 = 0; n0 < NPX; n0 += 128) {
    for (int q = 0; q < 16; ++q) {
      int idx = t + q*256;
      int r = idx >> 7, cc = idx & 127;
      xi[r][cc] = xb[(size_t)(it*32 + r)*NPX + n0 + cc];
      xj[r][cc] = xb[(size_t)(jt*32 + r)*NPX + n0 + cc];
    }
    __syncthreads();
    for (int p = 0; p < 128; ++p) {
      double a = (double)xi[ci][p];
      #pragma unroll
      for (int k = 0; k < 4; ++k) acc[k] += a * (double)xj[cjg + 8*k][p];
    }
    __syncthreads();
  }
  #pragma unroll
  for (int k = 0; k < 4; ++k)
    gram[((size_t)b*256 + it*32 + ci)*256 + jt*32 + cjg + 8*k] = acc[k];
}

__device__ __forceinline__ double blkSum16(double v, double* tmp, int t, int nw) {
  #pragma unroll
  for (int m = 1; m <= 32; m <<= 1) v += __shfl_xor(v, m);
  __syncthreads();
  if ((t & 63) == 0) tmp[t >> 6] = v;
  __syncthreads();
  double s = 0.0;
  for (int w = 0; w < nw; ++w) s += tmp[w];
  return s;
}

// ================= blocked tridiagonalization: dlatrd-style panel (nb=32) =================
// Per column: ONE read-only pass over trailing A0 (global) + small LDS corrections with the
// V,W panels; trailing rank-2nb update deferred to k_syr2k. Reflector rows written through
// to global A (backxf reads them). d/e/tau extracted on the fly.
__global__ __launch_bounds__(1024) void k_panel(int p, double* __restrict__ A,
        double* __restrict__ d_g, double* __restrict__ e_g, double* __restrict__ tau_g,
        double* __restrict__ Vg, double* __restrict__ Wg) {
  int b = blockIdx.x, t = threadIdx.x;
  int g = t >> 8, c = t & 255;
  double* Ab = A + (size_t)b*65536;
  __shared__ double V[256][33], W[256][33];     // 135168 B
  __shared__ double vL[256], wL[256], rowCur[256];
  __shared__ double wpart[4][256];
  __shared__ double c12[64];
  __shared__ double tmp[16];
  int jmax = (p == 7) ? 31 : 32;
  for (int j = 0; j < jmax; ++j) {
    int i = p*PNB + j;
    // 1. current (fully updated) pivot row i: A0 row + panel corrections
    if (g == 0) {
      double rv = 0.0;
      if (c >= i) {
        rv = Ab[(size_t)i*256 + c];
        for (int k = 0; k < j; ++k)
          rv -= V[i][k]*W[c][k] + W[i][k]*V[c][k];
      }
      rowCur[c] = rv;
    }
    __syncthreads();
    // 2. dlarfg
    double part = 0.0;
    int rx = i + 2 + t;
    if (rx < 256) { double v = rowCur[rx]; part = v*v; }
    double xn2 = blkSum16(part, tmp, t, 16);
    double alpha = rowCur[i + 1];
    double beta, tauv, scale;
    if (xn2 == 0.0) { beta = alpha; tauv = 0.0; scale = 0.0; }
    else {
      beta  = -copysign(sqrt(alpha*alpha + xn2), alpha);
      tauv  = (beta - alpha)/beta;
      scale = 1.0/(alpha - beta);
    }
    if (t == 0) { e_g[b*256 + i] = beta; tau_g[b*256 + i] = tauv; d_g[b*256 + i] = rowCur[i]; }
    // 3. v (fully defined each step), V column, reflector write-through
    if (g == 0) {
      double v = 0.0;
      if (c == i + 1) v = 1.0;
      else if (c >= i + 2) v = rowCur[c]*scale;
      vL[c] = v;
      V[c][j] = v;
      if (c >= i + 1) Ab[(size_t)i*256 + c] = v;
    }
    __syncthreads();
    // 4. matvec partial: wpart[g][c] = sum_{r=i+1+g step 4} A0[r][c] * v[r]  (read-only pass)
    {
      double s = 0.0;
      if (c >= i + 1) {
        for (int r = i + 1 + g; r < 256; r += 4) s += Ab[(size_t)r*256 + c]*vL[r];
      }
      wpart[g][c] = s;
    }
    // 5. corrections c1 = W^T v, c2 = V^T v (32-lane group dots in LDS)
    {
      int kk = t >> 5, lane = t & 31;
      if (kk < j) {
        double s = 0.0;
        for (int ci2 = lane; ci2 < 256; ci2 += 32) s += W[ci2][kk]*vL[ci2];
        s += __shfl_xor(s, 1); s += __shfl_xor(s, 2); s += __shfl_xor(s, 4);
        s += __shfl_xor(s, 8); s += __shfl_xor(s, 16);
        if (lane == 0) c12[kk] = s;
        double s2 = 0.0;
        for (int ci2 = lane; ci2 < 256; ci2 += 32) s2 += V[ci2][kk]*vL[ci2];
        s2 += __shfl_xor(s2, 1); s2 += __shfl_xor(s2, 2); s2 += __shfl_xor(s2, 4);
        s2 += __shfl_xor(s2, 8); s2 += __shfl_xor(s2, 16);
        if (lane == 0) c12[32 + kk] = s2;
      }
    }
    __syncthreads();
    // 6. w = tau*(A v - V c1 - W c2); dot = v.w; w += -0.5 tau dot v; W column
    double wfull = 0.0, part2 = 0.0;
    if (g == 0 && c >= i + 1) {
      double wr = wpart[0][c] + wpart[1][c] + wpart[2][c] + wpart[3][c];
      for (int k = 0; k < j; ++k) wr -= V[c][k]*c12[k] + W[c][k]*c12[32 + k];
      wfull = tauv*wr;
      part2 = vL[c]*wfull;
    }
    double dot = blkSum16(part2, tmp, t, 16);
    double coef = -0.5*tauv*dot;
    if (g == 0) {
      double wv2 = (c >= i + 1) ? (wfull + coef*vL[c]) : 0.0;
      wL[c] = wv2;
      W[c][j] = wv2;
    }
    __syncthreads();
  }
  if (p < 7) {
    // spill panels for the trailing syr2k
    for (int idx = t; idx < 256*32; idx += 1024) {
      int cc = idx >> 5, kk = idx & 31;
      Vg[((size_t)b*256 + cc)*32 + kk] = V[cc][kk];
      Wg[((size_t)b*256 + cc)*32 + kk] = W[cc][kk];
    }
  } else {
    if (t == 0) {
      double dv = Ab[(size_t)255*256 + 255];
      for (int k = 0; k < 31; ++k) dv -= 2.0*V[255][k]*W[255][k];
      d_g[b*256 + 255] = dv;
      e_g[b*256 + 255] = 0.0;
    }
  }
}

// ================= trailing update: A -= V W^T + W V^T on rows/cols >= 32(p+1) =================
__global__ __launch_bounds__(256) void k_syr2k(int p, const double* __restrict__ Vg,
        const double* __restrict__ Wg, double* __restrict__ A) {
  int rt = blockIdx.x, ct = blockIdx.y, b = blockIdx.z;
  int base = (p + 1)*32;
  int r0 = base + rt*32, c0 = base + ct*32;
  int t = threadIdx.x;
  __shared__ double Vr[32][33], Wr[32][33], Vc[32][33], Wc[32][33];
  for (int idx = t; idx < 1024; idx += 256) {
    int rr = idx >> 5, kk = idx & 31;
    Vr[rr][kk] = Vg[((size_t)b*256 + r0 + rr)*32 + kk];
    Wr[rr][kk] = Wg[((size_t)b*256 + r0 + rr)*32 + kk];
    Vc[rr][kk] = Vg[((size_t)b*256 + c0 + rr)*32 + kk];
    Wc[rr][kk] = Wg[((size_t)b*256 + c0 + rr)*32 + kk];
  }
  __syncthreads();
  int cl = t & 31, rg = t >> 5;
  double* Ab = A + (size_t)b*65536;
  #pragma unroll
  for (int q = 0; q < 4; ++q) {
    int rl = rg + 8*q;
    double acc = Ab[(size_t)(r0 + rl)*256 + c0 + cl];
    #pragma unroll
    for (int k = 0; k < 32; ++k)
      acc -= Vr[rl][k]*Wc[cl][k] + Wr[rl][k]*Vc[cl][k];
    Ab[(size_t)(r0 + rl)*256 + c0 + cl] = acc;
  }
}

// ================= LAPACK helpers =================
__device__ __forceinline__ void dlartg_(double f, double g, double& c, double& s, double& r) {
  if (g == 0.0) { c = 1.0; s = 0.0; r = f; }
  else if (f == 0.0) { c = 0.0; s = (g > 0.0) ? 1.0 : -1.0; r = fabs(g); }
  else {
    double d = sqrt(f*f + g*g);
    r = (f >= 0.0) ? d : -d;
    c = f / r;
    s = g / r;
  }
}

__device__ void dlaev2_(double a, double b, double cc, double& rt1, double& rt2, double& cs1, double& sn1) {
  double sm = a + cc, df = a - cc;
  double adf = fabs(df), tb = b + b, ab = fabs(tb);
  double acmx, acmn;
  if (fabs(a) > fabs(cc)) { acmx = a; acmn = cc; } else { acmx = cc; acmn = a; }
  double rt;
  if (adf > ab)      rt = adf*sqrt(1.0 + (ab/adf)*(ab/adf));
  else if (adf < ab) rt = ab*sqrt(1.0 + (adf/ab)*(adf/ab));
  else               rt = ab*sqrt(2.0);
  int sgn1;
  if (sm < 0.0)      { rt1 = 0.5*(sm - rt); sgn1 = -1; rt2 = (acmx/rt1)*acmn - (b/rt1)*b; }
  else if (sm > 0.0) { rt1 = 0.5*(sm + rt); sgn1 = 1;  rt2 = (acmx/rt1)*acmn - (b/rt1)*b; }
  else               { rt1 = 0.5*rt; rt2 = -0.5*rt; sgn1 = 1; }
  double cs; int sgn2;
  if (df >= 0.0) { cs = df + rt; sgn2 = 1; } else { cs = df - rt; sgn2 = -1; }
  double acs = fabs(cs);
  if (acs > ab) {
    double ct = -tb/cs;
    sn1 = 1.0/sqrt(1.0 + ct*ct);
    cs1 = ct*sn1;
  } else {
    if (ab == 0.0) { cs1 = 1.0; sn1 = 0.0; }
    else {
      double tn = -cs/tb;
      cs1 = 1.0/sqrt(1.0 + tn*tn);
      sn1 = tn*cs1;
    }
  }
  if (sgn1 == sgn2) { double tn = cs1; cs1 = -sn1; sn1 = tn; }
}

// faithful dsteqr('I') on an n<=16 block, f64 arithmetic with f32 tolerances
__device__ void steqr_leaf(int n, double* d, double* e, double* q, int ldq) {
  const double eps = EPS32, eps2 = EPS232, safmin = SAFMIN32;
  int nmaxit = n*30, jtot = 0;
  int l1 = 0;
  while (l1 < n) {
    if (l1 > 0) e[l1-1] = 0.0;
    int m;
    for (m = l1; m < n-1; ++m) {
      double tst = fabs(e[m]);
      if (tst == 0.0) break;
      if (tst <= (sqrt(fabs(d[m]))*sqrt(fabs(d[m+1])))*eps) { e[m] = 0.0; break; }
    }
    int l = l1, lend = m;
    l1 = m + 1;
    if (lend == l) continue;
    if (fabs(d[lend]) < fabs(d[l])) { int tsw = l; l = lend; lend = tsw; }
    if (lend > l) {
      while (true) {
        int mm;
        for (mm = l; mm < lend; ++mm) {
          double tst = e[mm]*e[mm];
          if (tst <= (eps2*fabs(d[mm]))*fabs(d[mm+1]) + safmin) break;
        }
        if (mm < lend) e[mm] = 0.0;
        double p = d[l];
        if (mm == l) { l = l + 1; if (l > lend) break; continue; }
        if (mm == l+1) {
          double rt1, rt2, c, s;
          dlaev2_(d[l], e[l], d[l+1], rt1, rt2, c, s);
          for (int i = 0; i < n; ++i) {
            double t1 = q[i*ldq + l+1], t0 = q[i*ldq + l];
            q[i*ldq + l+1] = c*t1 - s*t0;
            q[i*ldq + l]   = s*t1 + c*t0;
          }
          d[l] = rt1; d[l+1] = rt2; e[l] = 0.0;
          l += 2; if (l > lend) break; continue;
        }
        if (jtot == nmaxit) break;
        jtot++;
        double g = (d[l+1] - p)/(2.0*e[l]);
        double r = sqrt(g*g + 1.0);
        g = d[mm] - p + e[l]/(g + copysign(r, g));
        double s = 1.0, c = 1.0; p = 0.0;
        double csv[16], snv[16];
        for (int i = mm-1; i >= l; --i) {
          double f = s*e[i], bb = c*e[i];
          dlartg_(g, f, c, s, r);
          if (i != mm-1) e[i+1] = r;
          g = d[i+1] - p;
          r = (d[i] - g)*s + 2.0*c*bb;
          p = s*r;
          d[i+1] = g + p;
          g = c*r - bb;
          csv[i] = c; snv[i] = -s;
        }
        for (int i = mm-1; i >= l; --i) {
          double cc2 = csv[i], ss2 = snv[i];
          for (int k = 0; k < n; ++k) {
            double t1 = q[k*ldq + i+1], t0 = q[k*ldq + i];
            q[k*ldq + i+1] = cc2*t1 - ss2*t0;
            q[k*ldq + i]   = ss2*t1 + cc2*t0;
          }
        }
        d[l] -= p; e[l] = g;
      }
    } else {
      while (true) {
        int mm;
        for (mm = l; mm > lend; --mm) {
          double tst = e[mm-1]*e[mm-1];
          if (tst <= (eps2*fabs(d[mm]))*fabs(d[mm-1]) + safmin) break;
        }
        if (mm > lend) e[mm-1] = 0.0;
        double p = d[l];
        if (mm == l) { l = l - 1; if (l < lend) break; continue; }
        if (mm == l-1) {
          double rt1, rt2, c, s;
          dlaev2_(d[l-1], e[l-1], d[l], rt1, rt2, c, s);
          for (int i = 0; i < n; ++i) {
            double t1 = q[i*ldq + l], t0 = q[i*ldq + l-1];
            q[i*ldq + l]   = c*t1 - s*t0;
            q[i*ldq + l-1] = s*t1 + c*t0;
          }
          d[l-1] = rt1; d[l] = rt2; e[l-1] = 0.0;
          l -= 2; if (l < lend) break; continue;
        }
        if (jtot == nmaxit) break;
        jtot++;
        double g = (d[l-1] - p)/(2.0*e[l-1]);
        double r = sqrt(g*g + 1.0);
        g = d[mm] - p + e[l-1]/(g + copysign(r, g));
        double s = 1.0, c = 1.0; p = 0.0;
        double csv[16], snv[16];
        for (int i = mm; i <= l-1; ++i) {
          double f = s*e[i], bb = c*e[i];
          dlartg_(g, f, c, s, r);
          if (i != mm) e[i-1] = r;
          g = d[i] - p;
          r = (d[i+1] - g)*s + 2.0*c*bb;
          p = s*r;
          d[i] = g + p;
          g = c*r - bb;
          csv[i] = c; snv[i] = s;
        }
        for (int i = mm; i <= l-1; ++i) {
          double cc2 = csv[i], ss2 = snv[i];
          for (int k = 0; k < n; ++k) {
            double t1 = q[k*ldq + i+1], t0 = q[k*ldq + i];
            q[k*ldq + i+1] = cc2*t1 - ss2*t0;
            q[k*ldq + i]   = ss2*t1 + cc2*t0;
          }
        }
        d[l] -= p; e[l-1] = g;
      }
    }
  }
  for (int ii = 1; ii < n; ++ii) {
    int k = ii - 1; double p = d[k];
    for (int j = ii; j < n; ++j) if (d[j] < p) { k = j; p = d[j]; }
    if (k != ii-1) {
      d[k] = d[ii-1]; d[ii-1] = p;
      for (int r = 0; r < n; ++r) { double tq = q[r*ldq + ii-1]; q[r*ldq + ii-1] = q[r*ldq + k]; q[r*ldq + k] = tq; }
    }
  }
}

__global__ __launch_bounds__(256) void k_zeroq(double* __restrict__ QT) {
  size_t i = (size_t)blockIdx.x*256 + threadIdx.x;
  size_t total = (size_t)NB*65536;
  for (; i < total; i += (size_t)gridDim.x*256) QT[i] = 0.0;
}

// ================= leaves: tears + 16x ssteqr(16), write TRANSPOSED (QT[eigvec][component]) =================
__global__ __launch_bounds__(64) void k_leaves(const double* __restrict__ d_g, const double* __restrict__ e_g,
        double* __restrict__ QT, double* __restrict__ DW) {
  int b = blockIdx.x, t = threadIdx.x;
  __shared__ double dL[256], eL[256];
  __shared__ double ql[16*272];
  for (int i = t; i < 256; i += 64) { dL[i] = d_g[b*256 + i]; eL[i] = e_g[b*256 + i]; }
  __syncthreads();
  if (t == 0) {
    for (int cut = 16; cut < 256; cut += 16) {
      double a = fabs(eL[cut-1]);
      dL[cut-1] -= a; dL[cut] -= a;
    }
  }
  __syncthreads();
  if (t < 16) {
    double* q = &ql[t*272];
    for (int i = 0; i < 16; ++i)
      for (int j = 0; j < 16; ++j) q[i*17 + j] = (i == j) ? 1.0 : 0.0;
    steqr_leaf(16, dL + 16*t, eL + 16*t, q, 17);
  }
  __syncthreads();
  for (int idx = t; idx < 4096; idx += 64) {
    int lf = idx >> 8, i = (idx >> 4) & 15, j = idx & 15;
    QT[(size_t)b*65536 + (size_t)(lf*16 + j)*256 + lf*16 + i] = ql[lf*272 + i*17 + j];
  }
  for (int i = t; i < 256; i += 64) DW[b*256 + i] = dL[i];
}

// ================= merge phase 1: scan + rotations + secular + S (dlaed1/2/3 faithful) =================
__global__ __launch_bounds__(256) void k_mscan(int n1, const double* __restrict__ e_g,
        double* __restrict__ QT, double* __restrict__ DW, double* __restrict__ SG, int* __restrict__ META) {
  int mrg = blockIdx.x, b = blockIdx.y, t = threadIdx.x;
  int nn = 2*n1, r0 = mrg*nn;
  double* Q = QT + (size_t)b*65536;
  double* Sg = SG + (size_t)b*65536;
  int* meta = META + ((b*8 + mrg)*520);
  __shared__ double dloc[256], zloc[256], dlam[256], wv[256], w2[256], tauv[256], zh[256], dfin[256];
  __shared__ int indx[256], indxp[256], permf[256];
  __shared__ double rotc[256], rots[256];
  __shared__ short rotp[256], rotq[256];
  __shared__ int KK[3];
  __shared__ double sc[2];
  double rho_raw = e_g[b*256 + r0 + n1 - 1];
  if (t < nn) {
    dloc[t] = DW[b*256 + r0 + t];
    double zv = Q[(size_t)(r0 + t)*256 + r0 + ((t < n1) ? (n1 - 1) : n1)];
    if (t >= n1 && rho_raw < 0.0) zv = -zv;
    zloc[t] = zv * 0.70710678118654752440;
  }
  __syncthreads();
  if (t == 0) {
    int i = 0, jj = n1, pos = 0;
    while (i < n1 && jj < nn) { if (dloc[i] <= dloc[jj]) indx[pos++] = i++; else indx[pos++] = jj++; }
    while (i < n1) indx[pos++] = i++;
    while (jj < nn) indx[pos++] = jj++;
    double maxd = 0.0, maxz = 0.0;
    for (int q2 = 0; q2 < nn; ++q2) { maxd = fmax(maxd, fabs(dloc[q2])); maxz = fmax(maxz, fabs(zloc[q2])); }
    double rho = fabs(2.0*rho_raw);
    double tol = 8.0*EPS32*fmax(maxd, maxz);
    int K = 0, K2 = nn, nrot = 0, pj = -1, j = 0;
    for (; j < nn; ++j) {
      int nj = indx[j];
      if (rho*fabs(zloc[nj]) <= tol) { K2--; indxp[K2] = nj; }
      else { pj = nj; break; }
    }
    if (pj >= 0) {
      for (++j; j < nn; ++j) {
        int nj = indx[j];
        if (rho*fabs(zloc[nj]) <= tol) { K2--; indxp[K2] = nj; }
        else {
          double s = zloc[pj], c = zloc[nj];
          double tau = sqrt(c*c + s*s);
          double tdf = dloc[nj] - dloc[pj];
          c /= tau; s = -s/tau;
          if (fabs(tdf*c*s) <= tol) {
            zloc[nj] = tau; zloc[pj] = 0.0;
            rotp[nrot] = (short)pj; rotq[nrot] = (short)nj; rotc[nrot] = c; rots[nrot] = s; nrot++;
            double tt2 = dloc[pj]*c*c + dloc[nj]*s*s;
            dloc[nj] = dloc[pj]*s*s + dloc[nj]*c*c;
            dloc[pj] = tt2;
            K2--;
            int ii2 = 1;
            while (K2 + ii2 <= nn - 1 && dloc[pj] < dloc[indxp[K2 + ii2]]) { indxp[K2+ii2-1] = indxp[K2+ii2]; ii2++; }
            indxp[K2+ii2-1] = pj;
            pj = nj;
          } else {
            dlam[K] = dloc[pj]; wv[K] = zloc[pj]; indxp[K] = pj; K++;
            pj = nj;
          }
        }
      }
      dlam[K] = dloc[pj]; wv[K] = zloc[pj]; indxp[K] = pj; K++;
    }
    double sumw2 = 0.0;
    for (int q2 = 0; q2 < K; ++q2) sumw2 += wv[q2]*wv[q2];
    KK[0] = K; KK[1] = K2; KK[2] = nrot; sc[0] = rho; sc[1] = sumw2;
  }
  __syncthreads();
  int K = KK[0], K2 = KK[1], nrot = KK[2];
  double rho = sc[0], sumw2 = sc[1];
  if (t < nn) {
    for (int k = 0; k < nrot; ++k) {
      int p = rotp[k], q = rotq[k];
      double c = rotc[k], s = rots[k];
      size_t ip = (size_t)(r0 + p)*256 + r0 + t;
      size_t iq = (size_t)(r0 + q)*256 + r0 + t;
      double xq = Q[ip], yq = Q[iq];
      Q[ip] = c*xq + s*yq;
      Q[iq] = c*yq - s*xq;
    }
  }
  if (t < K) w2[t] = rho*wv[t]*wv[t];
  __syncthreads();
  if (t < K) {
    double dj = dlam[t];
    double hi0 = (t < K-1) ? (dlam[t+1] - dj) : rho*sumw2;
    double lo = 0.0, hi = hi0;
    for (int it = 0; it < 64; ++it) {
      double mid = 0.5*(lo + hi);
      double f = 1.0;
      for (int j2 = 0; j2 < K; ++j2) f += w2[j2]/((dlam[j2] - dj) - mid);
      if (f < 0.0) lo = mid; else hi = mid;
    }
    double tl = 0.5*(lo + hi);
    if (tl <= 0.0) tl = hi0*1e-300;
    tauv[t] = tl;
  }
  __syncthreads();
  if (t < K) {
    double dt2 = dlam[t], p = tauv[t];
    for (int i = 0; i < K; ++i) { if (i == t) continue; double del = dlam[i] - dt2; p *= (del + tauv[i])/del; }
    zh[t] = copysign(sqrt(fabs(p)), wv[t]);
  }
  __syncthreads();
  if (t < K) {
    double dj = dlam[t], tj = tauv[t];
    double nrm = 0.0;
    for (int i = 0; i < K; ++i) { double sij = zh[i]/((dlam[i] - dj) - tj); nrm += sij*sij; }
    double inv = 1.0/sqrt(nrm);
    for (int i = 0; i < K; ++i) Sg[(size_t)(r0 + i)*256 + t] = (zh[i]/((dlam[i] - dj) - tj))*inv;
  }
  __syncthreads();
  if (t == 0) {
    int i = 0, p = nn - 1, f = 0;
    while (f < nn) {
      bool takesec;
      if (i < K && p >= K2) takesec = ((dlam[i] + tauv[i]) <= dloc[indxp[p]]);
      else takesec = (i < K);
      if (takesec) { dfin[f] = dlam[i] + tauv[i]; permf[f] = i; i++; }
      else         { dfin[f] = dloc[indxp[p]];    permf[f] = K + (p - K2); p--; }
      f++;
    }
    for (f = 0; f < nn; ++f) DW[b*256 + r0 + f] = dfin[f];
    meta[0] = K; meta[1] = K2;
  }
  __syncthreads();
  if (t < nn) { meta[2 + t] = indxp[t]; meta[258 + t] = permf[t]; }
}

// ================= merge phase 2: QNT[j][r] = sum_i S[i][j] * QT[indxp[i]][r] =================
__global__ __launch_bounds__(256) void k_mgemm(int n1, int nmrg, const double* __restrict__ QT,
        const double* __restrict__ SG, const int* __restrict__ META, double* __restrict__ QNT) {
  int nn = 2*n1;
  int jt = blockIdx.x, rt = blockIdx.y;
  int z = blockIdx.z;
  int mrg = z % nmrg, b = z / nmrg;
  int r0 = mrg*nn;
  int t = threadIdx.x;
  const int* meta = META + ((b*8 + mrg)*520);
  __shared__ int sindxp[256];
  __shared__ double Gs[32][66];
  __shared__ double Ss[32][33];
  const double* Q = QT + (size_t)b*65536;
  const double* Sg = SG + (size_t)b*65536;
  double* Qn = QNT + (size_t)b*65536;
  int K = meta[0], K2 = meta[1];
  if (t < nn) sindxp[t] = meta[2 + t];
  __syncthreads();
  int jl = t >> 6, rl = t & 63;
  int r = rt*64 + rl;
  double acc[8];
  #pragma unroll
  for (int q = 0; q < 8; ++q) acc[q] = 0.0;
  if (jt*32 < K) {
    for (int i0 = 0; i0 < K; i0 += 32) {
      #pragma unroll
      for (int w = 0; w < 8; ++w) {
        int idx = t + 256*w;
        int ii = idx >> 6, rr = idx & 63;
        double v = 0.0;
        if (i0 + ii < K && rt*64 + rr < nn)
          v = Q[(size_t)(r0 + sindxp[i0 + ii])*256 + r0 + rt*64 + rr];
        Gs[ii][rr] = v;
      }
      #pragma unroll
      for (int w = 0; w < 4; ++w) {
        int idx = t + 256*w;
        int ii2 = idx >> 5, jj = idx & 31;
        double v = 0.0;
        if (i0 + ii2 < K)
          v = Sg[(size_t)(r0 + i0 + ii2)*256 + jt*32 + jj];
        Ss[ii2][jj] = v;
      }
      __syncthreads();
      int kmax = (K - i0 < 32) ? (K - i0) : 32;
      for (int ii = 0; ii < kmax; ++ii) {
        double gv = Gs[ii][rl];
        #pragma unroll
        for (int q = 0; q < 8; ++q) acc[q] += Ss[ii][jl + 4*q] * gv;
      }
      __syncthreads();
    }
  }
  if (r < nn) {
    #pragma unroll
    for (int q = 0; q < 8; ++q) {
      int j = jt*32 + jl + 4*q;
      if (j < K) Qn[(size_t)(r0 + j)*256 + r0 + r] = acc[q];
      else if (j < nn) {
        int p = K2 + (j - K);
        Qn[(size_t)(r0 + j)*256 + r0 + r] = Q[(size_t)(r0 + sindxp[p])*256 + r0 + r];
      }
    }
  }
}

// ================= merge phase 3: permute rows back into QT =================
__global__ __launch_bounds__(256) void k_mperm(int n1, const double* __restrict__ QNT,
        const int* __restrict__ META, double* __restrict__ QT) {
  int mrg = blockIdx.x, b = blockIdx.y, t = threadIdx.x;
  int nn = 2*n1, r0 = mrg*nn;
  const int* meta = META + ((b*8 + mrg)*520);
  __shared__ int pf[256];
  if (t < nn) pf[t] = meta[258 + t];
  __syncthreads();
  if (t < nn) {
    for (int f = 0; f < nn; ++f)
      QT[(size_t)b*65536 + (size_t)(r0 + f)*256 + r0 + t] =
        QNT[(size_t)b*65536 + (size_t)(r0 + pf[f])*256 + r0 + t];
  }
}

// ================= back-transform, LDS-tiled: 16 eigvecs/block, emit Vt (f32) directly =================
__global__ __launch_bounds__(256) void k_backxf(const double* __restrict__ A, const double* __restrict__ tau_g,
        const double* __restrict__ QT, float* __restrict__ Vt) {
  int g = blockIdx.x, b = blockIdx.y;
  int t = threadIdx.x;
  int e = t >> 4, l = t & 15;
  __shared__ double zt[16][264];
  __shared__ double vL[256];
  __shared__ double tauL[256];
  const double* Ab = A + (size_t)b*65536;
  const double* Qb = QT + (size_t)b*65536 + (size_t)g*16*256;
  #pragma unroll
  for (int w = 0; w < 16; ++w) {
    int idx = t + 256*w;
    int ee = idx >> 8, rr = idx & 255;
    zt[ee][rr] = Qb[(size_t)ee*256 + rr];
  }
  tauL[t] = tau_g[b*256 + t];
  __syncthreads();
  for (int s = 253; s >= 0; --s) {
    if (t == 0) vL[s+1] = 1.0;
    int rx = s + 2 + t;
    if (rx < 256) vL[rx] = Ab[s*256 + rx];
    __syncthreads();
    double tauv = tauL[s];
    if (tauv != 0.0) {
      double acc = 0.0;
      for (int rr = s + 1 + l; rr < 256; rr += 16) acc += vL[rr]*zt[e][rr];
      acc += __shfl_xor(acc, 1);
      acc += __shfl_xor(acc, 2);
      acc += __shfl_xor(acc, 4);
      acc += __shfl_xor(acc, 8);
      double tw = tauv*acc;
      for (int rr = s + 1 + l; rr < 256; rr += 16) zt[e][rr] -= tw*vL[rr];
    }
    __syncthreads();
  }
  float* vtb = Vt + ((size_t)b*256 + (size_t)g*16)*256;
  #pragma unroll
  for (int w = 0; w < 16; ++w) {
    int idx = t + 256*w;
    int ee = idx >> 8, rr = idx & 255;
    vtb[(size_t)ee*256 + rr] = (float)zt[ee][rr];
  }
}

// ================= x_proj = V x, + x, fused maxpool + noise output =================
__global__ __launch_bounds__(256) void k_xproj(const float* __restrict__ x, const float* __restrict__ Vt,
        float* __restrict__ xp, float* __restrict__ noise_out) {
  int R = blockIdx.x, ct = blockIdx.y, b = blockIdx.z;
  int t = threadIdx.x;
  int cl = t >> 3, l8 = t & 7;
  __shared__ float vsh[32][20];
  __shared__ float xs[16][520];
  const float* xb = x + (size_t)b*256*NPX;
  int s0 = R*512;
  float acc[64];
  #pragma unroll
  for (int p = 0; p < 64; ++p) acc[p] = 0.0f;
  for (int d0 = 0; d0 < 256; d0 += 16) {
    for (int q = t; q < 512; q += 256) {
      int c = q >> 4, dd = q & 15;
      vsh[c][dd] = Vt[((size_t)b*256 + ct*32 + c)*256 + d0 + dd];
    }
    for (int q = t; q < 8192; q += 256) {
      int dd = q >> 9, px = q & 511;
      xs[dd][px] = xb[(size_t)(d0 + dd)*NPX + s0 + px];
    }
    __syncthreads();
    for (int dd = 0; dd < 16; ++dd) {
      float a = vsh[cl][dd];
      const float* xr = &xs[dd][l8];
      #pragma unroll
      for (int p = 0; p < 64; ++p) acc[p] += a*xr[8*p];
    }
    __syncthreads();
  }
  int cg = ct*32 + cl;
  const float* xc = xb + (size_t)cg*NPX + s0;
  float vmax[16];
  #pragma unroll
  for (int j = 0; j < 16; ++j) vmax[j] = -3.0e38f;
  bool isnz = (ct == 0);
  #pragma unroll
  for (int p = 0; p < 64; ++p) {
    int px = l8 + 8*p;
    float val = acc[p] + xc[px];
    vmax[p & 15] = fmaxf(vmax[p & 15], val);
    if (isnz) noise_out[((size_t)b*32 + cl)*NPX + s0 + px] = val;
  }
  #pragma unroll
  for (int j = 0; j < 16; ++j) {
    float v = vmax[j];
    v = fmaxf(v, __shfl_xor(v, 1));
    v = fmaxf(v, __shfl_xor(v, 2));
    vmax[j] = v;
  }
  if ((l8 & 3) == 0) {
    int halfsel = l8 >> 2;
    #pragma unroll
    for (int j = 0; j < 16; ++j)
      xp[((size_t)b*256 + cg)*PPX + R*32 + 2*j + halfsel] = vmax[j];
  }
}

// ================= qkv 1x1 conv (672 needed rows) =================
__global__ __launch_bounds__(256) void k_qkv(const float* __restrict__ xp, const float* __restrict__ wq,
        const float* __restrict__ bq, float* __restrict__ qkvm) {
  int pt = blockIdx.x, ot = blockIdx.y, b = blockIdx.z;
  int t = threadIdx.x;
  int ol = t & 31, pg = t >> 5;
  __shared__ float wsh[32][9];
  __shared__ float xsh[8][260];
  float acc[32];
  #pragma unroll
  for (int j = 0; j < 32; ++j) acc[j] = 0.0f;
  for (int ic0 = 0; ic0 < 256; ic0 += 8) {
    {
      int o = t >> 3, j = t & 7;
      int orow = ot*32 + o;
      int reg = orow/224, rem = orow - reg*224;
      int wrow = 32 + rem + 256*reg;
      wsh[o][j] = wq[(size_t)wrow*256 + ic0 + j];
    }
    for (int q = t; q < 2048; q += 256) {
      int ic = q >> 8, px = q & 255;
      xsh[ic][px] = xp[((size_t)b*256 + ic0 + ic)*PPX + pt*256 + px];
    }
    __syncthreads();
    for (int ic = 0; ic < 8; ++ic) {
      float a = wsh[ol][ic];
      const float* xr = &xsh[ic][pg];
      #pragma unroll
      for (int j = 0; j < 32; ++j) acc[j] += a*xr[8*j];
    }
    __syncthreads();
  }
  int orow = ot*32 + ol;
  int reg = orow/224, rem = orow - reg*224;
  float bv = bq[32 + rem + 256*reg];
  #pragma unroll
  for (int j = 0; j < 32; ++j)
    qkvm[((size_t)b*672 + orow)*PPX + pt*256 + pg + 8*j] = acc[j] + bv;
}

// ================= attention =================
__global__ __launch_bounds__(256) void k_attn(const float* __restrict__ qkvm, const float* __restrict__ emb,
        const float* __restrict__ xp, float* __restrict__ pool) {
  int rt = blockIdx.x, n = blockIdx.y, b = blockIdx.z;
  int t = threadIdx.x;
  int rl = t >> 5, pg = t & 31;
  __shared__ float S[8][1032];
  __shared__ float qsh[8][33];
  __shared__ float kv[4224];
  const float* qb = qkvm + (size_t)b*672*PPX;
  int rg0 = rt*8;
  {
    int rg = rg0 + rl;
    float qv = qb[(size_t)(32*n + (rg >> 5))*PPX + ((rg & 31) << 5) + pg];
    float ev = emb[(((size_t)n*8 + b)*1024 + rg)*32 + pg];
    qsh[rl][pg] = (qv + ev)*0.17677669529663688f;
  }
  __syncthreads();
  const float* kb = qb + (size_t)(224 + 32*n)*PPX;
  for (int p0 = 0; p0 < 1024; p0 += 128) {
    for (int q = t; q < 4096; q += 256) {
      int c = q >> 7, pp = q & 127;
      kv[c*132 + pp] = kb[(size_t)c*PPX + p0 + pp];
    }
    __syncthreads();
    float a0 = 0, a1 = 0, a2 = 0, a3 = 0;
    for (int c = 0; c < 32; ++c) {
      float qv = qsh[rl][c];
      const float* kr = &kv[c*132 + pg];
      a0 += qv*kr[0]; a1 += qv*kr[32]; a2 += qv*kr[64]; a3 += qv*kr[96];
    }
    S[rl][p0 + pg]      = a0;
    S[rl][p0 + pg + 32] = a1;
    S[rl][p0 + pg + 64] = a2;
    S[rl][p0 + pg + 96] = a3;
    __syncthreads();
  }
  float mx = -3.0e38f;
  for (int j = 0; j < 32; ++j) mx = fmaxf(mx, S[rl][pg + 32*j]);
  #pragma unroll
  for (int m = 1; m <= 16; m <<= 1) mx = fmaxf(mx, __shfl_xor(mx, m));
  float sum = 0.0f;
  for (int j = 0; j < 32; ++j) {
    float e = expf(S[rl][pg + 32*j] - mx);
    S[rl][pg + 32*j] = e;
    sum += e;
  }
  #pragma unroll
  for (int m = 1; m <= 16; m <<= 1) sum += __shfl_xor(sum, m);
  float inv = 1.0f/sum;
  for (int j = 0; j < 32; ++j) S[rl][pg + 32*j] *= inv;
  __syncthreads();
  const float* vb = qb + (size_t)(448 + 32*n)*PPX;
  float acc = 0.0f;
  for (int p0 = 0; p0 < 1024; p0 += 128) {
    for (int q = t; q < 4096; q += 256) {
      int pp = q >> 5, c = q & 31;
      int p = p0 + pp;
      kv[pp*33 + c] = vb[(size_t)(p >> 5)*PPX + ((p & 31) << 5) + c];
    }
    __syncthreads();
    for (int pp = 0; pp < 128; ++pp) acc += S[rl][p0 + pp]*kv[pp*33 + pg];
    __syncthreads();
  }
  int rg = rg0 + rl;
  int ch = 32*n + (rg >> 5);
  size_t sp = (size_t)((rg & 31) << 5) + pg;
  pool[((size_t)b*224 + ch)*PPX + sp] = acc + xp[((size_t)b*256 + 32 + ch)*PPX + sp];
}

__global__ void k_owt(const float* __restrict__ ow, float* __restrict__ owt) {
  int t = blockIdx.x*256 + threadIdx.x;
  if (t < 256*224) {
    int oc = t/224, ch = t - oc*224;
    owt[(size_t)ch*256 + oc] = ow[t];
  }
}

// ================= bilinear + sim gating + final conv =================
__global__ __launch_bounds__(256) void k_final(const float* __restrict__ pool, const float* __restrict__ noise,
        const float* __restrict__ sim_w, const float* __restrict__ owt, float* __restrict__ out) {
  int tt = blockIdx.x, b = blockIdx.y;
  int t = threadIdx.x;
  int h = tt >> 3, w0 = (tt & 7)*16;
  __shared__ float xa[224][20];
  __shared__ float nsc[224][20];
  __shared__ float nz[32][20];
  __shared__ float scl[16];
  for (int q = t; q < 512; q += 256) {
    int c = q >> 4, px = q & 15;
    nz[c][px] = noise[((size_t)b*32 + c)*NPX + h*128 + w0 + px];
  }
  float hs = h*0.25f - 0.375f;
  float hf = floorf(hs);
  int h0 = (int)hf;
  float fh = hs - hf;
  int h0c = min(max(h0, 0), 31);
  int h1c = min(max(h0 + 1, 0), 31);
  __syncthreads();
  for (int q = t; q < 3584; q += 256) {
    int c = q >> 4, px = q & 15;
    int w = w0 + px;
    float wsrc = w*0.25f - 0.375f;
    float wf = floorf(wsrc);
    int W0 = (int)wf;
    float fw = wsrc - wf;
    int w0c = min(max(W0, 0), 31);
    int w1c = min(max(W0 + 1, 0), 31);
    const float* pb = pool + ((size_t)b*224 + c)*PPX;
    float v00 = pb[h0c*32 + w0c], v01 = pb[h0c*32 + w1c];
    float v10 = pb[h1c*32 + w0c], v11 = pb[h1c*32 + w1c];
    xa[c][px] = (1.0f - fh)*((1.0f - fw)*v00 + fw*v01) + fh*((1.0f - fw)*v10 + fw*v11);
    float np = 0.0f;
    #pragma unroll
    for (int j = 0; j < 32; ++j) np += sim_w[c*32 + j]*nz[j][px];
    nsc[c][px] = np;
  }
  __syncthreads();
  {
    int px = t >> 4, kk = t & 15;
    float s1 = 0, s2 = 0, s3 = 0;
    for (int c = kk; c < 224; c += 16) {
      float a = xa[c][px], p = nsc[c][px];
      s1 += a*a; s2 += p*p; s3 += a*p;
    }
    #pragma unroll
    for (int m = 1; m <= 8; m <<= 1) {
      s1 += __shfl_xor(s1, m);
      s2 += __shfl_xor(s2, m);
      s3 += __shfl_xor(s3, m);
    }
    if (kk == 0) {
      float n1 = fmaxf(sqrtf(s1), 1e-12f);
      float n2 = fmaxf(sqrtf(s2), 1e-12f);
      float sim = (s3/(n1*n2) + 1.0f)*0.5f;
      scl[px] = 1.0f - sim;
    }
  }
  __syncthreads();
  {
    float accp[16];
    #pragma unroll
    for (int px = 0; px < 16; ++px) accp[px] = 0.0f;
    for (int c = 0; c < 224; ++c) {
      float wv = owt[(size_t)c*256 + t];
      #pragma unroll
      for (int px = 0; px < 16; ++px) accp[px] += wv*xa[c][px];
    }
    size_t obase = ((size_t)b*256 + t)*NPX + (size_t)h*128 + w0;
    #pragma unroll
    for (int px = 0; px < 16; ++px) out[obase + px] = accp[px]*scl[px];
  }
  if (b == 0 && tt == 0 && t == 0) out[(size_t)33554432] = 8.0f;   // AVG_K
}

extern "C" void kernel_launch(void* const* d_in, const int* in_sizes, int n_in,
                              void* d_out, int out_size, void* d_ws, size_t ws_size,
                              hipStream_t stream) {
  (void)in_sizes; (void)n_in; (void)out_size; (void)ws_size;
  const float* x     = (const float*)d_in[0];
  const float* qkv_w = (const float*)d_in[1];
  const float* qkv_b = (const float*)d_in[2];
  const float* emb   = (const float*)d_in[3];
  const float* sim_w = (const float*)d_in[4];
  const float* out_w = (const float*)d_in[5];
  float* out = (float*)d_out;
  char* ws = (char*)d_ws;
  double* A    = (double*)(ws + OFF_A);
  double* QT   = (double*)(ws + OFF_QT);
  double* SG   = (double*)(ws + OFF_SG);
  double* QNT  = (double*)(ws + OFF_QN);
  double* d_a  = (double*)(ws + OFF_D);
  double* e_a  = (double*)(ws + OFF_E);
  double* tau_a= (double*)(ws + OFF_TAU);
  double* DW   = (double*)(ws + OFF_DW);
  int*    META = (int*)   (ws + OFF_META);
  double* Vg   = (double*)(ws + OFF_VG);
  double* Wg   = (double*)(ws + OFF_WG);
  float*  Vt   = (float*) (ws + OFF_VT);
  float*  xp   = (float*) (ws + OFF_XP);
  float*  qkvm = (float*) (ws + OFF_QKV);
  float*  pool = (float*) (ws + OFF_POOL);
  float*  owt  = (float*) (ws + OFF_OWT);
  float*  noise_out = out + 33554433;

  k_gram <<<dim3(8,8,8), 256, 0, stream>>>(x, A);   // gram written straight into A
  for (int p = 0; p < 8; ++p) {
    k_panel<<<dim3(8), 1024, 0, stream>>>(p, A, d_a, e_a, tau_a, Vg, Wg);
    if (p < 7) {
      int nt = 256 - 32*(p + 1);
      k_syr2k<<<dim3(nt/32, nt/32, 8), 256, 0, stream>>>(p, Vg, Wg, A);
    }
  }
  k_zeroq  <<<dim3(512),     256, 0, stream>>>(QT);
  k_leaves <<<dim3(8),       64,  0, stream>>>(d_a, e_a, QT, DW);
  {
    const int n1s[4]   = {16, 32, 64, 128};
    const int nmrgs[4] = {8, 4, 2, 1};
    for (int lv = 0; lv < 4; ++lv) {
      int n1 = n1s[lv], nmrg = nmrgs[lv], nn = 2*n1;
      k_mscan<<<dim3(nmrg, 8), 256, 0, stream>>>(n1, e_a, QT, DW, SG, META);
      k_mgemm<<<dim3(nn/32, (nn + 63)/64, nmrg*8), 256, 0, stream>>>(n1, nmrg, QT, SG, META, QNT);
      k_mperm<<<dim3(nmrg, 8), 256, 0, stream>>>(n1, QNT, META, QT);
    }
  }
  k_backxf <<<dim3(16,8),    256, 0, stream>>>(A, tau_a, QT, Vt);
  k_xproj  <<<dim3(32,8,8),  256, 0, stream>>>(x, Vt, xp, noise_out);
  k_qkv    <<<dim3(4,21,8),  256, 0, stream>>>(xp, qkv_w, qkv_b, qkvm);
  k_attn   <<<dim3(128,7,8), 256, 0, stream>>>(qkvm, emb, xp, pool);
  k_owt    <<<dim3(224),     256, 0, stream>>>(out_w, owt);
  k_final  <<<dim3(1024,8),  256, 0, stream>>>(pool, noise_out, sim_w, owt, out);
}

// Round 11
// 8412.766 us; speedup vs baseline: 1.2725x; 1.1138x over previous
//
#include <hip/hip_runtime.h>
#include <math.h>

#define NB  8
#define NPX 16384   // 128*128
#define PPX 1024    // 32*32
#define PNB 32      // dlatrd panel width

// f32 LAPACK machine constants (SLAMCH) used for branch tolerances
#define EPS32   5.9604644775390625e-8   // 2^-24 (slamch 'E')
#define EPS232  (EPS32*EPS32)
#define SAFMIN32 1.1754943508222875e-38

// ---------------- workspace layout (bytes), phase-aliased ----------------
static constexpr size_t OFF_VT   = 0;                    // f32 [8][256][256] 2MB (lives across phases)
static constexpr size_t U        = 0x200000;
static constexpr size_t OFF_A    = U + 0x400000;         // f64 [8][256][256] 4MB gram -> in-place tridiag / reflectors
static constexpr size_t OFF_QT   = U + 0x800000;         // f64 [8][256][256] 4MB QT[col][row]
static constexpr size_t OFF_SG   = U + 0xC00000;         // f64 [8][256][256] 4MB S scratch
static constexpr size_t OFF_QN   = U + 0x1000000;        // f64 [8][256][256] 4MB QNT scratch
static constexpr size_t OFF_D    = U + 0x1400000;        // f64 [8][256]
static constexpr size_t OFF_E    = U + 0x1404000;        // f64 [8][256]
static constexpr size_t OFF_TAU  = U + 0x1408000;        // f64 [8][256]
static constexpr size_t OFF_DW   = U + 0x140C000;        // f64 [8][256]
static constexpr size_t OFF_META = U + 0x1410000;        // int [8][8][520]
static constexpr size_t OFF_VG   = U + 0x1500000;        // f64 [8][256][32] 512KB panel V
static constexpr size_t OFF_WG   = U + 0x1580000;        // f64 [8][256][32] 512KB panel W
static constexpr size_t OFF_GP   = U + 0x1600000;        // f64 [16][256][256] 8MB gram k-split partials
// phase2 aliases (phase1 dead in order: GP after gsum, A/QT after backxf, SG/QN/META/VG/WG after merges):
static constexpr size_t OFF_XP   = U;                    // f32 [8][256][1024] 8MB
static constexpr size_t OFF_QKV  = U + 0x800000;         // f32 [8][672][1024] 21MB
static constexpr size_t OFF_POOL = U + 0x1D00000;        // f32 [8][224][1024] 7MB
static constexpr size_t OFF_OWT  = U + 0x2400000;        // f32 [224][256]

// ================= gram partials: 64x64 register-tiled f64, 2-way k-split =================
// grid (4,4,16): z = ks*8 + b. Thread (tx,ty) owns C[ty*4..+3][tx*4..+3] of the 64x64 tile.
// LDS tiles stored transposed [k][i] (f32) so per-k operand fetch = two float4 b128 reads.
__global__ __launch_bounds__(256) void k_gram(const float* __restrict__ x, double* __restrict__ GP) {
  int jt = blockIdx.x, it = blockIdx.y;
  int z = blockIdx.z;
  int ks = z >> 3, b = z & 7;
  const float* xb = x + (size_t)b*256*NPX;
  int t = threadIdx.x;
  int tx = t & 15, ty = t >> 4;
  __shared__ float xiT[64][65], xjT[64][65];
  double acc[4][4];
  #pragma unroll
  for (int i = 0; i < 4; ++i)
    #pragma unroll
    for (int j = 0; j < 4; ++j) acc[i][j] = 0.0;
  int kb = ks*8192;
  for (int k0 = 0; k0 < 8192; k0 += 64) {
    for (int q = t; q < 4096; q += 256) {
      int r = q >> 6, c = q & 63;
      xiT[c][r] = xb[(size_t)(it*64 + r)*NPX + kb + k0 + c];
      xjT[c][r] = xb[(size_t)(jt*64 + r)*NPX + kb + k0 + c];
    }
    __syncthreads();
    for (int k = 0; k < 64; ++k) {
      float4 af = *(const float4*)&xiT[k][ty*4];
      float4 bf = *(const float4*)&xjT[k][tx*4];
      double a0 = (double)af.x, a1 = (double)af.y, a2 = (double)af.z, a3 = (double)af.w;
      double b0 = (double)bf.x, b1 = (double)bf.y, b2 = (double)bf.z, b3 = (double)bf.w;
      acc[0][0] += a0*b0; acc[0][1] += a0*b1; acc[0][2] += a0*b2; acc[0][3] += a0*b3;
      acc[1][0] += a1*b0; acc[1][1] += a1*b1; acc[1][2] += a1*b2; acc[1][3] += a1*b3;
      acc[2][0] += a2*b0; acc[2][1] += a2*b1; acc[2][2] += a2*b2; acc[2][3] += a2*b3;
      acc[3][0] += a3*b0; acc[3][1] += a3*b1; acc[3][2] += a3*b2; acc[3][3] += a3*b3;
    }
    __syncthreads();
  }
  double* gp = GP + (size_t)z*65536;
  #pragma unroll
  for (int ii = 0; ii < 4; ++ii)
    #pragma unroll
    for (int jj = 0; jj < 4; ++jj)
      gp[(size_t)(it*64 + ty*4 + ii)*256 + jt*64 + tx*4 + jj] = acc[ii][jj];
}

// A = GP[0..7] + GP[8..15]  (sum the two k-halves)
__global__ __launch_bounds__(256) void k_gsum(const double* __restrict__ GP, double* __restrict__ A) {
  size_t i = (size_t)blockIdx.x*256 + threadIdx.x;
  size_t total = (size_t)NB*65536;
  for (; i < total; i += (size_t)gridDim.x*256)
    A[i] = GP[i] + GP[i + total];
}

__device__ __forceinline__ double blkSum16(double v, double* tmp, int t, int nw) {
  #pragma unroll
  for (int m = 1; m <= 32; m <<= 1) v += __shfl_xor(v, m);
  __syncthreads();
  if ((t & 63) == 0) tmp[t >> 6] = v;
  __syncthreads();
  double s = 0.0;
  for (int w = 0; w < nw; ++w) s += tmp[w];
  return s;
}

// ================= blocked tridiagonalization: dlatrd-style panel (nb=32) =================
__global__ __launch_bounds__(1024) void k_panel(int p, double* __restrict__ A,
        double* __restrict__ d_g, double* __restrict__ e_g, double* __restrict__ tau_g,
        double* __restrict__ Vg, double* __restrict__ Wg) {
  int b = blockIdx.x, t = threadIdx.x;
  int g = t >> 8, c = t & 255;
  double* Ab = A + (size_t)b*65536;
  __shared__ double V[256][33], W[256][33];
  __shared__ double vL[256], wL[256], rowCur[256];
  __shared__ double wpart[4][256];
  __shared__ double c12[64];
  __shared__ double tmp[16];
  int jmax = (p == 7) ? 31 : 32;
  for (int j = 0; j < jmax; ++j) {
    int i = p*PNB + j;
    if (g == 0) {
      double rv = 0.0;
      if (c >= i) {
        rv = Ab[(size_t)i*256 + c];
        for (int k = 0; k < j; ++k)
          rv -= V[i][k]*W[c][k] + W[i][k]*V[c][k];
      }
      rowCur[c] = rv;
    }
    __syncthreads();
    double part = 0.0;
    int rx = i + 2 + t;
    if (rx < 256) { double v = rowCur[rx]; part = v*v; }
    double xn2 = blkSum16(part, tmp, t, 16);
    double alpha = rowCur[i + 1];
    double beta, tauv, scale;
    if (xn2 == 0.0) { beta = alpha; tauv = 0.0; scale = 0.0; }
    else {
      beta  = -copysign(sqrt(alpha*alpha + xn2), alpha);
      tauv  = (beta - alpha)/beta;
      scale = 1.0/(alpha - beta);
    }
    if (t == 0) { e_g[b*256 + i] = beta; tau_g[b*256 + i] = tauv; d_g[b*256 + i] = rowCur[i]; }
    if (g == 0) {
      double v = 0.0;
      if (c == i + 1) v = 1.0;
      else if (c >= i + 2) v = rowCur[c]*scale;
      vL[c] = v;
      V[c][j] = v;
      if (c >= i + 1) Ab[(size_t)i*256 + c] = v;
    }
    __syncthreads();
    {
      double s = 0.0;
      if (c >= i + 1) {
        for (int r = i + 1 + g; r < 256; r += 4) s += Ab[(size_t)r*256 + c]*vL[r];
      }
      wpart[g][c] = s;
    }
    {
      int kk = t >> 5, lane = t & 31;
      if (kk < j) {
        double s = 0.0;
        for (int ci2 = lane; ci2 < 256; ci2 += 32) s += W[ci2][kk]*vL[ci2];
        s += __shfl_xor(s, 1); s += __shfl_xor(s, 2); s += __shfl_xor(s, 4);
        s += __shfl_xor(s, 8); s += __shfl_xor(s, 16);
        if (lane == 0) c12[kk] = s;
        double s2 = 0.0;
        for (int ci2 = lane; ci2 < 256; ci2 += 32) s2 += V[ci2][kk]*vL[ci2];
        s2 += __shfl_xor(s2, 1); s2 += __shfl_xor(s2, 2); s2 += __shfl_xor(s2, 4);
        s2 += __shfl_xor(s2, 8); s2 += __shfl_xor(s2, 16);
        if (lane == 0) c12[32 + kk] = s2;
      }
    }
    __syncthreads();
    double wfull = 0.0, part2 = 0.0;
    if (g == 0 && c >= i + 1) {
      double wr = wpart[0][c] + wpart[1][c] + wpart[2][c] + wpart[3][c];
      for (int k = 0; k < j; ++k) wr -= V[c][k]*c12[k] + W[c][k]*c12[32 + k];
      wfull = tauv*wr;
      part2 = vL[c]*wfull;
    }
    double dot = blkSum16(part2, tmp, t, 16);
    double coef = -0.5*tauv*dot;
    if (g == 0) {
      double wv2 = (c >= i + 1) ? (wfull + coef*vL[c]) : 0.0;
      wL[c] = wv2;
      W[c][j] = wv2;
    }
    __syncthreads();
  }
  if (p < 7) {
    for (int idx = t; idx < 256*32; idx += 1024) {
      int cc = idx >> 5, kk = idx & 31;
      Vg[((size_t)b*256 + cc)*32 + kk] = V[cc][kk];
      Wg[((size_t)b*256 + cc)*32 + kk] = W[cc][kk];
    }
  } else {
    if (t == 0) {
      double dv = Ab[(size_t)255*256 + 255];
      for (int k = 0; k < 31; ++k) dv -= 2.0*V[255][k]*W[255][k];
      d_g[b*256 + 255] = dv;
      e_g[b*256 + 255] = 0.0;
    }
  }
}

// ================= trailing update: A -= V W^T + W V^T on rows/cols >= 32(p+1) =================
__global__ __launch_bounds__(256) void k_syr2k(int p, const double* __restrict__ Vg,
        const double* __restrict__ Wg, double* __restrict__ A) {
  int rt = blockIdx.x, ct = blockIdx.y, b = blockIdx.z;
  int base = (p + 1)*32;
  int r0 = base + rt*32, c0 = base + ct*32;
  int t = threadIdx.x;
  __shared__ double Vr[32][33], Wr[32][33], Vc[32][33], Wc[32][33];
  for (int idx = t; idx < 1024; idx += 256) {
    int rr = idx >> 5, kk = idx & 31;
    Vr[rr][kk] = Vg[((size_t)b*256 + r0 + rr)*32 + kk];
    Wr[rr][kk] = Wg[((size_t)b*256 + r0 + rr)*32 + kk];
    Vc[rr][kk] = Vg[((size_t)b*256 + c0 + rr)*32 + kk];
    Wc[rr][kk] = Wg[((size_t)b*256 + c0 + rr)*32 + kk];
  }
  __syncthreads();
  int cl = t & 31, rg = t >> 5;
  double* Ab = A + (size_t)b*65536;
  #pragma unroll
  for (int q = 0; q < 4; ++q) {
    int rl = rg + 8*q;
    double acc = Ab[(size_t)(r0 + rl)*256 + c0 + cl];
    #pragma unroll
    for (int k = 0; k < 32; ++k)
      acc -= Vr[rl][k]*Wc[cl][k] + Wr[rl][k]*Vc[cl][k];
    Ab[(size_t)(r0 + rl)*256 + c0 + cl] = acc;
  }
}

// ================= LAPACK helpers =================
__device__ __forceinline__ void dlartg_(double f, double g, double& c, double& s, double& r) {
  if (g == 0.0) { c = 1.0; s = 0.0; r = f; }
  else if (f == 0.0) { c = 0.0; s = (g > 0.0) ? 1.0 : -1.0; r = fabs(g); }
  else {
    double d = sqrt(f*f + g*g);
    r = (f >= 0.0) ? d : -d;
    c = f / r;
    s = g / r;
  }
}

__device__ void dlaev2_(double a, double b, double cc, double& rt1, double& rt2, double& cs1, double& sn1) {
  double sm = a + cc, df = a - cc;
  double adf = fabs(df), tb = b + b, ab = fabs(tb);
  double acmx, acmn;
  if (fabs(a) > fabs(cc)) { acmx = a; acmn = cc; } else { acmx = cc; acmn = a; }
  double rt;
  if (adf > ab)      rt = adf*sqrt(1.0 + (ab/adf)*(ab/adf));
  else if (adf < ab) rt = ab*sqrt(1.0 + (adf/ab)*(adf/ab));
  else               rt = ab*sqrt(2.0);
  int sgn1;
  if (sm < 0.0)      { rt1 = 0.5*(sm - rt); sgn1 = -1; rt2 = (acmx/rt1)*acmn - (b/rt1)*b; }
  else if (sm > 0.0) { rt1 = 0.5*(sm + rt); sgn1 = 1;  rt2 = (acmx/rt1)*acmn - (b/rt1)*b; }
  else               { rt1 = 0.5*rt; rt2 = -0.5*rt; sgn1 = 1; }
  double cs; int sgn2;
  if (df >= 0.0) { cs = df + rt; sgn2 = 1; } else { cs = df - rt; sgn2 = -1; }
  double acs = fabs(cs);
  if (acs > ab) {
    double ct = -tb/cs;
    sn1 = 1.0/sqrt(1.0 + ct*ct);
    cs1 = ct*sn1;
  } else {
    if (ab == 0.0) { cs1 = 1.0; sn1 = 0.0; }
    else {
      double tn = -cs/tb;
      cs1 = 1.0/sqrt(1.0 + tn*tn);
      sn1 = tn*cs1;
    }
  }
  if (sgn1 == sgn2) { double tn = cs1; cs1 = -sn1; sn1 = tn; }
}

// faithful dsteqr('I') on an n<=16 block, f64 arithmetic with f32 tolerances
__device__ void steqr_leaf(int n, double* d, double* e, double* q, int ldq) {
  const double eps = EPS32, eps2 = EPS232, safmin = SAFMIN32;
  int nmaxit = n*30, jtot = 0;
  int l1 = 0;
  while (l1 < n) {
    if (l1 > 0) e[l1-1] = 0.0;
    int m;
    for (m = l1; m < n-1; ++m) {
      double tst = fabs(e[m]);
      if (tst == 0.0) break;
      if (tst <= (sqrt(fabs(d[m]))*sqrt(fabs(d[m+1])))*eps) { e[m] = 0.0; break; }
    }
    int l = l1, lend = m;
    l1 = m + 1;
    if (lend == l) continue;
    if (fabs(d[lend]) < fabs(d[l])) { int tsw = l; l = lend; lend = tsw; }
    if (lend > l) {
      while (true) {
        int mm;
        for (mm = l; mm < lend; ++mm) {
          double tst = e[mm]*e[mm];
          if (tst <= (eps2*fabs(d[mm]))*fabs(d[mm+1]) + safmin) break;
        }
        if (mm < lend) e[mm] = 0.0;
        double p = d[l];
        if (mm == l) { l = l + 1; if (l > lend) break; continue; }
        if (mm == l+1) {
          double rt1, rt2, c, s;
          dlaev2_(d[l], e[l], d[l+1], rt1, rt2, c, s);
          for (int i = 0; i < n; ++i) {
            double t1 = q[i*ldq + l+1], t0 = q[i*ldq + l];
            q[i*ldq + l+1] = c*t1 - s*t0;
            q[i*ldq + l]   = s*t1 + c*t0;
          }
          d[l] = rt1; d[l+1] = rt2; e[l] = 0.0;
          l += 2; if (l > lend) break; continue;
        }
        if (jtot == nmaxit) break;
        jtot++;
        double g = (d[l+1] - p)/(2.0*e[l]);
        double r = sqrt(g*g + 1.0);
        g = d[mm] - p + e[l]/(g + copysign(r, g));
        double s = 1.0, c = 1.0; p = 0.0;
        double csv[16], snv[16];
        for (int i = mm-1; i >= l; --i) {
          double f = s*e[i], bb = c*e[i];
          dlartg_(g, f, c, s, r);
          if (i != mm-1) e[i+1] = r;
          g = d[i+1] - p;
          r = (d[i] - g)*s + 2.0*c*bb;
          p = s*r;
          d[i+1] = g + p;
          g = c*r - bb;
          csv[i] = c; snv[i] = -s;
        }
        for (int i = mm-1; i >= l; --i) {
          double cc2 = csv[i], ss2 = snv[i];
          for (int k = 0; k < n; ++k) {
            double t1 = q[k*ldq + i+1], t0 = q[k*ldq + i];
            q[k*ldq + i+1] = cc2*t1 - ss2*t0;
            q[k*ldq + i]   = ss2*t1 + cc2*t0;
          }
        }
        d[l] -= p; e[l] = g;
      }
    } else {
      while (true) {
        int mm;
        for (mm = l; mm > lend; --mm) {
          double tst = e[mm-1]*e[mm-1];
          if (tst <= (eps2*fabs(d[mm]))*fabs(d[mm-1]) + safmin) break;
        }
        if (mm > lend) e[mm-1] = 0.0;
        double p = d[l];
        if (mm == l) { l = l - 1; if (l < lend) break; continue; }
        if (mm == l-1) {
          double rt1, rt2, c, s;
          dlaev2_(d[l-1], e[l-1], d[l], rt1, rt2, c, s);
          for (int i = 0; i < n; ++i) {
            double t1 = q[i*ldq + l], t0 = q[i*ldq + l-1];
            q[i*ldq + l]   = c*t1 - s*t0;
            q[i*ldq + l-1] = s*t1 + c*t0;
          }
          d[l-1] = rt1; d[l] = rt2; e[l-1] = 0.0;
          l -= 2; if (l < lend) break; continue;
        }
        if (jtot == nmaxit) break;
        jtot++;
        double g = (d[l-1] - p)/(2.0*e[l-1]);
        double r = sqrt(g*g + 1.0);
        g = d[mm] - p + e[l-1]/(g + copysign(r, g));
        double s = 1.0, c = 1.0; p = 0.0;
        double csv[16], snv[16];
        for (int i = mm; i <= l-1; ++i) {
          double f = s*e[i], bb = c*e[i];
          dlartg_(g, f, c, s, r);
          if (i != mm) e[i-1] = r;
          g = d[i] - p;
          r = (d[i+1] - g)*s + 2.0*c*bb;
          p = s*r;
          d[i] = g + p;
          g = c*r - bb;
          csv[i] = c; snv[i] = s;
        }
        for (int i = mm; i <= l-1; ++i) {
          double cc2 = csv[i], ss2 = snv[i];
          for (int k = 0; k < n; ++k) {
            double t1 = q[k*ldq + i+1], t0 = q[k*ldq + i];
            q[k*ldq + i+1] = cc2*t1 - ss2*t0;
            q[k*ldq + i]   = ss2*t1 + cc2*t0;
          }
        }
        d[l] -= p; e[l-1] = g;
      }
    }
  }
  for (int ii = 1; ii < n; ++ii) {
    int k = ii - 1; double p = d[k];
    for (int j = ii; j < n; ++j) if (d[j] < p) { k = j; p = d[j]; }
    if (k != ii-1) {
      d[k] = d[ii-1]; d[ii-1] = p;
      for (int r = 0; r < n; ++r) { double tq = q[r*ldq + ii-1]; q[r*ldq + ii-1] = q[r*ldq + k]; q[r*ldq + k] = tq; }
    }
  }
}

__global__ __launch_bounds__(256) void k_zeroq(double* __restrict__ QT) {
  size_t i = (size_t)blockIdx.x*256 + threadIdx.x;
  size_t total = (size_t)NB*65536;
  for (; i < total; i += (size_t)gridDim.x*256) QT[i] = 0.0;
}

// ================= leaves: tears + 16x ssteqr(16), write TRANSPOSED =================
__global__ __launch_bounds__(64) void k_leaves(const double* __restrict__ d_g, const double* __restrict__ e_g,
        double* __restrict__ QT, double* __restrict__ DW) {
  int b = blockIdx.x, t = threadIdx.x;
  __shared__ double dL[256], eL[256];
  __shared__ double ql[16*272];
  for (int i = t; i < 256; i += 64) { dL[i] = d_g[b*256 + i]; eL[i] = e_g[b*256 + i]; }
  __syncthreads();
  if (t == 0) {
    for (int cut = 16; cut < 256; cut += 16) {
      double a = fabs(eL[cut-1]);
      dL[cut-1] -= a; dL[cut] -= a;
    }
  }
  __syncthreads();
  if (t < 16) {
    double* q = &ql[t*272];
    for (int i = 0; i < 16; ++i)
      for (int j = 0; j < 16; ++j) q[i*17 + j] = (i == j) ? 1.0 : 0.0;
    steqr_leaf(16, dL + 16*t, eL + 16*t, q, 17);
  }
  __syncthreads();
  for (int idx = t; idx < 4096; idx += 64) {
    int lf = idx >> 8, i = (idx >> 4) & 15, j = idx & 15;
    QT[(size_t)b*65536 + (size_t)(lf*16 + j)*256 + lf*16 + i] = ql[lf*272 + i*17 + j];
  }
  for (int i = t; i < 256; i += 64) DW[b*256 + i] = dL[i];
}

// ================= merge phase 1: scan + rotations + secular + S =================
__global__ __launch_bounds__(256) void k_mscan(int n1, const double* __restrict__ e_g,
        double* __restrict__ QT, double* __restrict__ DW, double* __restrict__ SG, int* __restrict__ META) {
  int mrg = blockIdx.x, b = blockIdx.y, t = threadIdx.x;
  int nn = 2*n1, r0 = mrg*nn;
  double* Q = QT + (size_t)b*65536;
  double* Sg = SG + (size_t)b*65536;
  int* meta = META + ((b*8 + mrg)*520);
  __shared__ double dloc[256], zloc[256], dlam[256], wv[256], w2[256], tauv[256], zh[256], dfin[256];
  __shared__ int indx[256], indxp[256], permf[256];
  __shared__ double rotc[256], rots[256];
  __shared__ short rotp[256], rotq[256];
  __shared__ int KK[3];
  __shared__ double sc[2];
  double rho_raw = e_g[b*256 + r0 + n1 - 1];
  if (t < nn) {
    dloc[t] = DW[b*256 + r0 + t];
    double zv = Q[(size_t)(r0 + t)*256 + r0 + ((t < n1) ? (n1 - 1) : n1)];
    if (t >= n1 && rho_raw < 0.0) zv = -zv;
    zloc[t] = zv * 0.70710678118654752440;
  }
  __syncthreads();
  if (t == 0) {
    int i = 0, jj = n1, pos = 0;
    while (i < n1 && jj < nn) { if (dloc[i] <= dloc[jj]) indx[pos++] = i++; else indx[pos++] = jj++; }
    while (i < n1) indx[pos++] = i++;
    while (jj < nn) indx[pos++] = jj++;
    double maxd = 0.0, maxz = 0.0;
    for (int q2 = 0; q2 < nn; ++q2) { maxd = fmax(maxd, fabs(dloc[q2])); maxz = fmax(maxz, fabs(zloc[q2])); }
    double rho = fabs(2.0*rho_raw);
    double tol = 8.0*EPS32*fmax(maxd, maxz);
    int K = 0, K2 = nn, nrot = 0, pj = -1, j = 0;
    for (; j < nn; ++j) {
      int nj = indx[j];
      if (rho*fabs(zloc[nj]) <= tol) { K2--; indxp[K2] = nj; }
      else { pj = nj; break; }
    }
    if (pj >= 0) {
      for (++j; j < nn; ++j) {
        int nj = indx[j];
        if (rho*fabs(zloc[nj]) <= tol) { K2--; indxp[K2] = nj; }
        else {
          double s = zloc[pj], c = zloc[nj];
          double tau = sqrt(c*c + s*s);
          double tdf = dloc[nj] - dloc[pj];
          c /= tau; s = -s/tau;
          if (fabs(tdf*c*s) <= tol) {
            zloc[nj] = tau; zloc[pj] = 0.0;
            rotp[nrot] = (short)pj; rotq[nrot] = (short)nj; rotc[nrot] = c; rots[nrot] = s; nrot++;
            double tt2 = dloc[pj]*c*c + dloc[nj]*s*s;
            dloc[nj] = dloc[pj]*s*s + dloc[nj]*c*c;
            dloc[pj] = tt2;
            K2--;
            int ii2 = 1;
            while (K2 + ii2 <= nn - 1 && dloc[pj] < dloc[indxp[K2 + ii2]]) { indxp[K2+ii2-1] = indxp[K2+ii2]; ii2++; }
            indxp[K2+ii2-1] = pj;
            pj = nj;
          } else {
            dlam[K] = dloc[pj]; wv[K] = zloc[pj]; indxp[K] = pj; K++;
            pj = nj;
          }
        }
      }
      dlam[K] = dloc[pj]; wv[K] = zloc[pj]; indxp[K] = pj; K++;
    }
    double sumw2 = 0.0;
    for (int q2 = 0; q2 < K; ++q2) sumw2 += wv[q2]*wv[q2];
    KK[0] = K; KK[1] = K2; KK[2] = nrot; sc[0] = rho; sc[1] = sumw2;
  }
  __syncthreads();
  int K = KK[0], K2 = KK[1], nrot = KK[2];
  double rho = sc[0], sumw2 = sc[1];
  if (t < nn) {
    for (int k = 0; k < nrot; ++k) {
      int p = rotp[k], q = rotq[k];
      double c = rotc[k], s = rots[k];
      size_t ip = (size_t)(r0 + p)*256 + r0 + t;
      size_t iq = (size_t)(r0 + q)*256 + r0 + t;
      double xq = Q[ip], yq = Q[iq];
      Q[ip] = c*xq + s*yq;
      Q[iq] = c*yq - s*xq;
    }
  }
  if (t < K) w2[t] = rho*wv[t]*wv[t];
  __syncthreads();
  if (t < K) {
    double dj = dlam[t];
    double hi0 = (t < K-1) ? (dlam[t+1] - dj) : rho*sumw2;
    double lo = 0.0, hi = hi0;
    for (int it = 0; it < 64; ++it) {
      double mid = 0.5*(lo + hi);
      double f = 1.0;
      for (int j2 = 0; j2 < K; ++j2) f += w2[j2]/((dlam[j2] - dj) - mid);
      if (f < 0.0) lo = mid; else hi = mid;
    }
    double tl = 0.5*(lo + hi);
    if (tl <= 0.0) tl = hi0*1e-300;
    tauv[t] = tl;
  }
  __syncthreads();
  if (t < K) {
    double dt2 = dlam[t], p = tauv[t];
    for (int i = 0; i < K; ++i) { if (i == t) continue; double del = dlam[i] - dt2; p *= (del + tauv[i])/del; }
    zh[t] = copysign(sqrt(fabs(p)), wv[t]);
  }
  __syncthreads();
  if (t < K) {
    double dj = dlam[t], tj = tauv[t];
    double nrm = 0.0;
    for (int i = 0; i < K; ++i) { double sij = zh[i]/((dlam[i] - dj) - tj); nrm += sij*sij; }
    double inv = 1.0/sqrt(nrm);
    for (int i = 0; i < K; ++i) Sg[(size_t)(r0 + i)*256 + t] = (zh[i]/((dlam[i] - dj) - tj))*inv;
  }
  __syncthreads();
  if (t == 0) {
    int i = 0, p = nn - 1, f = 0;
    while (f < nn) {
      bool takesec;
      if (i < K && p >= K2) takesec = ((dlam[i] + tauv[i]) <= dloc[indxp[p]]);
      else takesec = (i < K);
      if (takesec) { dfin[f] = dlam[i] + tauv[i]; permf[f] = i; i++; }
      else         { dfin[f] = dloc[indxp[p]];    permf[f] = K + (p - K2); p--; }
      f++;
    }
    for (f = 0; f < nn; ++f) DW[b*256 + r0 + f] = dfin[f];
    meta[0] = K; meta[1] = K2;
  }
  __syncthreads();
  if (t < nn) { meta[2 + t] = indxp[t]; meta[258 + t] = permf[t]; }
}

// ================= merge phase 2 =================
__global__ __launch_bounds__(256) void k_mgemm(int n1, int nmrg, const double* __restrict__ QT,
        const double* __restrict__ SG, const int* __restrict__ META, double* __restrict__ QNT) {
  int nn = 2*n1;
  int jt = blockIdx.x, rt = blockIdx.y;
  int z = blockIdx.z;
  int mrg = z % nmrg, b = z / nmrg;
  int r0 = mrg*nn;
  int t = threadIdx.x;
  const int* meta = META + ((b*8 + mrg)*520);
  __shared__ int sindxp[256];
  __shared__ double Gs[32][66];
  __shared__ double Ss[32][33];
  const double* Q = QT + (size_t)b*65536;
  const double* Sg = SG + (size_t)b*65536;
  double* Qn = QNT + (size_t)b*65536;
  int K = meta[0], K2 = meta[1];
  if (t < nn) sindxp[t] = meta[2 + t];
  __syncthreads();
  int jl = t >> 6, rl = t & 63;
  int r = rt*64 + rl;
  double acc[8];
  #pragma unroll
  for (int q = 0; q < 8; ++q) acc[q] = 0.0;
  if (jt*32 < K) {
    for (int i0 = 0; i0 < K; i0 += 32) {
      #pragma unroll
      for (int w = 0; w < 8; ++w) {
        int idx = t + 256*w;
        int ii = idx >> 6, rr = idx & 63;
        double v = 0.0;
        if (i0 + ii < K && rt*64 + rr < nn)
          v = Q[(size_t)(r0 + sindxp[i0 + ii])*256 + r0 + rt*64 + rr];
        Gs[ii][rr] = v;
      }
      #pragma unroll
      for (int w = 0; w < 4; ++w) {
        int idx = t + 256*w;
        int ii2 = idx >> 5, jj = idx & 31;
        double v = 0.0;
        if (i0 + ii2 < K)
          v = Sg[(size_t)(r0 + i0 + ii2)*256 + jt*32 + jj];
        Ss[ii2][jj] = v;
      }
      __syncthreads();
      int kmax = (K - i0 < 32) ? (K - i0) : 32;
      for (int ii = 0; ii < kmax; ++ii) {
        double gv = Gs[ii][rl];
        #pragma unroll
        for (int q = 0; q < 8; ++q) acc[q] += Ss[ii][jl + 4*q] * gv;
      }
      __syncthreads();
    }
  }
  if (r < nn) {
    #pragma unroll
    for (int q = 0; q < 8; ++q) {
      int j = jt*32 + jl + 4*q;
      if (j < K) Qn[(size_t)(r0 + j)*256 + r0 + r] = acc[q];
      else if (j < nn) {
        int p = K2 + (j - K);
        Qn[(size_t)(r0 + j)*256 + r0 + r] = Q[(size_t)(r0 + sindxp[p])*256 + r0 + r];
      }
    }
  }
}

// ================= merge phase 3 =================
__global__ __launch_bounds__(256) void k_mperm(int n1, const double* __restrict__ QNT,
        const int* __restrict__ META, double* __restrict__ QT) {
  int mrg = blockIdx.x, b = blockIdx.y, t = threadIdx.x;
  int nn = 2*n1, r0 = mrg*nn;
  const int* meta = META + ((b*8 + mrg)*520);
  __shared__ int pf[256];
  if (t < nn) pf[t] = meta[258 + t];
  __syncthreads();
  if (t < nn) {
    for (int f = 0; f < nn; ++f)
      QT[(size_t)b*65536 + (size_t)(r0 + f)*256 + r0 + t] =
        QNT[(size_t)b*65536 + (size_t)(r0 + pf[f])*256 + r0 + t];
  }
}

// ================= back-transform, LDS-tiled: emit Vt (f32) directly =================
__global__ __launch_bounds__(256) void k_backxf(const double* __restrict__ A, const double* __restrict__ tau_g,
        const double* __restrict__ QT, float* __restrict__ Vt) {
  int g = blockIdx.x, b = blockIdx.y;
  int t = threadIdx.x;
  int e = t >> 4, l = t & 15;
  __shared__ double zt[16][264];
  __shared__ double vL[256];
  __shared__ double tauL[256];
  const double* Ab = A + (size_t)b*65536;
  const double* Qb = QT + (size_t)b*65536 + (size_t)g*16*256;
  #pragma unroll
  for (int w = 0; w < 16; ++w) {
    int idx = t + 256*w;
    int ee = idx >> 8, rr = idx & 255;
    zt[ee][rr] = Qb[(size_t)ee*256 + rr];
  }
  tauL[t] = tau_g[b*256 + t];
  __syncthreads();
  for (int s = 253; s >= 0; --s) {
    if (t == 0) vL[s+1] = 1.0;
    int rx = s + 2 + t;
    if (rx < 256) vL[rx] = Ab[s*256 + rx];
    __syncthreads();
    double tauv = tauL[s];
    if (tauv != 0.0) {
      double acc = 0.0;
      for (int rr = s + 1 + l; rr < 256; rr += 16) acc += vL[rr]*zt[e][rr];
      acc += __shfl_xor(acc, 1);
      acc += __shfl_xor(acc, 2);
      acc += __shfl_xor(acc, 4);
      acc += __shfl_xor(acc, 8);
      double tw = tauv*acc;
      for (int rr = s + 1 + l; rr < 256; rr += 16) zt[e][rr] -= tw*vL[rr];
    }
    __syncthreads();
  }
  float* vtb = Vt + ((size_t)b*256 + (size_t)g*16)*256;
  #pragma unroll
  for (int w = 0; w < 16; ++w) {
    int idx = t + 256*w;
    int ee = idx >> 8, rr = idx & 255;
    vtb[(size_t)ee*256 + rr] = (float)zt[ee][rr];
  }
}

// ================= x_proj = V x, + x, fused maxpool + noise output =================
__global__ __launch_bounds__(256) void k_xproj(const float* __restrict__ x, const float* __restrict__ Vt,
        float* __restrict__ xp, float* __restrict__ noise_out) {
  int R = blockIdx.x, ct = blockIdx.y, b = blockIdx.z;
  int t = threadIdx.x;
  int cl = t >> 3, l8 = t & 7;
  __shared__ float vsh[32][20];
  __shared__ float xs[16][520];
  const float* xb = x + (size_t)b*256*NPX;
  int s0 = R*512;
  float acc[64];
  #pragma unroll
  for (int p = 0; p < 64; ++p) acc[p] = 0.0f;
  for (int d0 = 0; d0 < 256; d0 += 16) {
    for (int q = t; q < 512; q += 256) {
      int c = q >> 4, dd = q & 15;
      vsh[c][dd] = Vt[((size_t)b*256 + ct*32 + c)*256 + d0 + dd];
    }
    for (int q = t; q < 8192; q += 256) {
      int dd = q >> 9, px = q & 511;
      xs[dd][px] = xb[(size_t)(d0 + dd)*NPX + s0 + px];
    }
    __syncthreads();
    for (int dd = 0; dd < 16; ++dd) {
      float a = vsh[cl][dd];
      const float* xr = &xs[dd][l8];
      #pragma unroll
      for (int p = 0; p < 64; ++p) acc[p] += a*xr[8*p];
    }
    __syncthreads();
  }
  int cg = ct*32 + cl;
  const float* xc = xb + (size_t)cg*NPX + s0;
  float vmax[16];
  #pragma unroll
  for (int j = 0; j < 16; ++j) vmax[j] = -3.0e38f;
  bool isnz = (ct == 0);
  #pragma unroll
  for (int p = 0; p < 64; ++p) {
    int px = l8 + 8*p;
    float val = acc[p] + xc[px];
    vmax[p & 15] = fmaxf(vmax[p & 15], val);
    if (isnz) noise_out[((size_t)b*32 + cl)*NPX + s0 + px] = val;
  }
  #pragma unroll
  for (int j = 0; j < 16; ++j) {
    float v = vmax[j];
    v = fmaxf(v, __shfl_xor(v, 1));
    v = fmaxf(v, __shfl_xor(v, 2));
    vmax[j] = v;
  }
  if ((l8 & 3) == 0) {
    int halfsel = l8 >> 2;
    #pragma unroll
    for (int j = 0; j < 16; ++j)
      xp[((size_t)b*256 + cg)*PPX + R*32 + 2*j + halfsel] = vmax[j];
  }
}

// ================= qkv 1x1 conv (672 needed rows) =================
__global__ __launch_bounds__(256) void k_qkv(const float* __restrict__ xp, const float* __restrict__ wq,
        const float* __restrict__ bq, float* __restrict__ qkvm) {
  int pt = blockIdx.x, ot = blockIdx.y, b = blockIdx.z;
  int t = threadIdx.x;
  int ol = t & 31, pg = t >> 5;
  __shared__ float wsh[32][9];
  __shared__ float xsh[8][260];
  float acc[32];
  #pragma unroll
  for (int j = 0; j < 32; ++j) acc[j] = 0.0f;
  for (int ic0 = 0; ic0 < 256; ic0 += 8) {
    {
      int o = t >> 3, j = t & 7;
      int orow = ot*32 + o;
      int reg = orow/224, rem = orow - reg*224;
      int wrow = 32 + rem + 256*reg;
      wsh[o][j] = wq[(size_t)wrow*256 + ic0 + j];
    }
    for (int q = t; q < 2048; q += 256) {
      int ic = q >> 8, px = q & 255;
      xsh[ic][px] = xp[((size_t)b*256 + ic0 + ic)*PPX + pt*256 + px];
    }
    __syncthreads();
    for (int ic = 0; ic < 8; ++ic) {
      float a = wsh[ol][ic];
      const float* xr = &xsh[ic][pg];
      #pragma unroll
      for (int j = 0; j < 32; ++j) acc[j] += a*xr[8*j];
    }
    __syncthreads();
  }
  int orow = ot*32 + ol;
  int reg = orow/224, rem = orow - reg*224;
  float bv = bq[32 + rem + 256*reg];
  #pragma unroll
  for (int j = 0; j < 32; ++j)
    qkvm[((size_t)b*672 + orow)*PPX + pt*256 + pg + 8*j] = acc[j] + bv;
}

// ================= attention =================
__global__ __launch_bounds__(256) void k_attn(const float* __restrict__ qkvm, const float* __restrict__ emb,
        const float* __restrict__ xp, float* __restrict__ pool) {
  int rt = blockIdx.x, n = blockIdx.y, b = blockIdx.z;
  int t = threadIdx.x;
  int rl = t >> 5, pg = t & 31;
  __shared__ float S[8][1032];
  __shared__ float qsh[8][33];
  __shared__ float kv[4224];
  const float* qb = qkvm + (size_t)b*672*PPX;
  int rg0 = rt*8;
  {
    int rg = rg0 + rl;
    float qv = qb[(size_t)(32*n + (rg >> 5))*PPX + ((rg & 31) << 5) + pg];
    float ev = emb[(((size_t)n*8 + b)*1024 + rg)*32 + pg];
    qsh[rl][pg] = (qv + ev)*0.17677669529663688f;
  }
  __syncthreads();
  const float* kb = qb + (size_t)(224 + 32*n)*PPX;
  for (int p0 = 0; p0 < 1024; p0 += 128) {
    for (int q = t; q < 4096; q += 256) {
      int c = q >> 7, pp = q & 127;
      kv[c*132 + pp] = kb[(size_t)c*PPX + p0 + pp];
    }
    __syncthreads();
    float a0 = 0, a1 = 0, a2 = 0, a3 = 0;
    for (int c = 0; c < 32; ++c) {
      float qv = qsh[rl][c];
      const float* kr = &kv[c*132 + pg];
      a0 += qv*kr[0]; a1 += qv*kr[32]; a2 += qv*kr[64]; a3 += qv*kr[96];
    }
    S[rl][p0 + pg]      = a0;
    S[rl][p0 + pg + 32] = a1;
    S[rl][p0 + pg + 64] = a2;
    S[rl][p0 + pg + 96] = a3;
    __syncthreads();
  }
  float mx = -3.0e38f;
  for (int j = 0; j < 32; ++j) mx = fmaxf(mx, S[rl][pg + 32*j]);
  #pragma unroll
  for (int m = 1; m <= 16; m <<= 1) mx = fmaxf(mx, __shfl_xor(mx, m));
  float sum = 0.0f;
  for (int j = 0; j < 32; ++j) {
    float e = expf(S[rl][pg + 32*j] - mx);
    S[rl][pg + 32*j] = e;
    sum += e;
  }
  #pragma unroll
  for (int m = 1; m <= 16; m <<= 1) sum += __shfl_xor(sum, m);
  float inv = 1.0f/sum;
  for (int j = 0; j < 32; ++j) S[rl][pg + 32*j] *= inv;
  __syncthreads();
  const float* vb = qb + (size_t)(448 + 32*n)*PPX;
  float acc = 0.0f;
  for (int p0 = 0; p0 < 1024; p0 += 128) {
    for (int q = t; q < 4096; q += 256) {
      int pp = q >> 5, c = q & 31;
      int p = p0 + pp;
      kv[pp*33 + c] = vb[(size_t)(p >> 5)*PPX + ((p & 31) << 5) + c];
    }
    __syncthreads();
    for (int pp = 0; pp < 128; ++pp) acc += S[rl][p0 + pp]*kv[pp*33 + pg];
    __syncthreads();
  }
  int rg = rg0 + rl;
  int ch = 32*n + (rg >> 5);
  size_t sp = (size_t)((rg & 31) << 5) + pg;
  pool[((size_t)b*224 + ch)*PPX + sp] = acc + xp[((size_t)b*256 + 32 + ch)*PPX + sp];
}

__global__ void k_owt(const float* __restrict__ ow, float* __restrict__ owt) {
  int t = blockIdx.x*256 + threadIdx.x;
  if (t < 256*224) {
    int oc = t/224, ch = t - oc*224;
    owt[(size_t)ch*256 + oc] = ow[t];
  }
}

// ================= bilinear + sim gating + final conv =================
__global__ __launch_bounds__(256) void k_final(const float* __restrict__ pool, const float* __restrict__ noise,
        const float* __restrict__ sim_w, const float* __restrict__ owt, float* __restrict__ out) {
  int tt = blockIdx.x, b = blockIdx.y;
  int t = threadIdx.x;
  int h = tt >> 3, w0 = (tt & 7)*16;
  __shared__ float xa[224][20];
  __shared__ float nsc[224][20];
  __shared__ float nz[32][20];
  __shared__ float scl[16];
  for (int q = t; q < 512; q += 256) {
    int c = q >> 4, px = q & 15;
    nz[c][px] = noise[((size_t)b*32 + c)*NPX + h*128 + w0 + px];
  }
  float hs = h*0.25f - 0.375f;
  float hf = floorf(hs);
  int h0 = (int)hf;
  float fh = hs - hf;
  int h0c = min(max(h0, 0), 31);
  int h1c = min(max(h0 + 1, 0), 31);
  __syncthreads();
  for (int q = t; q < 3584; q += 256) {
    int c = q >> 4, px = q & 15;
    int w = w0 + px;
    float wsrc = w*0.25f - 0.375f;
    float wf = floorf(wsrc);
    int W0 = (int)wf;
    float fw = wsrc - wf;
    int w0c = min(max(W0, 0), 31);
    int w1c = min(max(W0 + 1, 0), 31);
    const float* pb = pool + ((size_t)b*224 + c)*PPX;
    float v00 = pb[h0c*32 + w0c], v01 = pb[h0c*32 + w1c];
    float v10 = pb[h1c*32 + w0c], v11 = pb[h1c*32 + w1c];
    xa[c][px] = (1.0f - fh)*((1.0f - fw)*v00 + fw*v01) + fh*((1.0f - fw)*v10 + fw*v11);
    float np = 0.0f;
    #pragma unroll
    for (int j = 0; j < 32; ++j) np += sim_w[c*32 + j]*nz[j][px];
    nsc[c][px] = np;
  }
  __syncthreads();
  {
    int px = t >> 4, kk = t & 15;
    float s1 = 0, s2 = 0, s3 = 0;
    for (int c = kk; c < 224; c += 16) {
      float a = xa[c][px], p = nsc[c][px];
      s1 += a*a; s2 += p*p; s3 += a*p;
    }
    #pragma unroll
    for (int m = 1; m <= 8; m <<= 1) {
      s1 += __shfl_xor(s1, m);
      s2 += __shfl_xor(s2, m);
      s3 += __shfl_xor(s3, m);
    }
    if (kk == 0) {
      float n1 = fmaxf(sqrtf(s1), 1e-12f);
      float n2 = fmaxf(sqrtf(s2), 1e-12f);
      float sim = (s3/(n1*n2) + 1.0f)*0.5f;
      scl[px] = 1.0f - sim;
    }
  }
  __syncthreads();
  {
    float accp[16];
    #pragma unroll
    for (int px = 0; px < 16; ++px) accp[px] = 0.0f;
    for (int c = 0; c < 224; ++c) {
      float wv = owt[(size_t)c*256 + t];
      #pragma unroll
      for (int px = 0; px < 16; ++px) accp[px] += wv*xa[c][px];
    }
    size_t obase = ((size_t)b*256 + t)*NPX + (size_t)h*128 + w0;
    #pragma unroll
    for (int px = 0; px < 16; ++px) out[obase + px] = accp[px]*scl[px];
  }
  if (b == 0 && tt == 0 && t == 0) out[(size_t)33554432] = 8.0f;   // AVG_K
}

extern "C" void kernel_launch(void* const* d_in, const int* in_sizes, int n_in,
                              void* d_out, int out_size, void* d_ws, size_t ws_size,
                              hipStream_t stream) {
  (void)in_sizes; (void)n_in; (void)out_size; (void)ws_size;
  const float* x     = (const float*)d_in[0];
  const float* qkv_w = (const float*)d_in[1];
  const float* qkv_b = (const float*)d_in[2];
  const float* emb   = (const float*)d_in[3];
  const float* sim_w = (const float*)d_in[4];
  const float* out_w = (const float*)d_in[5];
  float* out = (float*)d_out;
  char* ws = (char*)d_ws;
  double* A    = (double*)(ws + OFF_A);
  double* QT   = (double*)(ws + OFF_QT);
  double* SG   = (double*)(ws + OFF_SG);
  double* QNT  = (double*)(ws + OFF_QN);
  double* d_a  = (double*)(ws + OFF_D);
  double* e_a  = (double*)(ws + OFF_E);
  double* tau_a= (double*)(ws + OFF_TAU);
  double* DW   = (double*)(ws + OFF_DW);
  int*    META = (int*)   (ws + OFF_META);
  double* Vg   = (double*)(ws + OFF_VG);
  double* Wg   = (double*)(ws + OFF_WG);
  double* GP   = (double*)(ws + OFF_GP);
  float*  Vt   = (float*) (ws + OFF_VT);
  float*  xp   = (float*) (ws + OFF_XP);
  float*  qkvm = (float*) (ws + OFF_QKV);
  float*  pool = (float*) (ws + OFF_POOL);
  float*  owt  = (float*) (ws + OFF_OWT);
  float*  noise_out = out + 33554433;

  k_gram <<<dim3(4,4,16), 256, 0, stream>>>(x, GP);
  k_gsum <<<dim3(512),    256, 0, stream>>>(GP, A);
  for (int p = 0; p < 8; ++p) {
    k_panel<<<dim3(8), 1024, 0, stream>>>(p, A, d_a, e_a, tau_a, Vg, Wg);
    if (p < 7) {
      int nt = 256 - 32*(p + 1);
      k_syr2k<<<dim3(nt/32, nt/32, 8), 256, 0, stream>>>(p, Vg, Wg, A);
    }
  }
  k_zeroq  <<<dim3(512),     256, 0, stream>>>(QT);
  k_leaves <<<dim3(8),       64,  0, stream>>>(d_a, e_a, QT, DW);
  {
    const int n1s[4]   = {16, 32, 64, 128};
    const int nmrgs[4] = {8, 4, 2, 1};
    for (int lv = 0; lv < 4; ++lv) {
      int n1 = n1s[lv], nmrg = nmrgs[lv], nn = 2*n1;
      k_mscan<<<dim3(nmrg, 8), 256, 0, stream>>>(n1, e_a, QT, DW, SG, META);
      k_mgemm<<<dim3(nn/32, (nn + 63)/64, nmrg*8), 256, 0, stream>>>(n1, nmrg, QT, SG, META, QNT);
      k_mperm<<<dim3(nmrg, 8), 256, 0, stream>>>(n1, QNT, META, QT);
    }
  }
  k_backxf <<<dim3(16,8),    256, 0, stream>>>(A, tau_a, QT, Vt);
  k_xproj  <<<dim3(32,8,8),  256, 0, stream>>>(x, Vt, xp, noise_out);
  k_qkv    <<<dim3(4,21,8),  256, 0, stream>>>(xp, qkv_w, qkv_b, qkvm);
  k_attn   <<<dim3(128,7,8), 256, 0, stream>>>(qkvm, emb, xp, pool);
  k_owt    <<<dim3(224),     256, 0, stream>>>(out_w, owt);
  k_final  <<<dim3(1024,8),  256, 0, stream>>>(pool, noise_out, sim_w, owt, out);
}

// Round 12
// 8227.808 us; speedup vs baseline: 1.3011x; 1.0225x over previous
//
#include <hip/hip_runtime.h>
#include <math.h>

#define NB  8
#define NPX 16384   // 128*128
#define PPX 1024    // 32*32
#define PNB 32      // dlatrd panel width

// f32 LAPACK machine constants (SLAMCH) used for branch tolerances
#define EPS32   5.9604644775390625e-8   // 2^-24 (slamch 'E')
#define EPS232  (EPS32*EPS32)
#define SAFMIN32 1.1754943508222875e-38

// ---------------- workspace layout (bytes), phase-aliased ----------------
static constexpr size_t OFF_VT   = 0;                    // f32 [8][256][256] 2MB (lives across phases)
static constexpr size_t U        = 0x200000;
static constexpr size_t OFF_A    = U + 0x400000;         // f64 [8][256][256] 4MB gram -> in-place tridiag / reflectors
static constexpr size_t OFF_QT   = U + 0x800000;         // f64 [8][256][256] 4MB QT[col][row]
static constexpr size_t OFF_SG   = U + 0xC00000;         // f64 [8][256][256] 4MB S scratch
static constexpr size_t OFF_QN   = U + 0x1000000;        // f64 [8][256][256] 4MB QNT scratch
static constexpr size_t OFF_D    = U + 0x1400000;        // f64 [8][256]
static constexpr size_t OFF_E    = U + 0x1404000;        // f64 [8][256]
static constexpr size_t OFF_TAU  = U + 0x1408000;        // f64 [8][256]
static constexpr size_t OFF_DW   = U + 0x140C000;        // f64 [8][256]
static constexpr size_t OFF_META = U + 0x1410000;        // int [8][8][520]
static constexpr size_t OFF_VG   = U + 0x1500000;        // f64 [8][256][32] 512KB panel V
static constexpr size_t OFF_WG   = U + 0x1580000;        // f64 [8][256][32] 512KB panel W
static constexpr size_t OFF_GP   = U + 0x1600000;        // f64 [16][256][256] 8MB gram k-split partials
// phase2 aliases:
static constexpr size_t OFF_XP   = U;                    // f32 [8][256][1024] 8MB
static constexpr size_t OFF_QKV  = U + 0x800000;         // f32 [8][672][1024] 21MB
static constexpr size_t OFF_POOL = U + 0x1D00000;        // f32 [8][224][1024] 7MB
static constexpr size_t OFF_OWT  = U + 0x2400000;        // f32 [224][256]

// ================= gram partials: 64x64 register-tiled f64, 2-way k-split =================
__global__ __launch_bounds__(256) void k_gram(const float* __restrict__ x, double* __restrict__ GP) {
  int jt = blockIdx.x, it = blockIdx.y;
  int z = blockIdx.z;
  int ks = z >> 3, b = z & 7;
  const float* xb = x + (size_t)b*256*NPX;
  int t = threadIdx.x;
  int tx = t & 15, ty = t >> 4;
  __shared__ float xiT[64][65], xjT[64][65];
  double acc[4][4];
  #pragma unroll
  for (int i = 0; i < 4; ++i)
    #pragma unroll
    for (int j = 0; j < 4; ++j) acc[i][j] = 0.0;
  int kb = ks*8192;
  for (int k0 = 0; k0 < 8192; k0 += 64) {
    for (int q = t; q < 4096; q += 256) {
      int r = q >> 6, c = q & 63;
      xiT[c][r] = xb[(size_t)(it*64 + r)*NPX + kb + k0 + c];
      xjT[c][r] = xb[(size_t)(jt*64 + r)*NPX + kb + k0 + c];
    }
    __syncthreads();
    for (int k = 0; k < 64; ++k) {
      float4 af = *(const float4*)&xiT[k][ty*4];
      float4 bf = *(const float4*)&xjT[k][tx*4];
      double a0 = (double)af.x, a1 = (double)af.y, a2 = (double)af.z, a3 = (double)af.w;
      double b0 = (double)bf.x, b1 = (double)bf.y, b2 = (double)bf.z, b3 = (double)bf.w;
      acc[0][0] += a0*b0; acc[0][1] += a0*b1; acc[0][2] += a0*b2; acc[0][3] += a0*b3;
      acc[1][0] += a1*b0; acc[1][1] += a1*b1; acc[1][2] += a1*b2; acc[1][3] += a1*b3;
      acc[2][0] += a2*b0; acc[2][1] += a2*b1; acc[2][2] += a2*b2; acc[2][3] += a2*b3;
      acc[3][0] += a3*b0; acc[3][1] += a3*b1; acc[3][2] += a3*b2; acc[3][3] += a3*b3;
    }
    __syncthreads();
  }
  double* gp = GP + (size_t)z*65536;
  #pragma unroll
  for (int ii = 0; ii < 4; ++ii)
    #pragma unroll
    for (int jj = 0; jj < 4; ++jj)
      gp[(size_t)(it*64 + ty*4 + ii)*256 + jt*64 + tx*4 + jj] = acc[ii][jj];
}

__global__ __launch_bounds__(256) void k_gsum(const double* __restrict__ GP, double* __restrict__ A) {
  size_t i = (size_t)blockIdx.x*256 + threadIdx.x;
  size_t total = (size_t)NB*65536;
  for (; i < total; i += (size_t)gridDim.x*256)
    A[i] = GP[i] + GP[i + total];
}

__device__ __forceinline__ double blkSum16(double v, double* tmp, int t, int nw) {
  #pragma unroll
  for (int m = 1; m <= 32; m <<= 1) v += __shfl_xor(v, m);
  __syncthreads();
  if ((t & 63) == 0) tmp[t >> 6] = v;
  __syncthreads();
  double s = 0.0;
  for (int w = 0; w < nw; ++w) s += tmp[w];
  return s;
}

// ================= blocked tridiagonalization: dlatrd-style panel (nb=32) =================
__global__ __launch_bounds__(1024) void k_panel(int p, double* __restrict__ A,
        double* __restrict__ d_g, double* __restrict__ e_g, double* __restrict__ tau_g,
        double* __restrict__ Vg, double* __restrict__ Wg) {
  int b = blockIdx.x, t = threadIdx.x;
  int g = t >> 8, c = t & 255;
  double* Ab = A + (size_t)b*65536;
  __shared__ double V[256][33], W[256][33];
  __shared__ double vL[256], wL[256], rowCur[256];
  __shared__ double wpart[4][256];
  __shared__ double c12[64];
  __shared__ double tmp[16];
  int jmax = (p == 7) ? 31 : 32;
  for (int j = 0; j < jmax; ++j) {
    int i = p*PNB + j;
    if (g == 0) {
      double rv = 0.0;
      if (c >= i) {
        rv = Ab[(size_t)i*256 + c];
        for (int k = 0; k < j; ++k)
          rv -= V[i][k]*W[c][k] + W[i][k]*V[c][k];
      }
      rowCur[c] = rv;
    }
    __syncthreads();
    double part = 0.0;
    int rx = i + 2 + t;
    if (rx < 256) { double v = rowCur[rx]; part = v*v; }
    double xn2 = blkSum16(part, tmp, t, 16);
    double alpha = rowCur[i + 1];
    double beta, tauv, scale;
    if (xn2 == 0.0) { beta = alpha; tauv = 0.0; scale = 0.0; }
    else {
      beta  = -copysign(sqrt(alpha*alpha + xn2), alpha);
      tauv  = (beta - alpha)/beta;
      scale = 1.0/(alpha - beta);
    }
    if (t == 0) { e_g[b*256 + i] = beta; tau_g[b*256 + i] = tauv; d_g[b*256 + i] = rowCur[i]; }
    if (g == 0) {
      double v = 0.0;
      if (c == i + 1) v = 1.0;
      else if (c >= i + 2) v = rowCur[c]*scale;
      vL[c] = v;
      V[c][j] = v;
      if (c >= i + 1) Ab[(size_t)i*256 + c] = v;
    }
    __syncthreads();
    {
      double s = 0.0;
      if (c >= i + 1) {
        for (int r = i + 1 + g; r < 256; r += 4) s += Ab[(size_t)r*256 + c]*vL[r];
      }
      wpart[g][c] = s;
    }
    {
      int kk = t >> 5, lane = t & 31;
      if (kk < j) {
        double s = 0.0;
        for (int ci2 = lane; ci2 < 256; ci2 += 32) s += W[ci2][kk]*vL[ci2];
        s += __shfl_xor(s, 1); s += __shfl_xor(s, 2); s += __shfl_xor(s, 4);
        s += __shfl_xor(s, 8); s += __shfl_xor(s, 16);
        if (lane == 0) c12[kk] = s;
        double s2 = 0.0;
        for (int ci2 = lane; ci2 < 256; ci2 += 32) s2 += V[ci2][kk]*vL[ci2];
        s2 += __shfl_xor(s2, 1); s2 += __shfl_xor(s2, 2); s2 += __shfl_xor(s2, 4);
        s2 += __shfl_xor(s2, 8); s2 += __shfl_xor(s2, 16);
        if (lane == 0) c12[32 + kk] = s2;
      }
    }
    __syncthreads();
    double wfull = 0.0, part2 = 0.0;
    if (g == 0 && c >= i + 1) {
      double wr = wpart[0][c] + wpart[1][c] + wpart[2][c] + wpart[3][c];
      for (int k = 0; k < j; ++k) wr -= V[c][k]*c12[k] + W[c][k]*c12[32 + k];
      wfull = tauv*wr;
      part2 = vL[c]*wfull;
    }
    double dot = blkSum16(part2, tmp, t, 16);
    double coef = -0.5*tauv*dot;
    if (g == 0) {
      double wv2 = (c >= i + 1) ? (wfull + coef*vL[c]) : 0.0;
      wL[c] = wv2;
      W[c][j] = wv2;
    }
    __syncthreads();
  }
  if (p < 7) {
    for (int idx = t; idx < 256*32; idx += 1024) {
      int cc = idx >> 5, kk = idx & 31;
      Vg[((size_t)b*256 + cc)*32 + kk] = V[cc][kk];
      Wg[((size_t)b*256 + cc)*32 + kk] = W[cc][kk];
    }
  } else {
    if (t == 0) {
      double dv = Ab[(size_t)255*256 + 255];
      for (int k = 0; k < 31; ++k) dv -= 2.0*V[255][k]*W[255][k];
      d_g[b*256 + 255] = dv;
      e_g[b*256 + 255] = 0.0;
    }
  }
}

// ================= trailing update: A -= V W^T + W V^T =================
__global__ __launch_bounds__(256) void k_syr2k(int p, const double* __restrict__ Vg,
        const double* __restrict__ Wg, double* __restrict__ A) {
  int rt = blockIdx.x, ct = blockIdx.y, b = blockIdx.z;
  int base = (p + 1)*32;
  int r0 = base + rt*32, c0 = base + ct*32;
  int t = threadIdx.x;
  __shared__ double Vr[32][33], Wr[32][33], Vc[32][33], Wc[32][33];
  for (int idx = t; idx < 1024; idx += 256) {
    int rr = idx >> 5, kk = idx & 31;
    Vr[rr][kk] = Vg[((size_t)b*256 + r0 + rr)*32 + kk];
    Wr[rr][kk] = Wg[((size_t)b*256 + r0 + rr)*32 + kk];
    Vc[rr][kk] = Vg[((size_t)b*256 + c0 + rr)*32 + kk];
    Wc[rr][kk] = Wg[((size_t)b*256 + c0 + rr)*32 + kk];
  }
  __syncthreads();
  int cl = t & 31, rg = t >> 5;
  double* Ab = A + (size_t)b*65536;
  #pragma unroll
  for (int q = 0; q < 4; ++q) {
    int rl = rg + 8*q;
    double acc = Ab[(size_t)(r0 + rl)*256 + c0 + cl];
    #pragma unroll
    for (int k = 0; k < 32; ++k)
      acc -= Vr[rl][k]*Wc[cl][k] + Wr[rl][k]*Vc[cl][k];
    Ab[(size_t)(r0 + rl)*256 + c0 + cl] = acc;
  }
}

// ================= LAPACK helpers =================
__device__ __forceinline__ void dlartg_(double f, double g, double& c, double& s, double& r) {
  if (g == 0.0) { c = 1.0; s = 0.0; r = f; }
  else if (f == 0.0) { c = 0.0; s = (g > 0.0) ? 1.0 : -1.0; r = fabs(g); }
  else {
    double d = sqrt(f*f + g*g);
    r = (f >= 0.0) ? d : -d;
    c = f / r;
    s = g / r;
  }
}

__device__ void dlaev2_(double a, double b, double cc, double& rt1, double& rt2, double& cs1, double& sn1) {
  double sm = a + cc, df = a - cc;
  double adf = fabs(df), tb = b + b, ab = fabs(tb);
  double acmx, acmn;
  if (fabs(a) > fabs(cc)) { acmx = a; acmn = cc; } else { acmx = cc; acmn = a; }
  double rt;
  if (adf > ab)      rt = adf*sqrt(1.0 + (ab/adf)*(ab/adf));
  else if (adf < ab) rt = ab*sqrt(1.0 + (adf/ab)*(adf/ab));
  else               rt = ab*sqrt(2.0);
  int sgn1;
  if (sm < 0.0)      { rt1 = 0.5*(sm - rt); sgn1 = -1; rt2 = (acmx/rt1)*acmn - (b/rt1)*b; }
  else if (sm > 0.0) { rt1 = 0.5*(sm + rt); sgn1 = 1;  rt2 = (acmx/rt1)*acmn - (b/rt1)*b; }
  else               { rt1 = 0.5*rt; rt2 = -0.5*rt; sgn1 = 1; }
  double cs; int sgn2;
  if (df >= 0.0) { cs = df + rt; sgn2 = 1; } else { cs = df - rt; sgn2 = -1; }
  double acs = fabs(cs);
  if (acs > ab) {
    double ct = -tb/cs;
    sn1 = 1.0/sqrt(1.0 + ct*ct);
    cs1 = ct*sn1;
  } else {
    if (ab == 0.0) { cs1 = 1.0; sn1 = 0.0; }
    else {
      double tn = -cs/tb;
      cs1 = 1.0/sqrt(1.0 + tn*tn);
      sn1 = tn*cs1;
    }
  }
  if (sgn1 == sgn2) { double tn = cs1; cs1 = -sn1; sn1 = tn; }
}

// faithful dsteqr('I') on an n<=16 block; csv/snv buffers supplied (LDS) to keep VGPRs low
__device__ void steqr_leaf(int n, double* d, double* e, double* q, int ldq, double* csv, double* snv) {
  const double eps = EPS32, eps2 = EPS232, safmin = SAFMIN32;
  int nmaxit = n*30, jtot = 0;
  int l1 = 0;
  while (l1 < n) {
    if (l1 > 0) e[l1-1] = 0.0;
    int m;
    for (m = l1; m < n-1; ++m) {
      double tst = fabs(e[m]);
      if (tst == 0.0) break;
      if (tst <= (sqrt(fabs(d[m]))*sqrt(fabs(d[m+1])))*eps) { e[m] = 0.0; break; }
    }
    int l = l1, lend = m;
    l1 = m + 1;
    if (lend == l) continue;
    if (fabs(d[lend]) < fabs(d[l])) { int tsw = l; l = lend; lend = tsw; }
    if (lend > l) {
      while (true) {
        int mm;
        for (mm = l; mm < lend; ++mm) {
          double tst = e[mm]*e[mm];
          if (tst <= (eps2*fabs(d[mm]))*fabs(d[mm+1]) + safmin) break;
        }
        if (mm < lend) e[mm] = 0.0;
        double p = d[l];
        if (mm == l) { l = l + 1; if (l > lend) break; continue; }
        if (mm == l+1) {
          double rt1, rt2, c, s;
          dlaev2_(d[l], e[l], d[l+1], rt1, rt2, c, s);
          for (int i = 0; i < n; ++i) {
            double t1 = q[i*ldq + l+1], t0 = q[i*ldq + l];
            q[i*ldq + l+1] = c*t1 - s*t0;
            q[i*ldq + l]   = s*t1 + c*t0;
          }
          d[l] = rt1; d[l+1] = rt2; e[l] = 0.0;
          l += 2; if (l > lend) break; continue;
        }
        if (jtot == nmaxit) break;
        jtot++;
        double g = (d[l+1] - p)/(2.0*e[l]);
        double r = sqrt(g*g + 1.0);
        g = d[mm] - p + e[l]/(g + copysign(r, g));
        double s = 1.0, c = 1.0; p = 0.0;
        for (int i = mm-1; i >= l; --i) {
          double f = s*e[i], bb = c*e[i];
          dlartg_(g, f, c, s, r);
          if (i != mm-1) e[i+1] = r;
          g = d[i+1] - p;
          r = (d[i] - g)*s + 2.0*c*bb;
          p = s*r;
          d[i+1] = g + p;
          g = c*r - bb;
          csv[i] = c; snv[i] = -s;
        }
        for (int i = mm-1; i >= l; --i) {
          double cc2 = csv[i], ss2 = snv[i];
          for (int k = 0; k < n; ++k) {
            double t1 = q[k*ldq + i+1], t0 = q[k*ldq + i];
            q[k*ldq + i+1] = cc2*t1 - ss2*t0;
            q[k*ldq + i]   = ss2*t1 + cc2*t0;
          }
        }
        d[l] -= p; e[l] = g;
      }
    } else {
      while (true) {
        int mm;
        for (mm = l; mm > lend; --mm) {
          double tst = e[mm-1]*e[mm-1];
          if (tst <= (eps2*fabs(d[mm]))*fabs(d[mm-1]) + safmin) break;
        }
        if (mm > lend) e[mm-1] = 0.0;
        double p = d[l];
        if (mm == l) { l = l - 1; if (l < lend) break; continue; }
        if (mm == l-1) {
          double rt1, rt2, c, s;
          dlaev2_(d[l-1], e[l-1], d[l], rt1, rt2, c, s);
          for (int i = 0; i < n; ++i) {
            double t1 = q[i*ldq + l], t0 = q[i*ldq + l-1];
            q[i*ldq + l]   = c*t1 - s*t0;
            q[i*ldq + l-1] = s*t1 + c*t0;
          }
          d[l-1] = rt1; d[l] = rt2; e[l-1] = 0.0;
          l -= 2; if (l < lend) break; continue;
        }
        if (jtot == nmaxit) break;
        jtot++;
        double g = (d[l-1] - p)/(2.0*e[l-1]);
        double r = sqrt(g*g + 1.0);
        g = d[mm] - p + e[l-1]/(g + copysign(r, g));
        double s = 1.0, c = 1.0; p = 0.0;
        for (int i = mm; i <= l-1; ++i) {
          double f = s*e[i], bb = c*e[i];
          dlartg_(g, f, c, s, r);
          if (i != mm) e[i-1] = r;
          g = d[i] - p;
          r = (d[i+1] - g)*s + 2.0*c*bb;
          p = s*r;
          d[i] = g + p;
          g = c*r - bb;
          csv[i] = c; snv[i] = s;
        }
        for (int i = mm; i <= l-1; ++i) {
          double cc2 = csv[i], ss2 = snv[i];
          for (int k = 0; k < n; ++k) {
            double t1 = q[k*ldq + i+1], t0 = q[k*ldq + i];
            q[k*ldq + i+1] = cc2*t1 - ss2*t0;
            q[k*ldq + i]   = ss2*t1 + cc2*t0;
          }
        }
        d[l] -= p; e[l-1] = g;
      }
    }
  }
  for (int ii = 1; ii < n; ++ii) {
    int k = ii - 1; double p = d[k];
    for (int j = ii; j < n; ++j) if (d[j] < p) { k = j; p = d[j]; }
    if (k != ii-1) {
      d[k] = d[ii-1]; d[ii-1] = p;
      for (int r = 0; r < n; ++r) { double tq = q[r*ldq + ii-1]; q[r*ldq + ii-1] = q[r*ldq + k]; q[r*ldq + k] = tq; }
    }
  }
}

__global__ __launch_bounds__(256) void k_zeroq(double* __restrict__ QT) {
  size_t i = (size_t)blockIdx.x*256 + threadIdx.x;
  size_t total = (size_t)NB*65536;
  for (; i < total; i += (size_t)gridDim.x*256) QT[i] = 0.0;
}

// ================= leaves: one ssteqr(16) per WAVE (no divergence, no conflicts) =================
__global__ __launch_bounds__(1024) void k_leaves(const double* __restrict__ d_g, const double* __restrict__ e_g,
        double* __restrict__ QT, double* __restrict__ DW) {
  int b = blockIdx.x, t = threadIdx.x;
  __shared__ double dL[256], eL[256];
  __shared__ double ql[16*272];      // 16 leaves x [16][17]
  __shared__ double csb[16*16], snb[16*16];
  if (t < 256) { dL[t] = d_g[b*256 + t]; eL[t] = e_g[b*256 + t]; }
  __syncthreads();
  if (t == 0) {
    for (int cut = 16; cut < 256; cut += 16) {   // dlaed0 tears
      double a = fabs(eL[cut-1]);
      dL[cut-1] -= a; dL[cut] -= a;
    }
  }
  __syncthreads();
  int w = t >> 6, lane = t & 63;
  if (lane == 0) {                   // leaf w on its own wave: independent control flow
    double* q = &ql[w*272];
    for (int i = 0; i < 16; ++i)
      for (int j = 0; j < 16; ++j) q[i*17 + j] = (i == j) ? 1.0 : 0.0;
    steqr_leaf(16, dL + 16*w, eL + 16*w, q, 17, &csb[w*16], &snb[w*16]);
  }
  __syncthreads();
  for (int idx = t; idx < 4096; idx += 1024) {
    int lf = idx >> 8, i = (idx >> 4) & 15, j = idx & 15;
    QT[(size_t)b*65536 + (size_t)(lf*16 + j)*256 + lf*16 + i] = ql[lf*272 + i*17 + j];
  }
  if (t < 256) DW[b*256 + t] = dL[t];
}

// ================= merge phase 1: scan + rotations + secular + S =================
__global__ __launch_bounds__(256) void k_mscan(int n1, const double* __restrict__ e_g,
        double* __restrict__ QT, double* __restrict__ DW, double* __restrict__ SG, int* __restrict__ META) {
  int mrg = blockIdx.x, b = blockIdx.y, t = threadIdx.x;
  int nn = 2*n1, r0 = mrg*nn;
  double* Q = QT + (size_t)b*65536;
  double* Sg = SG + (size_t)b*65536;
  int* meta = META + ((b*8 + mrg)*520);
  __shared__ double dloc[256], zloc[256], dlam[256], wv[256], w2[256], tauv[256], zh[256], dfin[256];
  __shared__ int indx[256], indxp[256], permf[256];
  __shared__ double rotc[256], rots[256];
  __shared__ short rotp[256], rotq[256];
  __shared__ int KK[3];
  __shared__ double sc[2];
  double rho_raw = e_g[b*256 + r0 + n1 - 1];
  if (t < nn) {
    dloc[t] = DW[b*256 + r0 + t];
    double zv = Q[(size_t)(r0 + t)*256 + r0 + ((t < n1) ? (n1 - 1) : n1)];
    if (t >= n1 && rho_raw < 0.0) zv = -zv;
    zloc[t] = zv * 0.70710678118654752440;
  }
  __syncthreads();
  if (t == 0) {
    int i = 0, jj = n1, pos = 0;
    while (i < n1 && jj < nn) { if (dloc[i] <= dloc[jj]) indx[pos++] = i++; else indx[pos++] = jj++; }
    while (i < n1) indx[pos++] = i++;
    while (jj < nn) indx[pos++] = jj++;
    double maxd = 0.0, maxz = 0.0;
    for (int q2 = 0; q2 < nn; ++q2) { maxd = fmax(maxd, fabs(dloc[q2])); maxz = fmax(maxz, fabs(zloc[q2])); }
    double rho = fabs(2.0*rho_raw);
    double tol = 8.0*EPS32*fmax(maxd, maxz);
    int K = 0, K2 = nn, nrot = 0, pj = -1, j = 0;
    for (; j < nn; ++j) {
      int nj = indx[j];
      if (rho*fabs(zloc[nj]) <= tol) { K2--; indxp[K2] = nj; }
      else { pj = nj; break; }
    }
    if (pj >= 0) {
      for (++j; j < nn; ++j) {
        int nj = indx[j];
        if (rho*fabs(zloc[nj]) <= tol) { K2--; indxp[K2] = nj; }
        else {
          double s = zloc[pj], c = zloc[nj];
          double tau = sqrt(c*c + s*s);
          double tdf = dloc[nj] - dloc[pj];
          c /= tau; s = -s/tau;
          if (fabs(tdf*c*s) <= tol) {
            zloc[nj] = tau; zloc[pj] = 0.0;
            rotp[nrot] = (short)pj; rotq[nrot] = (short)nj; rotc[nrot] = c; rots[nrot] = s; nrot++;
            double tt2 = dloc[pj]*c*c + dloc[nj]*s*s;
            dloc[nj] = dloc[pj]*s*s + dloc[nj]*c*c;
            dloc[pj] = tt2;
            K2--;
            int ii2 = 1;
            while (K2 + ii2 <= nn - 1 && dloc[pj] < dloc[indxp[K2 + ii2]]) { indxp[K2+ii2-1] = indxp[K2+ii2]; ii2++; }
            indxp[K2+ii2-1] = pj;
            pj = nj;
          } else {
            dlam[K] = dloc[pj]; wv[K] = zloc[pj]; indxp[K] = pj; K++;
            pj = nj;
          }
        }
      }
      dlam[K] = dloc[pj]; wv[K] = zloc[pj]; indxp[K] = pj; K++;
    }
    double sumw2 = 0.0;
    for (int q2 = 0; q2 < K; ++q2) sumw2 += wv[q2]*wv[q2];
    KK[0] = K; KK[1] = K2; KK[2] = nrot; sc[0] = rho; sc[1] = sumw2;
  }
  __syncthreads();
  int K = KK[0], K2 = KK[1], nrot = KK[2];
  double rho = sc[0], sumw2 = sc[1];
  if (t < nn) {
    for (int k = 0; k < nrot; ++k) {
      int p = rotp[k], q = rotq[k];
      double c = rotc[k], s = rots[k];
      size_t ip = (size_t)(r0 + p)*256 + r0 + t;
      size_t iq = (size_t)(r0 + q)*256 + r0 + t;
      double xq = Q[ip], yq = Q[iq];
      Q[ip] = c*xq + s*yq;
      Q[iq] = c*yq - s*xq;
    }
  }
  if (t < K) w2[t] = rho*wv[t]*wv[t];
  __syncthreads();
  if (t < K) {
    double dj = dlam[t];
    double hi0 = (t < K-1) ? (dlam[t+1] - dj) : rho*sumw2;
    double lo = 0.0, hi = hi0;
    for (int it = 0; it < 64; ++it) {
      double mid = 0.5*(lo + hi);
      double f = 1.0;
      for (int j2 = 0; j2 < K; ++j2) f += w2[j2]/((dlam[j2] - dj) - mid);
      if (f < 0.0) lo = mid; else hi = mid;
    }
    double tl = 0.5*(lo + hi);
    if (tl <= 0.0) tl = hi0*1e-300;
    tauv[t] = tl;
  }
  __syncthreads();
  if (t < K) {
    double dt2 = dlam[t], p = tauv[t];
    for (int i = 0; i < K; ++i) { if (i == t) continue; double del = dlam[i] - dt2; p *= (del + tauv[i])/del; }
    zh[t] = copysign(sqrt(fabs(p)), wv[t]);
  }
  __syncthreads();
  if (t < K) {
    double dj = dlam[t], tj = tauv[t];
    double nrm = 0.0;
    for (int i = 0; i < K; ++i) { double sij = zh[i]/((dlam[i] - dj) - tj); nrm += sij*sij; }
    double inv = 1.0/sqrt(nrm);
    for (int i = 0; i < K; ++i) Sg[(size_t)(r0 + i)*256 + t] = (zh[i]/((dlam[i] - dj) - tj))*inv;
  }
  __syncthreads();
  if (t == 0) {
    int i = 0, p = nn - 1, f = 0;
    while (f < nn) {
      bool takesec;
      if (i < K && p >= K2) takesec = ((dlam[i] + tauv[i]) <= dloc[indxp[p]]);
      else takesec = (i < K);
      if (takesec) { dfin[f] = dlam[i] + tauv[i]; permf[f] = i; i++; }
      else         { dfin[f] = dloc[indxp[p]];    permf[f] = K + (p - K2); p--; }
      f++;
    }
    for (f = 0; f < nn; ++f) DW[b*256 + r0 + f] = dfin[f];
    meta[0] = K; meta[1] = K2;
  }
  __syncthreads();
  if (t < nn) { meta[2 + t] = indxp[t]; meta[258 + t] = permf[t]; }
}

// ================= merge phase 2 =================
__global__ __launch_bounds__(256) void k_mgemm(int n1, int nmrg, const double* __restrict__ QT,
        const double* __restrict__ SG, const int* __restrict__ META, double* __restrict__ QNT) {
  int nn = 2*n1;
  int jt = blockIdx.x, rt = blockIdx.y;
  int z = blockIdx.z;
  int mrg = z % nmrg, b = z / nmrg;
  int r0 = mrg*nn;
  int t = threadIdx.x;
  const int* meta = META + ((b*8 + mrg)*520);
  __shared__ int sindxp[256];
  __shared__ double Gs[32][66];
  __shared__ double Ss[32][33];
  const double* Q = QT + (size_t)b*65536;
  const double* Sg = SG + (size_t)b*65536;
  double* Qn = QNT + (size_t)b*65536;
  int K = meta[0], K2 = meta[1];
  if (t < nn) sindxp[t] = meta[2 + t];
  __syncthreads();
  int jl = t >> 6, rl = t & 63;
  int r = rt*64 + rl;
  double acc[8];
  #pragma unroll
  for (int q = 0; q < 8; ++q) acc[q] = 0.0;
  if (jt*32 < K) {
    for (int i0 = 0; i0 < K; i0 += 32) {
      #pragma unroll
      for (int w = 0; w < 8; ++w) {
        int idx = t + 256*w;
        int ii = idx >> 6, rr = idx & 63;
        double v = 0.0;
        if (i0 + ii < K && rt*64 + rr < nn)
          v = Q[(size_t)(r0 + sindxp[i0 + ii])*256 + r0 + rt*64 + rr];
        Gs[ii][rr] = v;
      }
      #pragma unroll
      for (int w = 0; w < 4; ++w) {
        int idx = t + 256*w;
        int ii2 = idx >> 5, jj = idx & 31;
        double v = 0.0;
        if (i0 + ii2 < K)
          v = Sg[(size_t)(r0 + i0 + ii2)*256 + jt*32 + jj];
        Ss[ii2][jj] = v;
      }
      __syncthreads();
      int kmax = (K - i0 < 32) ? (K - i0) : 32;
      for (int ii = 0; ii < kmax; ++ii) {
        double gv = Gs[ii][rl];
        #pragma unroll
        for (int q = 0; q < 8; ++q) acc[q] += Ss[ii][jl + 4*q] * gv;
      }
      __syncthreads();
    }
  }
  if (r < nn) {
    #pragma unroll
    for (int q = 0; q < 8; ++q) {
      int j = jt*32 + jl + 4*q;
      if (j < K) Qn[(size_t)(r0 + j)*256 + r0 + r] = acc[q];
      else if (j < nn) {
        int p = K2 + (j - K);
        Qn[(size_t)(r0 + j)*256 + r0 + r] = Q[(size_t)(r0 + sindxp[p])*256 + r0 + r];
      }
    }
  }
}

// ================= merge phase 3 =================
__global__ __launch_bounds__(256) void k_mperm(int n1, const double* __restrict__ QNT,
        const int* __restrict__ META, double* __restrict__ QT) {
  int mrg = blockIdx.x, b = blockIdx.y, t = threadIdx.x;
  int nn = 2*n1, r0 = mrg*nn;
  const int* meta = META + ((b*8 + mrg)*520);
  __shared__ int pf[256];
  if (t < nn) pf[t] = meta[258 + t];
  __syncthreads();
  if (t < nn) {
    for (int f = 0; f < nn; ++f)
      QT[(size_t)b*65536 + (size_t)(r0 + f)*256 + r0 + t] =
        QNT[(size_t)b*65536 + (size_t)(r0 + pf[f])*256 + r0 + t];
  }
}

// ================= back-transform, LDS-tiled: emit Vt (f32) directly =================
__global__ __launch_bounds__(256) void k_backxf(const double* __restrict__ A, const double* __restrict__ tau_g,
        const double* __restrict__ QT, float* __restrict__ Vt) {
  int g = blockIdx.x, b = blockIdx.y;
  int t = threadIdx.x;
  int e = t >> 4, l = t & 15;
  __shared__ double zt[16][264];
  __shared__ double vL[256];
  __shared__ double tauL[256];
  const double* Ab = A + (size_t)b*65536;
  const double* Qb = QT + (size_t)b*65536 + (size_t)g*16*256;
  #pragma unroll
  for (int w = 0; w < 16; ++w) {
    int idx = t + 256*w;
    int ee = idx >> 8, rr = idx & 255;
    zt[ee][rr] = Qb[(size_t)ee*256 + rr];
  }
  tauL[t] = tau_g[b*256 + t];
  __syncthreads();
  for (int s = 253; s >= 0; --s) {
    if (t == 0) vL[s+1] = 1.0;
    int rx = s + 2 + t;
    if (rx < 256) vL[rx] = Ab[s*256 + rx];
    __syncthreads();
    double tauv = tauL[s];
    if (tauv != 0.0) {
      double acc = 0.0;
      for (int rr = s + 1 + l; rr < 256; rr += 16) acc += vL[rr]*zt[e][rr];
      acc += __shfl_xor(acc, 1);
      acc += __shfl_xor(acc, 2);
      acc += __shfl_xor(acc, 4);
      acc += __shfl_xor(acc, 8);
      double tw = tauv*acc;
      for (int rr = s + 1 + l; rr < 256; rr += 16) zt[e][rr] -= tw*vL[rr];
    }
    __syncthreads();
  }
  float* vtb = Vt + ((size_t)b*256 + (size_t)g*16)*256;
  #pragma unroll
  for (int w = 0; w < 16; ++w) {
    int idx = t + 256*w;
    int ee = idx >> 8, rr = idx & 255;
    vtb[(size_t)ee*256 + rr] = (float)zt[ee][rr];
  }
}

// ================= x_proj = V x, + x, fused maxpool + noise output =================
__global__ __launch_bounds__(256) void k_xproj(const float* __restrict__ x, const float* __restrict__ Vt,
        float* __restrict__ xp, float* __restrict__ noise_out) {
  int R = blockIdx.x, ct = blockIdx.y, b = blockIdx.z;
  int t = threadIdx.x;
  int cl = t >> 3, l8 = t & 7;
  __shared__ float vsh[32][20];
  __shared__ float xs[16][520];
  const float* xb = x + (size_t)b*256*NPX;
  int s0 = R*512;
  float acc[64];
  #pragma unroll
  for (int p = 0; p < 64; ++p) acc[p] = 0.0f;
  for (int d0 = 0; d0 < 256; d0 += 16) {
    for (int q = t; q < 512; q += 256) {
      int c = q >> 4, dd = q & 15;
      vsh[c][dd] = Vt[((size_t)b*256 + ct*32 + c)*256 + d0 + dd];
    }
    for (int q = t; q < 8192; q += 256) {
      int dd = q >> 9, px = q & 511;
      xs[dd][px] = xb[(size_t)(d0 + dd)*NPX + s0 + px];
    }
    __syncthreads();
    for (int dd = 0; dd < 16; ++dd) {
      float a = vsh[cl][dd];
      const float* xr = &xs[dd][l8];
      #pragma unroll
      for (int p = 0; p < 64; ++p) acc[p] += a*xr[8*p];
    }
    __syncthreads();
  }
  int cg = ct*32 + cl;
  const float* xc = xb + (size_t)cg*NPX + s0;
  float vmax[16];
  #pragma unroll
  for (int j = 0; j < 16; ++j) vmax[j] = -3.0e38f;
  bool isnz = (ct == 0);
  #pragma unroll
  for (int p = 0; p < 64; ++p) {
    int px = l8 + 8*p;
    float val = acc[p] + xc[px];
    vmax[p & 15] = fmaxf(vmax[p & 15], val);
    if (isnz) noise_out[((size_t)b*32 + cl)*NPX + s0 + px] = val;
  }
  #pragma unroll
  for (int j = 0; j < 16; ++j) {
    float v = vmax[j];
    v = fmaxf(v, __shfl_xor(v, 1));
    v = fmaxf(v, __shfl_xor(v, 2));
    vmax[j] = v;
  }
  if ((l8 & 3) == 0) {
    int halfsel = l8 >> 2;
    #pragma unroll
    for (int j = 0; j < 16; ++j)
      xp[((size_t)b*256 + cg)*PPX + R*32 + 2*j + halfsel] = vmax[j];
  }
}

// ================= qkv 1x1 conv (672 needed rows) =================
__global__ __launch_bounds__(256) void k_qkv(const float* __restrict__ xp, const float* __restrict__ wq,
        const float* __restrict__ bq, float* __restrict__ qkvm) {
  int pt = blockIdx.x, ot = blockIdx.y, b = blockIdx.z;
  int t = threadIdx.x;
  int ol = t & 31, pg = t >> 5;
  __shared__ float wsh[32][9];
  __shared__ float xsh[8][260];
  float acc[32];
  #pragma unroll
  for (int j = 0; j < 32; ++j) acc[j] = 0.0f;
  for (int ic0 = 0; ic0 < 256; ic0 += 8) {
    {
      int o = t >> 3, j = t & 7;
      int orow = ot*32 + o;
      int reg = orow/224, rem = orow - reg*224;
      int wrow = 32 + rem + 256*reg;
      wsh[o][j] = wq[(size_t)wrow*256 + ic0 + j];
    }
    for (int q = t; q < 2048; q += 256) {
      int ic = q >> 8, px = q & 255;
      xsh[ic][px] = xp[((size_t)b*256 + ic0 + ic)*PPX + pt*256 + px];
    }
    __syncthreads();
    for (int ic = 0; ic < 8; ++ic) {
      float a = wsh[ol][ic];
      const float* xr = &xsh[ic][pg];
      #pragma unroll
      for (int j = 0; j < 32; ++j) acc[j] += a*xr[8*j];
    }
    __syncthreads();
  }
  int orow = ot*32 + ol;
  int reg = orow/224, rem = orow - reg*224;
  float bv = bq[32 + rem + 256*reg];
  #pragma unroll
  for (int j = 0; j < 32; ++j)
    qkvm[((size_t)b*672 + orow)*PPX + pt*256 + pg + 8*j] = acc[j] + bv;
}

// ================= attention =================
__global__ __launch_bounds__(256) void k_attn(const float* __restrict__ qkvm, const float* __restrict__ emb,
        const float* __restrict__ xp, float* __restrict__ pool) {
  int rt = blockIdx.x, n = blockIdx.y, b = blockIdx.z;
  int t = threadIdx.x;
  int rl = t >> 5, pg = t & 31;
  __shared__ float S[8][1032];
  __shared__ float qsh[8][33];
  __shared__ float kv[4224];
  const float* qb = qkvm + (size_t)b*672*PPX;
  int rg0 = rt*8;
  {
    int rg = rg0 + rl;
    float qv = qb[(size_t)(32*n + (rg >> 5))*PPX + ((rg & 31) << 5) + pg];
    float ev = emb[(((size_t)n*8 + b)*1024 + rg)*32 + pg];
    qsh[rl][pg] = (qv + ev)*0.17677669529663688f;
  }
  __syncthreads();
  const float* kb = qb + (size_t)(224 + 32*n)*PPX;
  for (int p0 = 0; p0 < 1024; p0 += 128) {
    for (int q = t; q < 4096; q += 256) {
      int c = q >> 7, pp = q & 127;
      kv[c*132 + pp] = kb[(size_t)c*PPX + p0 + pp];
    }
    __syncthreads();
    float a0 = 0, a1 = 0, a2 = 0, a3 = 0;
    for (int c = 0; c < 32; ++c) {
      float qv = qsh[rl][c];
      const float* kr = &kv[c*132 + pg];
      a0 += qv*kr[0]; a1 += qv*kr[32]; a2 += qv*kr[64]; a3 += qv*kr[96];
    }
    S[rl][p0 + pg]      = a0;
    S[rl][p0 + pg + 32] = a1;
    S[rl][p0 + pg + 64] = a2;
    S[rl][p0 + pg + 96] = a3;
    __syncthreads();
  }
  float mx = -3.0e38f;
  for (int j = 0; j < 32; ++j) mx = fmaxf(mx, S[rl][pg + 32*j]);
  #pragma unroll
  for (int m = 1; m <= 16; m <<= 1) mx = fmaxf(mx, __shfl_xor(mx, m));
  float sum = 0.0f;
  for (int j = 0; j < 32; ++j) {
    float e = expf(S[rl][pg + 32*j] - mx);
    S[rl][pg + 32*j] = e;
    sum += e;
  }
  #pragma unroll
  for (int m = 1; m <= 16; m <<= 1) sum += __shfl_xor(sum, m);
  float inv = 1.0f/sum;
  for (int j = 0; j < 32; ++j) S[rl][pg + 32*j] *= inv;
  __syncthreads();
  const float* vb = qb + (size_t)(448 + 32*n)*PPX;
  float acc = 0.0f;
  for (int p0 = 0; p0 < 1024; p0 += 128) {
    for (int q = t; q < 4096; q += 256) {
      int pp = q >> 5, c = q & 31;
      int p = p0 + pp;
      kv[pp*33 + c] = vb[(size_t)(p >> 5)*PPX + ((p & 31) << 5) + c];
    }
    __syncthreads();
    for (int pp = 0; pp < 128; ++pp) acc += S[rl][p0 + pp]*kv[pp*33 + pg];
    __syncthreads();
  }
  int rg = rg0 + rl;
  int ch = 32*n + (rg >> 5);
  size_t sp = (size_t)((rg & 31) << 5) + pg;
  pool[((size_t)b*224 + ch)*PPX + sp] = acc + xp[((size_t)b*256 + 32 + ch)*PPX + sp];
}

__global__ void k_owt(const float* __restrict__ ow, float* __restrict__ owt) {
  int t = blockIdx.x*256 + threadIdx.x;
  if (t < 256*224) {
    int oc = t/224, ch = t - oc*224;
    owt[(size_t)ch*256 + oc] = ow[t];
  }
}

// ================= bilinear + sim gating + final conv =================
__global__ __launch_bounds__(256) void k_final(const float* __restrict__ pool, const float* __restrict__ noise,
        const float* __restrict__ sim_w, const float* __restrict__ owt, float* __restrict__ out) {
  int tt = blockIdx.x, b = blockIdx.y;
  int t = threadIdx.x;
  int h = tt >> 3, w0 = (tt & 7)*16;
  __shared__ float xa[224][20];
  __shared__ float nsc[224][20];
  __shared__ float nz[32][20];
  __shared__ float scl[16];
  for (int q = t; q < 512; q += 256) {
    int c = q >> 4, px = q & 15;
    nz[c][px] = noise[((size_t)b*32 + c)*NPX + h*128 + w0 + px];
  }
  float hs = h*0.25f - 0.375f;
  float hf = floorf(hs);
  int h0 = (int)hf;
  float fh = hs - hf;
  int h0c = min(max(h0, 0), 31);
  int h1c = min(max(h0 + 1, 0), 31);
  __syncthreads();
  for (int q = t; q < 3584; q += 256) {
    int c = q >> 4, px = q & 15;
    int w = w0 + px;
    float wsrc = w*0.25f - 0.375f;
    float wf = floorf(wsrc);
    int W0 = (int)wf;
    float fw = wsrc - wf;
    int w0c = min(max(W0, 0), 31);
    int w1c = min(max(W0 + 1, 0), 31);
    const float* pb = pool + ((size_t)b*224 + c)*PPX;
    float v00 = pb[h0c*32 + w0c], v01 = pb[h0c*32 + w1c];
    float v10 = pb[h1c*32 + w0c], v11 = pb[h1c*32 + w1c];
    xa[c][px] = (1.0f - fh)*((1.0f - fw)*v00 + fw*v01) + fh*((1.0f - fw)*v10 + fw*v11);
    float np = 0.0f;
    #pragma unroll
    for (int j = 0; j < 32; ++j) np += sim_w[c*32 + j]*nz[j][px];
    nsc[c][px] = np;
  }
  __syncthreads();
  {
    int px = t >> 4, kk = t & 15;
    float s1 = 0, s2 = 0, s3 = 0;
    for (int c = kk; c < 224; c += 16) {
      float a = xa[c][px], p = nsc[c][px];
      s1 += a*a; s2 += p*p; s3 += a*p;
    }
    #pragma unroll
    for (int m = 1; m <= 8; m <<= 1) {
      s1 += __shfl_xor(s1, m);
      s2 += __shfl_xor(s2, m);
      s3 += __shfl_xor(s3, m);
    }
    if (kk == 0) {
      float n1 = fmaxf(sqrtf(s1), 1e-12f);
      float n2 = fmaxf(sqrtf(s2), 1e-12f);
      float sim = (s3/(n1*n2) + 1.0f)*0.5f;
      scl[px] = 1.0f - sim;
    }
  }
  __syncthreads();
  {
    float accp[16];
    #pragma unroll
    for (int px = 0; px < 16; ++px) accp[px] = 0.0f;
    for (int c = 0; c < 224; ++c) {
      float wv = owt[(size_t)c*256 + t];
      #pragma unroll
      for (int px = 0; px < 16; ++px) accp[px] += wv*xa[c][px];
    }
    size_t obase = ((size_t)b*256 + t)*NPX + (size_t)h*128 + w0;
    #pragma unroll
    for (int px = 0; px < 16; ++px) out[obase + px] = accp[px]*scl[px];
  }
  if (b == 0 && tt == 0 && t == 0) out[(size_t)33554432] = 8.0f;   // AVG_K
}

extern "C" void kernel_launch(void* const* d_in, const int* in_sizes, int n_in,
                              void* d_out, int out_size, void* d_ws, size_t ws_size,
                              hipStream_t stream) {
  (void)in_sizes; (void)n_in; (void)out_size; (void)ws_size;
  const float* x     = (const float*)d_in[0];
  const float* qkv_w = (const float*)d_in[1];
  const float* qkv_b = (const float*)d_in[2];
  const float* emb   = (const float*)d_in[3];
  const float* sim_w = (const float*)d_in[4];
  const float* out_w = (const float*)d_in[5];
  float* out = (float*)d_out;
  char* ws = (char*)d_ws;
  double* A    = (double*)(ws + OFF_A);
  double* QT   = (double*)(ws + OFF_QT);
  double* SG   = (double*)(ws + OFF_SG);
  double* QNT  = (double*)(ws + OFF_QN);
  double* d_a  = (double*)(ws + OFF_D);
  double* e_a  = (double*)(ws + OFF_E);
  double* tau_a= (double*)(ws + OFF_TAU);
  double* DW   = (double*)(ws + OFF_DW);
  int*    META = (int*)   (ws + OFF_META);
  double* Vg   = (double*)(ws + OFF_VG);
  double* Wg   = (double*)(ws + OFF_WG);
  double* GP   = (double*)(ws + OFF_GP);
  float*  Vt   = (float*) (ws + OFF_VT);
  float*  xp   = (float*) (ws + OFF_XP);
  float*  qkvm = (float*) (ws + OFF_QKV);
  float*  pool = (float*) (ws + OFF_POOL);
  float*  owt  = (float*) (ws + OFF_OWT);
  float*  noise_out = out + 33554433;

  k_gram <<<dim3(4,4,16), 256, 0, stream>>>(x, GP);
  k_gsum <<<dim3(512),    256, 0, stream>>>(GP, A);
  for (int p = 0; p < 8; ++p) {
    k_panel<<<dim3(8), 1024, 0, stream>>>(p, A, d_a, e_a, tau_a, Vg, Wg);
    if (p < 7) {
      int nt = 256 - 32*(p + 1);
      k_syr2k<<<dim3(nt/32, nt/32, 8), 256, 0, stream>>>(p, Vg, Wg, A);
    }
  }
  k_zeroq  <<<dim3(512),     256,  0, stream>>>(QT);
  k_leaves <<<dim3(8),       1024, 0, stream>>>(d_a, e_a, QT, DW);
  {
    const int n1s[4]   = {16, 32, 64, 128};
    const int nmrgs[4] = {8, 4, 2, 1};
    for (int lv = 0; lv < 4; ++lv) {
      int n1 = n1s[lv], nmrg = nmrgs[lv], nn = 2*n1;
      k_mscan<<<dim3(nmrg, 8), 256, 0, stream>>>(n1, e_a, QT, DW, SG, META);
      k_mgemm<<<dim3(nn/32, (nn + 63)/64, nmrg*8), 256, 0, stream>>>(n1, nmrg, QT, SG, META, QNT);
      k_mperm<<<dim3(nmrg, 8), 256, 0, stream>>>(n1, QNT, META, QT);
    }
  }
  k_backxf <<<dim3(16,8),    256, 0, stream>>>(A, tau_a, QT, Vt);
  k_xproj  <<<dim3(32,8,8),  256, 0, stream>>>(x, Vt, xp, noise_out);
  k_qkv    <<<dim3(4,21,8),  256, 0, stream>>>(xp, qkv_w, qkv_b, qkvm);
  k_attn   <<<dim3(128,7,8), 256, 0, stream>>>(qkvm, emb, xp, pool);
  k_owt    <<<dim3(224),     256, 0, stream>>>(out_w, owt);
  k_final  <<<dim3(1024,8),  256, 0, stream>>>(pool, noise_out, sim_w, owt, out);
}

// Round 13
// 7577.493 us; speedup vs baseline: 1.4128x; 1.0858x over previous
//
#include <hip/hip_runtime.h>
#include <math.h>

#define NB  8
#define NPX 16384   // 128*128
#define PPX 1024    // 32*32
#define PNB 32      // dlatrd panel width

// f32 LAPACK machine constants (SLAMCH) used for branch tolerances
#define EPS32   5.9604644775390625e-8   // 2^-24 (slamch 'E')
#define EPS232  (EPS32*EPS32)
#define SAFMIN32 1.1754943508222875e-38

// ---------------- workspace layout (bytes), phase-aliased ----------------
static constexpr size_t OFF_VT   = 0;                    // f32 [8][256][256] 2MB (lives across phases)
static constexpr size_t U        = 0x200000;
static constexpr size_t OFF_A    = U + 0x400000;         // f64 [8][256][256] 4MB gram -> in-place tridiag / reflectors
static constexpr size_t OFF_GP   = U + 0x800000;         // f64 [32][256][256] 16MB gram k-split partials (dead after gsum)
static constexpr size_t OFF_QT   = U + 0x800000;         // f64 [8][256][256] 4MB (aliases GP; first use after panels)
static constexpr size_t OFF_SG   = U + 0xC00000;         // f64 [8][256][256] 4MB
static constexpr size_t OFF_QN   = U + 0x1000000;        // f64 [8][256][256] 4MB
static constexpr size_t OFF_D    = U + 0x1800000;        // f64 [8][256]
static constexpr size_t OFF_E    = U + 0x1804000;        // f64 [8][256]
static constexpr size_t OFF_TAU  = U + 0x1808000;        // f64 [8][256]
static constexpr size_t OFF_DW   = U + 0x180C000;        // f64 [8][256]
static constexpr size_t OFF_META = U + 0x1810000;        // int [8][8][520]
static constexpr size_t OFF_VG   = U + 0x1900000;        // f64 [8][256][32] 512KB panel V
static constexpr size_t OFF_WG   = U + 0x1980000;        // f64 [8][256][32] 512KB panel W
// phase2 aliases:
static constexpr size_t OFF_XP   = U;                    // f32 [8][256][1024] 8MB
static constexpr size_t OFF_QKV  = U + 0x800000;         // f32 [8][672][1024] 21MB
static constexpr size_t OFF_POOL = U + 0x1D00000;        // f32 [8][224][1024] 7MB
static constexpr size_t OFF_OWT  = U + 0x2400000;        // f32 [224][256]

// ================= gram partials: 64x64 register-tiled f64, 4-way k-split =================
// grid (4,4,32): z = ks*8 + b. LDS rows padded to 68 floats (16B-aligned rows -> true b128
// reads, 2-way banks = free); staging writes are aligned float4 along r (2-way = free).
__global__ __launch_bounds__(256) void k_gram(const float* __restrict__ x, double* __restrict__ GP) {
  int jt = blockIdx.x, it = blockIdx.y;
  int z = blockIdx.z;
  int ks = z >> 3, b = z & 7;
  const float* xb = x + (size_t)b*256*NPX;
  int t = threadIdx.x;
  int tx = t & 15, ty = t >> 4;
  __shared__ float xiT[64][68], xjT[64][68];
  double acc[4][4];
  #pragma unroll
  for (int i = 0; i < 4; ++i)
    #pragma unroll
    for (int j = 0; j < 4; ++j) acc[i][j] = 0.0;
  int kb = ks*4096;
  for (int k0 = 0; k0 < 4096; k0 += 64) {
    for (int q = t; q < 1024; q += 256) {
      int c = q & 63, rg = q >> 6;             // c = k-offset (coalesced across lanes), rg = row group
      const float* pi = xb + (size_t)(it*64 + rg*4)*NPX + kb + k0 + c;
      const float* pj = xb + (size_t)(jt*64 + rg*4)*NPX + kb + k0 + c;
      float4 vi, vj;
      vi.x = pi[0]; vi.y = pi[NPX]; vi.z = pi[2*NPX]; vi.w = pi[3*NPX];
      vj.x = pj[0]; vj.y = pj[NPX]; vj.z = pj[2*NPX]; vj.w = pj[3*NPX];
      *(float4*)&xiT[c][rg*4] = vi;
      *(float4*)&xjT[c][rg*4] = vj;
    }
    __syncthreads();
    for (int k = 0; k < 64; ++k) {
      float4 af = *(const float4*)&xiT[k][ty*4];
      float4 bf = *(const float4*)&xjT[k][tx*4];
      double a0 = (double)af.x, a1 = (double)af.y, a2 = (double)af.z, a3 = (double)af.w;
      double b0 = (double)bf.x, b1 = (double)bf.y, b2 = (double)bf.z, b3 = (double)bf.w;
      acc[0][0] += a0*b0; acc[0][1] += a0*b1; acc[0][2] += a0*b2; acc[0][3] += a0*b3;
      acc[1][0] += a1*b0; acc[1][1] += a1*b1; acc[1][2] += a1*b2; acc[1][3] += a1*b3;
      acc[2][0] += a2*b0; acc[2][1] += a2*b1; acc[2][2] += a2*b2; acc[2][3] += a2*b3;
      acc[3][0] += a3*b0; acc[3][1] += a3*b1; acc[3][2] += a3*b2; acc[3][3] += a3*b3;
    }
    __syncthreads();
  }
  double* gp = GP + (size_t)z*65536;
  #pragma unroll
  for (int ii = 0; ii < 4; ++ii)
    #pragma unroll
    for (int jj = 0; jj < 4; ++jj)
      gp[(size_t)(it*64 + ty*4 + ii)*256 + jt*64 + tx*4 + jj] = acc[ii][jj];
}

// A = sum of 4 k-split partials
__global__ __launch_bounds__(256) void k_gsum(const double* __restrict__ GP, double* __restrict__ A) {
  size_t i = (size_t)blockIdx.x*256 + threadIdx.x;
  size_t T = (size_t)NB*65536;
  for (; i < T; i += (size_t)gridDim.x*256)
    A[i] = (GP[i] + GP[i + T]) + (GP[i + 2*T] + GP[i + 3*T]);
}

__device__ __forceinline__ double blkSum16(double v, double* tmp, int t, int nw) {
  #pragma unroll
  for (int m = 1; m <= 32; m <<= 1) v += __shfl_xor(v, m);
  __syncthreads();
  if ((t & 63) == 0) tmp[t >> 6] = v;
  __syncthreads();
  double s = 0.0;
  for (int w = 0; w < nw; ++w) s += tmp[w];
  return s;
}

// ================= blocked tridiagonalization: dlatrd-style panel (nb=32) =================
__global__ __launch_bounds__(1024) void k_panel(int p, double* __restrict__ A,
        double* __restrict__ d_g, double* __restrict__ e_g, double* __restrict__ tau_g,
        double* __restrict__ Vg, double* __restrict__ Wg) {
  int b = blockIdx.x, t = threadIdx.x;
  int g = t >> 8, c = t & 255;
  double* Ab = A + (size_t)b*65536;
  __shared__ double V[256][33], W[256][33];
  __shared__ double vL[256], wL[256], rowCur[256];
  __shared__ double wpart[4][256];
  __shared__ double c12[64];
  __shared__ double tmp[16];
  int jmax = (p == 7) ? 31 : 32;
  for (int j = 0; j < jmax; ++j) {
    int i = p*PNB + j;
    if (g == 0) {
      double rv = 0.0;
      if (c >= i) {
        rv = Ab[(size_t)i*256 + c];
        for (int k = 0; k < j; ++k)
          rv -= V[i][k]*W[c][k] + W[i][k]*V[c][k];
      }
      rowCur[c] = rv;
    }
    __syncthreads();
    double part = 0.0;
    int rx = i + 2 + t;
    if (rx < 256) { double v = rowCur[rx]; part = v*v; }
    double xn2 = blkSum16(part, tmp, t, 16);
    double alpha = rowCur[i + 1];
    double beta, tauv, scale;
    if (xn2 == 0.0) { beta = alpha; tauv = 0.0; scale = 0.0; }
    else {
      beta  = -copysign(sqrt(alpha*alpha + xn2), alpha);
      tauv  = (beta - alpha)/beta;
      scale = 1.0/(alpha - beta);
    }
    if (t == 0) { e_g[b*256 + i] = beta; tau_g[b*256 + i] = tauv; d_g[b*256 + i] = rowCur[i]; }
    if (g == 0) {
      double v = 0.0;
      if (c == i + 1) v = 1.0;
      else if (c >= i + 2) v = rowCur[c]*scale;
      vL[c] = v;
      V[c][j] = v;
      if (c >= i + 1) Ab[(size_t)i*256 + c] = v;
    }
    __syncthreads();
    {
      double s = 0.0;
      if (c >= i + 1) {
        for (int r = i + 1 + g; r < 256; r += 4) s += Ab[(size_t)r*256 + c]*vL[r];
      }
      wpart[g][c] = s;
    }
    {
      int kk = t >> 5, lane = t & 31;
      if (kk < j) {
        double s = 0.0;
        for (int ci2 = lane; ci2 < 256; ci2 += 32) s += W[ci2][kk]*vL[ci2];
        s += __shfl_xor(s, 1); s += __shfl_xor(s, 2); s += __shfl_xor(s, 4);
        s += __shfl_xor(s, 8); s += __shfl_xor(s, 16);
        if (lane == 0) c12[kk] = s;
        double s2 = 0.0;
        for (int ci2 = lane; ci2 < 256; ci2 += 32) s2 += V[ci2][kk]*vL[ci2];
        s2 += __shfl_xor(s2, 1); s2 += __shfl_xor(s2, 2); s2 += __shfl_xor(s2, 4);
        s2 += __shfl_xor(s2, 8); s2 += __shfl_xor(s2, 16);
        if (lane == 0) c12[32 + kk] = s2;
      }
    }
    __syncthreads();
    double wfull = 0.0, part2 = 0.0;
    if (g == 0 && c >= i + 1) {
      double wr = wpart[0][c] + wpart[1][c] + wpart[2][c] + wpart[3][c];
      for (int k = 0; k < j; ++k) wr -= V[c][k]*c12[k] + W[c][k]*c12[32 + k];
      wfull = tauv*wr;
      part2 = vL[c]*wfull;
    }
    double dot = blkSum16(part2, tmp, t, 16);
    double coef = -0.5*tauv*dot;
    if (g == 0) {
      double wv2 = (c >= i + 1) ? (wfull + coef*vL[c]) : 0.0;
      wL[c] = wv2;
      W[c][j] = wv2;
    }
    __syncthreads();
  }
  if (p < 7) {
    for (int idx = t; idx < 256*32; idx += 1024) {
      int cc = idx >> 5, kk = idx & 31;
      Vg[((size_t)b*256 + cc)*32 + kk] = V[cc][kk];
      Wg[((size_t)b*256 + cc)*32 + kk] = W[cc][kk];
    }
  } else {
    if (t == 0) {
      double dv = Ab[(size_t)255*256 + 255];
      for (int k = 0; k < 31; ++k) dv -= 2.0*V[255][k]*W[255][k];
      d_g[b*256 + 255] = dv;
      e_g[b*256 + 255] = 0.0;
    }
  }
}

// ================= trailing update: A -= V W^T + W V^T =================
__global__ __launch_bounds__(256) void k_syr2k(int p, const double* __restrict__ Vg,
        const double* __restrict__ Wg, double* __restrict__ A) {
  int rt = blockIdx.x, ct = blockIdx.y, b = blockIdx.z;
  int base = (p + 1)*32;
  int r0 = base + rt*32, c0 = base + ct*32;
  int t = threadIdx.x;
  __shared__ double Vr[32][33], Wr[32][33], Vc[32][33], Wc[32][33];
  for (int idx = t; idx < 1024; idx += 256) {
    int rr = idx >> 5, kk = idx & 31;
    Vr[rr][kk] = Vg[((size_t)b*256 + r0 + rr)*32 + kk];
    Wr[rr][kk] = Wg[((size_t)b*256 + r0 + rr)*32 + kk];
    Vc[rr][kk] = Vg[((size_t)b*256 + c0 + rr)*32 + kk];
    Wc[rr][kk] = Wg[((size_t)b*256 + c0 + rr)*32 + kk];
  }
  __syncthreads();
  int cl = t & 31, rg = t >> 5;
  double* Ab = A + (size_t)b*65536;
  #pragma unroll
  for (int q = 0; q < 4; ++q) {
    int rl = rg + 8*q;
    double acc = Ab[(size_t)(r0 + rl)*256 + c0 + cl];
    #pragma unroll
    for (int k = 0; k < 32; ++k)
      acc -= Vr[rl][k]*Wc[cl][k] + Wr[rl][k]*Vc[cl][k];
    Ab[(size_t)(r0 + rl)*256 + c0 + cl] = acc;
  }
}

// ================= LAPACK helpers =================
__device__ __forceinline__ void dlartg_(double f, double g, double& c, double& s, double& r) {
  if (g == 0.0) { c = 1.0; s = 0.0; r = f; }
  else if (f == 0.0) { c = 0.0; s = (g > 0.0) ? 1.0 : -1.0; r = fabs(g); }
  else {
    double d = sqrt(f*f + g*g);
    r = (f >= 0.0) ? d : -d;
    c = f / r;
    s = g / r;
  }
}

__device__ void dlaev2_(double a, double b, double cc, double& rt1, double& rt2, double& cs1, double& sn1) {
  double sm = a + cc, df = a - cc;
  double adf = fabs(df), tb = b + b, ab = fabs(tb);
  double acmx, acmn;
  if (fabs(a) > fabs(cc)) { acmx = a; acmn = cc; } else { acmx = cc; acmn = a; }
  double rt;
  if (adf > ab)      rt = adf*sqrt(1.0 + (ab/adf)*(ab/adf));
  else if (adf < ab) rt = ab*sqrt(1.0 + (adf/ab)*(adf/ab));
  else               rt = ab*sqrt(2.0);
  int sgn1;
  if (sm < 0.0)      { rt1 = 0.5*(sm - rt); sgn1 = -1; rt2 = (acmx/rt1)*acmn - (b/rt1)*b; }
  else if (sm > 0.0) { rt1 = 0.5*(sm + rt); sgn1 = 1;  rt2 = (acmx/rt1)*acmn - (b/rt1)*b; }
  else               { rt1 = 0.5*rt; rt2 = -0.5*rt; sgn1 = 1; }
  double cs; int sgn2;
  if (df >= 0.0) { cs = df + rt; sgn2 = 1; } else { cs = df - rt; sgn2 = -1; }
  double acs = fabs(cs);
  if (acs > ab) {
    double ct = -tb/cs;
    sn1 = 1.0/sqrt(1.0 + ct*ct);
    cs1 = ct*sn1;
  } else {
    if (ab == 0.0) { cs1 = 1.0; sn1 = 0.0; }
    else {
      double tn = -cs/tb;
      cs1 = 1.0/sqrt(1.0 + tn*tn);
      sn1 = tn*cs1;
    }
  }
  if (sgn1 == sgn2) { double tn = cs1; cs1 = -sn1; sn1 = tn; }
}

// faithful dsteqr('I') on an n<=16 block; csv/snv buffers supplied (LDS) to keep VGPRs low
__device__ void steqr_leaf(int n, double* d, double* e, double* q, int ldq, double* csv, double* snv) {
  const double eps = EPS32, eps2 = EPS232, safmin = SAFMIN32;
  int nmaxit = n*30, jtot = 0;
  int l1 = 0;
  while (l1 < n) {
    if (l1 > 0) e[l1-1] = 0.0;
    int m;
    for (m = l1; m < n-1; ++m) {
      double tst = fabs(e[m]);
      if (tst == 0.0) break;
      if (tst <= (sqrt(fabs(d[m]))*sqrt(fabs(d[m+1])))*eps) { e[m] = 0.0; break; }
    }
    int l = l1, lend = m;
    l1 = m + 1;
    if (lend == l) continue;
    if (fabs(d[lend]) < fabs(d[l])) { int tsw = l; l = lend; lend = tsw; }
    if (lend > l) {
      while (true) {
        int mm;
        for (mm = l; mm < lend; ++mm) {
          double tst = e[mm]*e[mm];
          if (tst <= (eps2*fabs(d[mm]))*fabs(d[mm+1]) + safmin) break;
        }
        if (mm < lend) e[mm] = 0.0;
        double p = d[l];
        if (mm == l) { l = l + 1; if (l > lend) break; continue; }
        if (mm == l+1) {
          double rt1, rt2, c, s;
          dlaev2_(d[l], e[l], d[l+1], rt1, rt2, c, s);
          for (int i = 0; i < n; ++i) {
            double t1 = q[i*ldq + l+1], t0 = q[i*ldq + l];
            q[i*ldq + l+1] = c*t1 - s*t0;
            q[i*ldq + l]   = s*t1 + c*t0;
          }
          d[l] = rt1; d[l+1] = rt2; e[l] = 0.0;
          l += 2; if (l > lend) break; continue;
        }
        if (jtot == nmaxit) break;
        jtot++;
        double g = (d[l+1] - p)/(2.0*e[l]);
        double r = sqrt(g*g + 1.0);
        g = d[mm] - p + e[l]/(g + copysign(r, g));
        double s = 1.0, c = 1.0; p = 0.0;
        for (int i = mm-1; i >= l; --i) {
          double f = s*e[i], bb = c*e[i];
          dlartg_(g, f, c, s, r);
          if (i != mm-1) e[i+1] = r;
          g = d[i+1] - p;
          r = (d[i] - g)*s + 2.0*c*bb;
          p = s*r;
          d[i+1] = g + p;
          g = c*r - bb;
          csv[i] = c; snv[i] = -s;
        }
        for (int i = mm-1; i >= l; --i) {
          double cc2 = csv[i], ss2 = snv[i];
          for (int k = 0; k < n; ++k) {
            double t1 = q[k*ldq + i+1], t0 = q[k*ldq + i];
            q[k*ldq + i+1] = cc2*t1 - ss2*t0;
            q[k*ldq + i]   = ss2*t1 + cc2*t0;
          }
        }
        d[l] -= p; e[l] = g;
      }
    } else {
      while (true) {
        int mm;
        for (mm = l; mm > lend; --mm) {
          double tst = e[mm-1]*e[mm-1];
          if (tst <= (eps2*fabs(d[mm]))*fabs(d[mm-1]) + safmin) break;
        }
        if (mm > lend) e[mm-1] = 0.0;
        double p = d[l];
        if (mm == l) { l = l - 1; if (l < lend) break; continue; }
        if (mm == l-1) {
          double rt1, rt2, c, s;
          dlaev2_(d[l-1], e[l-1], d[l], rt1, rt2, c, s);
          for (int i = 0; i < n; ++i) {
            double t1 = q[i*ldq + l], t0 = q[i*ldq + l-1];
            q[i*ldq + l]   = c*t1 - s*t0;
            q[i*ldq + l-1] = s*t1 + c*t0;
          }
          d[l-1] = rt1; d[l] = rt2; e[l-1] = 0.0;
          l -= 2; if (l < lend) break; continue;
        }
        if (jtot == nmaxit) break;
        jtot++;
        double g = (d[l-1] - p)/(2.0*e[l-1]);
        double r = sqrt(g*g + 1.0);
        g = d[mm] - p + e[l-1]/(g + copysign(r, g));
        double s = 1.0, c = 1.0; p = 0.0;
        for (int i = mm; i <= l-1; ++i) {
          double f = s*e[i], bb = c*e[i];
          dlartg_(g, f, c, s, r);
          if (i != mm) e[i-1] = r;
          g = d[i] - p;
          r = (d[i+1] - g)*s + 2.0*c*bb;
          p = s*r;
          d[i] = g + p;
          g = c*r - bb;
          csv[i] = c; snv[i] = s;
        }
        for (int i = mm; i <= l-1; ++i) {
          double cc2 = csv[i], ss2 = snv[i];
          for (int k = 0; k < n; ++k) {
            double t1 = q[k*ldq + i+1], t0 = q[k*ldq + i];
            q[k*ldq + i+1] = cc2*t1 - ss2*t0;
            q[k*ldq + i]   = ss2*t1 + cc2*t0;
          }
        }
        d[l] -= p; e[l-1] = g;
      }
    }
  }
  for (int ii = 1; ii < n; ++ii) {
    int k = ii - 1; double p = d[k];
    for (int j = ii; j < n; ++j) if (d[j] < p) { k = j; p = d[j]; }
    if (k != ii-1) {
      d[k] = d[ii-1]; d[ii-1] = p;
      for (int r = 0; r < n; ++r) { double tq = q[r*ldq + ii-1]; q[r*ldq + ii-1] = q[r*ldq + k]; q[r*ldq + k] = tq; }
    }
  }
}

__global__ __launch_bounds__(256) void k_zeroq(double* __restrict__ QT) {
  size_t i = (size_t)blockIdx.x*256 + threadIdx.x;
  size_t total = (size_t)NB*65536;
  for (; i < total; i += (size_t)gridDim.x*256) QT[i] = 0.0;
}

// ================= leaves: one ssteqr(16) per WAVE =================
__global__ __launch_bounds__(1024) void k_leaves(const double* __restrict__ d_g, const double* __restrict__ e_g,
        double* __restrict__ QT, double* __restrict__ DW) {
  int b = blockIdx.x, t = threadIdx.x;
  __shared__ double dL[256], eL[256];
  __shared__ double ql[16*272];
  __shared__ double csb[16*16], snb[16*16];
  if (t < 256) { dL[t] = d_g[b*256 + t]; eL[t] = e_g[b*256 + t]; }
  __syncthreads();
  if (t == 0) {
    for (int cut = 16; cut < 256; cut += 16) {
      double a = fabs(eL[cut-1]);
      dL[cut-1] -= a; dL[cut] -= a;
    }
  }
  __syncthreads();
  int w = t >> 6, lane = t & 63;
  if (lane == 0) {
    double* q = &ql[w*272];
    for (int i = 0; i < 16; ++i)
      for (int j = 0; j < 16; ++j) q[i*17 + j] = (i == j) ? 1.0 : 0.0;
    steqr_leaf(16, dL + 16*w, eL + 16*w, q, 17, &csb[w*16], &snb[w*16]);
  }
  __syncthreads();
  for (int idx = t; idx < 4096; idx += 1024) {
    int lf = idx >> 8, i = (idx >> 4) & 15, j = idx & 15;
    QT[(size_t)b*65536 + (size_t)(lf*16 + j)*256 + lf*16 + i] = ql[lf*272 + i*17 + j];
  }
  if (t < 256) DW[b*256 + t] = dL[t];
}

// ================= merge phase 1: scan + rotations + secular + S =================
__global__ __launch_bounds__(256) void k_mscan(int n1, const double* __restrict__ e_g,
        double* __restrict__ QT, double* __restrict__ DW, double* __restrict__ SG, int* __restrict__ META) {
  int mrg = blockIdx.x, b = blockIdx.y, t = threadIdx.x;
  int nn = 2*n1, r0 = mrg*nn;
  double* Q = QT + (size_t)b*65536;
  double* Sg = SG + (size_t)b*65536;
  int* meta = META + ((b*8 + mrg)*520);
  __shared__ double dloc[256], zloc[256], dlam[256], wv[256], w2[256], tauv[256], zh[256], dfin[256];
  __shared__ int indx[256], indxp[256], permf[256];
  __shared__ double rotc[256], rots[256];
  __shared__ short rotp[256], rotq[256];
  __shared__ int KK[3];
  __shared__ double sc[2];
  double rho_raw = e_g[b*256 + r0 + n1 - 1];
  if (t < nn) {
    dloc[t] = DW[b*256 + r0 + t];
    double zv = Q[(size_t)(r0 + t)*256 + r0 + ((t < n1) ? (n1 - 1) : n1)];
    if (t >= n1 && rho_raw < 0.0) zv = -zv;
    zloc[t] = zv * 0.70710678118654752440;
  }
  __syncthreads();
  if (t == 0) {
    int i = 0, jj = n1, pos = 0;
    while (i < n1 && jj < nn) { if (dloc[i] <= dloc[jj]) indx[pos++] = i++; else indx[pos++] = jj++; }
    while (i < n1) indx[pos++] = i++;
    while (jj < nn) indx[pos++] = jj++;
    double maxd = 0.0, maxz = 0.0;
    for (int q2 = 0; q2 < nn; ++q2) { maxd = fmax(maxd, fabs(dloc[q2])); maxz = fmax(maxz, fabs(zloc[q2])); }
    double rho = fabs(2.0*rho_raw);
    double tol = 8.0*EPS32*fmax(maxd, maxz);
    int K = 0, K2 = nn, nrot = 0, pj = -1, j = 0;
    for (; j < nn; ++j) {
      int nj = indx[j];
      if (rho*fabs(zloc[nj]) <= tol) { K2--; indxp[K2] = nj; }
      else { pj = nj; break; }
    }
    if (pj >= 0) {
      for (++j; j < nn; ++j) {
        int nj = indx[j];
        if (rho*fabs(zloc[nj]) <= tol) { K2--; indxp[K2] = nj; }
        else {
          double s = zloc[pj], c = zloc[nj];
          double tau = sqrt(c*c + s*s);
          double tdf = dloc[nj] - dloc[pj];
          c /= tau; s = -s/tau;
          if (fabs(tdf*c*s) <= tol) {
            zloc[nj] = tau; zloc[pj] = 0.0;
            rotp[nrot] = (short)pj; rotq[nrot] = (short)nj; rotc[nrot] = c; rots[nrot] = s; nrot++;
            double tt2 = dloc[pj]*c*c + dloc[nj]*s*s;
            dloc[nj] = dloc[pj]*s*s + dloc[nj]*c*c;
            dloc[pj] = tt2;
            K2--;
            int ii2 = 1;
            while (K2 + ii2 <= nn - 1 && dloc[pj] < dloc[indxp[K2 + ii2]]) { indxp[K2+ii2-1] = indxp[K2+ii2]; ii2++; }
            indxp[K2+ii2-1] = pj;
            pj = nj;
          } else {
            dlam[K] = dloc[pj]; wv[K] = zloc[pj]; indxp[K] = pj; K++;
            pj = nj;
          }
        }
      }
      dlam[K] = dloc[pj]; wv[K] = zloc[pj]; indxp[K] = pj; K++;
    }
    double sumw2 = 0.0;
    for (int q2 = 0; q2 < K; ++q2) sumw2 += wv[q2]*wv[q2];
    KK[0] = K; KK[1] = K2; KK[2] = nrot; sc[0] = rho; sc[1] = sumw2;
  }
  __syncthreads();
  int K = KK[0], K2 = KK[1], nrot = KK[2];
  double rho = sc[0], sumw2 = sc[1];
  if (t < nn) {
    for (int k = 0; k < nrot; ++k) {
      int p = rotp[k], q = rotq[k];
      double c = rotc[k], s = rots[k];
      size_t ip = (size_t)(r0 + p)*256 + r0 + t;
      size_t iq = (size_t)(r0 + q)*256 + r0 + t;
      double xq = Q[ip], yq = Q[iq];
      Q[ip] = c*xq + s*yq;
      Q[iq] = c*yq - s*xq;
    }
  }
  if (t < K) w2[t] = rho*wv[t]*wv[t];
  __syncthreads();
  if (t < K) {
    double dj = dlam[t];
    double hi0 = (t < K-1) ? (dlam[t+1] - dj) : rho*sumw2;
    double lo = 0.0, hi = hi0;
    for (int it = 0; it < 64; ++it) {
      double mid = 0.5*(lo + hi);
      double f = 1.0;
      for (int j2 = 0; j2 < K; ++j2) f += w2[j2]/((dlam[j2] - dj) - mid);
      if (f < 0.0) lo = mid; else hi = mid;
    }
    double tl = 0.5*(lo + hi);
    if (tl <= 0.0) tl = hi0*1e-300;
    tauv[t] = tl;
  }
  __syncthreads();
  if (t < K) {
    double dt2 = dlam[t], p = tauv[t];
    for (int i = 0; i < K; ++i) { if (i == t) continue; double del = dlam[i] - dt2; p *= (del + tauv[i])/del; }
    zh[t] = copysign(sqrt(fabs(p)), wv[t]);
  }
  __syncthreads();
  if (t < K) {
    double dj = dlam[t], tj = tauv[t];
    double nrm = 0.0;
    for (int i = 0; i < K; ++i) { double sij = zh[i]/((dlam[i] - dj) - tj); nrm += sij*sij; }
    double inv = 1.0/sqrt(nrm);
    for (int i = 0; i < K; ++i) Sg[(size_t)(r0 + i)*256 + t] = (zh[i]/((dlam[i] - dj) - tj))*inv;
  }
  __syncthreads();
  if (t == 0) {
    int i = 0, p = nn - 1, f = 0;
    while (f < nn) {
      bool takesec;
      if (i < K && p >= K2) takesec = ((dlam[i] + tauv[i]) <= dloc[indxp[p]]);
      else takesec = (i < K);
      if (takesec) { dfin[f] = dlam[i] + tauv[i]; permf[f] = i; i++; }
      else         { dfin[f] = dloc[indxp[p]];    permf[f] = K + (p - K2); p--; }
      f++;
    }
    for (f = 0; f < nn; ++f) DW[b*256 + r0 + f] = dfin[f];
    meta[0] = K; meta[1] = K2;
  }
  __syncthreads();
  if (t < nn) { meta[2 + t] = indxp[t]; meta[258 + t] = permf[t]; }
}

// ================= merge phase 2 =================
__global__ __launch_bounds__(256) void k_mgemm(int n1, int nmrg, const double* __restrict__ QT,
        const double* __restrict__ SG, const int* __restrict__ META, double* __restrict__ QNT) {
  int nn = 2*n1;
  int jt = blockIdx.x, rt = blockIdx.y;
  int z = blockIdx.z;
  int mrg = z % nmrg, b = z / nmrg;
  int r0 = mrg*nn;
  int t = threadIdx.x;
  const int* meta = META + ((b*8 + mrg)*520);
  __shared__ int sindxp[256];
  __shared__ double Gs[32][66];
  __shared__ double Ss[32][33];
  const double* Q = QT + (size_t)b*65536;
  const double* Sg = SG + (size_t)b*65536;
  double* Qn = QNT + (size_t)b*65536;
  int K = meta[0], K2 = meta[1];
  if (t < nn) sindxp[t] = meta[2 + t];
  __syncthreads();
  int jl = t >> 6, rl = t & 63;
  int r = rt*64 + rl;
  double acc[8];
  #pragma unroll
  for (int q = 0; q < 8; ++q) acc[q] = 0.0;
  if (jt*32 < K) {
    for (int i0 = 0; i0 < K; i0 += 32) {
      #pragma unroll
      for (int w = 0; w < 8; ++w) {
        int idx = t + 256*w;
        int ii = idx >> 6, rr = idx & 63;
        double v = 0.0;
        if (i0 + ii < K && rt*64 + rr < nn)
          v = Q[(size_t)(r0 + sindxp[i0 + ii])*256 + r0 + rt*64 + rr];
        Gs[ii][rr] = v;
      }
      #pragma unroll
      for (int w = 0; w < 4; ++w) {
        int idx = t + 256*w;
        int ii2 = idx >> 5, jj = idx & 31;
        double v = 0.0;
        if (i0 + ii2 < K)
          v = Sg[(size_t)(r0 + i0 + ii2)*256 + jt*32 + jj];
        Ss[ii2][jj] = v;
      }
      __syncthreads();
      int kmax = (K - i0 < 32) ? (K - i0) : 32;
      for (int ii = 0; ii < kmax; ++ii) {
        double gv = Gs[ii][rl];
        #pragma unroll
        for (int q = 0; q < 8; ++q) acc[q] += Ss[ii][jl + 4*q] * gv;
      }
      __syncthreads();
    }
  }
  if (r < nn) {
    #pragma unroll
    for (int q = 0; q < 8; ++q) {
      int j = jt*32 + jl + 4*q;
      if (j < K) Qn[(size_t)(r0 + j)*256 + r0 + r] = acc[q];
      else if (j < nn) {
        int p = K2 + (j - K);
        Qn[(size_t)(r0 + j)*256 + r0 + r] = Q[(size_t)(r0 + sindxp[p])*256 + r0 + r];
      }
    }
  }
}

// ================= merge phase 3 =================
__global__ __launch_bounds__(256) void k_mperm(int n1, const double* __restrict__ QNT,
        const int* __restrict__ META, double* __restrict__ QT) {
  int mrg = blockIdx.x, b = blockIdx.y, t = threadIdx.x;
  int nn = 2*n1, r0 = mrg*nn;
  const int* meta = META + ((b*8 + mrg)*520);
  __shared__ int pf[256];
  if (t < nn) pf[t] = meta[258 + t];
  __syncthreads();
  if (t < nn) {
    for (int f = 0; f < nn; ++f)
      QT[(size_t)b*65536 + (size_t)(r0 + f)*256 + r0 + t] =
        QNT[(size_t)b*65536 + (size_t)(r0 + pf[f])*256 + r0 + t];
  }
}

// ================= back-transform, LDS-tiled: emit Vt (f32) directly =================
__global__ __launch_bounds__(256) void k_backxf(const double* __restrict__ A, const double* __restrict__ tau_g,
        const double* __restrict__ QT, float* __restrict__ Vt) {
  int g = blockIdx.x, b = blockIdx.y;
  int t = threadIdx.x;
  int e = t >> 4, l = t & 15;
  __shared__ double zt[16][264];
  __shared__ double vL[256];
  __shared__ double tauL[256];
  const double* Ab = A + (size_t)b*65536;
  const double* Qb = QT + (size_t)b*65536 + (size_t)g*16*256;
  #pragma unroll
  for (int w = 0; w < 16; ++w) {
    int idx = t + 256*w;
    int ee = idx >> 8, rr = idx & 255;
    zt[ee][rr] = Qb[(size_t)ee*256 + rr];
  }
  tauL[t] = tau_g[b*256 + t];
  __syncthreads();
  for (int s = 253; s >= 0; --s) {
    if (t == 0) vL[s+1] = 1.0;
    int rx = s + 2 + t;
    if (rx < 256) vL[rx] = Ab[s*256 + rx];
    __syncthreads();
    double tauv = tauL[s];
    if (tauv != 0.0) {
      double acc = 0.0;
      for (int rr = s + 1 + l; rr < 256; rr += 16) acc += vL[rr]*zt[e][rr];
      acc += __shfl_xor(acc, 1);
      acc += __shfl_xor(acc, 2);
      acc += __shfl_xor(acc, 4);
      acc += __shfl_xor(acc, 8);
      double tw = tauv*acc;
      for (int rr = s + 1 + l; rr < 256; rr += 16) zt[e][rr] -= tw*vL[rr];
    }
    __syncthreads();
  }
  float* vtb = Vt + ((size_t)b*256 + (size_t)g*16)*256;
  #pragma unroll
  for (int w = 0; w < 16; ++w) {
    int idx = t + 256*w;
    int ee = idx >> 8, rr = idx & 255;
    vtb[(size_t)ee*256 + rr] = (float)zt[ee][rr];
  }
}

// ================= x_proj = V x, + x, fused maxpool + noise output =================
__global__ __launch_bounds__(256) void k_xproj(const float* __restrict__ x, const float* __restrict__ Vt,
        float* __restrict__ xp, float* __restrict__ noise_out) {
  int R = blockIdx.x, ct = blockIdx.y, b = blockIdx.z;
  int t = threadIdx.x;
  int cl = t >> 3, l8 = t & 7;
  __shared__ float vsh[32][20];
  __shared__ float xs[16][520];
  const float* xb = x + (size_t)b*256*NPX;
  int s0 = R*512;
  float acc[64];
  #pragma unroll
  for (int p = 0; p < 64; ++p) acc[p] = 0.0f;
  for (int d0 = 0; d0 < 256; d0 += 16) {
    for (int q = t; q < 512; q += 256) {
      int c = q >> 4, dd = q & 15;
      vsh[c][dd] = Vt[((size_t)b*256 + ct*32 + c)*256 + d0 + dd];
    }
    for (int q = t; q < 8192; q += 256) {
      int dd = q >> 9, px = q & 511;
      xs[dd][px] = xb[(size_t)(d0 + dd)*NPX + s0 + px];
    }
    __syncthreads();
    for (int dd = 0; dd < 16; ++dd) {
      float a = vsh[cl][dd];
      const float* xr = &xs[dd][l8];
      #pragma unroll
      for (int p = 0; p < 64; ++p) acc[p] += a*xr[8*p];
    }
    __syncthreads();
  }
  int cg = ct*32 + cl;
  const float* xc = xb + (size_t)cg*NPX + s0;
  float vmax[16];
  #pragma unroll
  for (int j = 0; j < 16; ++j) vmax[j] = -3.0e38f;
  bool isnz = (ct == 0);
  #pragma unroll
  for (int p = 0; p < 64; ++p) {
    int px = l8 + 8*p;
    float val = acc[p] + xc[px];
    vmax[p & 15] = fmaxf(vmax[p & 15], val);
    if (isnz) noise_out[((size_t)b*32 + cl)*NPX + s0 + px] = val;
  }
  #pragma unroll
  for (int j = 0; j < 16; ++j) {
    float v = vmax[j];
    v = fmaxf(v, __shfl_xor(v, 1));
    v = fmaxf(v, __shfl_xor(v, 2));
    vmax[j] = v;
  }
  if ((l8 & 3) == 0) {
    int halfsel = l8 >> 2;
    #pragma unroll
    for (int j = 0; j < 16; ++j)
      xp[((size_t)b*256 + cg)*PPX + R*32 + 2*j + halfsel] = vmax[j];
  }
}

// ================= qkv 1x1 conv (672 needed rows) =================
__global__ __launch_bounds__(256) void k_qkv(const float* __restrict__ xp, const float* __restrict__ wq,
        const float* __restrict__ bq, float* __restrict__ qkvm) {
  int pt = blockIdx.x, ot = blockIdx.y, b = blockIdx.z;
  int t = threadIdx.x;
  int ol = t & 31, pg = t >> 5;
  __shared__ float wsh[32][9];
  __shared__ float xsh[8][260];
  float acc[32];
  #pragma unroll
  for (int j = 0; j < 32; ++j) acc[j] = 0.0f;
  for (int ic0 = 0; ic0 < 256; ic0 += 8) {
    {
      int o = t >> 3, j = t & 7;
      int orow = ot*32 + o;
      int reg = orow/224, rem = orow - reg*224;
      int wrow = 32 + rem + 256*reg;
      wsh[o][j] = wq[(size_t)wrow*256 + ic0 + j];
    }
    for (int q = t; q < 2048; q += 256) {
      int ic = q >> 8, px = q & 255;
      xsh[ic][px] = xp[((size_t)b*256 + ic0 + ic)*PPX + pt*256 + px];
    }
    __syncthreads();
    for (int ic = 0; ic < 8; ++ic) {
      float a = wsh[ol][ic];
      const float* xr = &xsh[ic][pg];
      #pragma unroll
      for (int j = 0; j < 32; ++j) acc[j] += a*xr[8*j];
    }
    __syncthreads();
  }
  int orow = ot*32 + ol;
  int reg = orow/224, rem = orow - reg*224;
  float bv = bq[32 + rem + 256*reg];
  #pragma unroll
  for (int j = 0; j < 32; ++j)
    qkvm[((size_t)b*672 + orow)*PPX + pt*256 + pg + 8*j] = acc[j] + bv;
}

// ================= attention =================
__global__ __launch_bounds__(256) void k_attn(const float* __restrict__ qkvm, const float* __restrict__ emb,
        const float* __restrict__ xp, float* __restrict__ pool) {
  int rt = blockIdx.x, n = blockIdx.y, b = blockIdx.z;
  int t = threadIdx.x;
  int rl = t >> 5, pg = t & 31;
  __shared__ float S[8][1032];
  __shared__ float qsh[8][33];
  __shared__ float kv[4224];
  const float* qb = qkvm + (size_t)b*672*PPX;
  int rg0 = rt*8;
  {
    int rg = rg0 + rl;
    float qv = qb[(size_t)(32*n + (rg >> 5))*PPX + ((rg & 31) << 5) + pg];
    float ev = emb[(((size_t)n*8 + b)*1024 + rg)*32 + pg];
    qsh[rl][pg] = (qv + ev)*0.17677669529663688f;
  }
  __syncthreads();
  const float* kb = qb + (size_t)(224 + 32*n)*PPX;
  for (int p0 = 0; p0 < 1024; p0 += 128) {
    for (int q = t; q < 4096; q += 256) {
      int c = q >> 7, pp = q & 127;
      kv[c*132 + pp] = kb[(size_t)c*PPX + p0 + pp];
    }
    __syncthreads();
    float a0 = 0, a1 = 0, a2 = 0, a3 = 0;
    for (int c = 0; c < 32; ++c) {
      float qv = qsh[rl][c];
      const float* kr = &kv[c*132 + pg];
      a0 += qv*kr[0]; a1 += qv*kr[32]; a2 += qv*kr[64]; a3 += qv*kr[96];
    }
    S[rl][p0 + pg]      = a0;
    S[rl][p0 + pg + 32] = a1;
    S[rl][p0 + pg + 64] = a2;
    S[rl][p0 + pg + 96] = a3;
    __syncthreads();
  }
  float mx = -3.0e38f;
  for (int j = 0; j < 32; ++j) mx = fmaxf(mx, S[rl][pg + 32*j]);
  #pragma unroll
  for (int m = 1; m <= 16; m <<= 1) mx = fmaxf(mx, __shfl_xor(mx, m));
  float sum = 0.0f;
  for (int j = 0; j < 32; ++j) {
    float e = expf(S[rl][pg + 32*j] - mx);
    S[rl][pg + 32*j] = e;
    sum += e;
  }
  #pragma unroll
  for (int m = 1; m <= 16; m <<= 1) sum += __shfl_xor(sum, m);
  float inv = 1.0f/sum;
  for (int j = 0; j < 32; ++j) S[rl][pg + 32*j] *= inv;
  __syncthreads();
  const float* vb = qb + (size_t)(448 + 32*n)*PPX;
  float acc = 0.0f;
  for (int p0 = 0; p0 < 1024; p0 += 128) {
    for (int q = t; q < 4096; q += 256) {
      int pp = q >> 5, c = q & 31;
      int p = p0 + pp;
      kv[pp*33 + c] = vb[(size_t)(p >> 5)*PPX + ((p & 31) << 5) + c];
    }
    __syncthreads();
    for (int pp = 0; pp < 128; ++pp) acc += S[rl][p0 + pp]*kv[pp*33 + pg];
    __syncthreads();
  }
  int rg = rg0 + rl;
  int ch = 32*n + (rg >> 5);
  size_t sp = (size_t)((rg & 31) << 5) + pg;
  pool[((size_t)b*224 + ch)*PPX + sp] = acc + xp[((size_t)b*256 + 32 + ch)*PPX + sp];
}

__global__ void k_owt(const float* __restrict__ ow, float* __restrict__ owt) {
  int t = blockIdx.x*256 + threadIdx.x;
  if (t < 256*224) {
    int oc = t/224, ch = t - oc*224;
    owt[(size_t)ch*256 + oc] = ow[t];
  }
}

// ================= bilinear + sim gating + final conv =================
__global__ __launch_bounds__(256) void k_final(const float* __restrict__ pool, const float* __restrict__ noise,
        const float* __restrict__ sim_w, const float* __restrict__ owt, float* __restrict__ out) {
  int tt = blockIdx.x, b = blockIdx.y;
  int t = threadIdx.x;
  int h = tt >> 3, w0 = (tt & 7)*16;
  __shared__ float xa[224][20];
  __shared__ float nsc[224][20];
  __shared__ float nz[32][20];
  __shared__ float scl[16];
  for (int q = t; q < 512; q += 256) {
    int c = q >> 4, px = q & 15;
    nz[c][px] = noise[((size_t)b*32 + c)*NPX + h*128 + w0 + px];
  }
  float hs = h*0.25f - 0.375f;
  float hf = floorf(hs);
  int h0 = (int)hf;
  float fh = hs - hf;
  int h0c = min(max(h0, 0), 31);
  int h1c = min(max(h0 + 1, 0), 31);
  __syncthreads();
  for (int q = t; q < 3584; q += 256) {
    int c = q >> 4, px = q & 15;
    int w = w0 + px;
    float wsrc = w*0.25f - 0.375f;
    float wf = floorf(wsrc);
    int W0 = (int)wf;
    float fw = wsrc - wf;
    int w0c = min(max(W0, 0), 31);
    int w1c = min(max(W0 + 1, 0), 31);
    const float* pb = pool + ((size_t)b*224 + c)*PPX;
    float v00 = pb[h0c*32 + w0c], v01 = pb[h0c*32 + w1c];
    float v10 = pb[h1c*32 + w0c], v11 = pb[h1c*32 + w1c];
    xa[c][px] = (1.0f - fh)*((1.0f - fw)*v00 + fw*v01) + fh*((1.0f - fw)*v10 + fw*v11);
    float np = 0.0f;
    #pragma unroll
    for (int j = 0; j < 32; ++j) np += sim_w[c*32 + j]*nz[j][px];
    nsc[c][px] = np;
  }
  __syncthreads();
  {
    int px = t >> 4, kk = t & 15;
    float s1 = 0, s2 = 0, s3 = 0;
    for (int c = kk; c < 224; c += 16) {
      float a = xa[c][px], p = nsc[c][px];
      s1 += a*a; s2 += p*p; s3 += a*p;
    }
    #pragma unroll
    for (int m = 1; m <= 8; m <<= 1) {
      s1 += __shfl_xor(s1, m);
      s2 += __shfl_xor(s2, m);
      s3 += __shfl_xor(s3, m);
    }
    if (kk == 0) {
      float n1 = fmaxf(sqrtf(s1), 1e-12f);
      float n2 = fmaxf(sqrtf(s2), 1e-12f);
      float sim = (s3/(n1*n2) + 1.0f)*0.5f;
      scl[px] = 1.0f - sim;
    }
  }
  __syncthreads();
  {
    float accp[16];
    #pragma unroll
    for (int px = 0; px < 16; ++px) accp[px] = 0.0f;
    for (int c = 0; c < 224; ++c) {
      float wv = owt[(size_t)c*256 + t];
      #pragma unroll
      for (int px = 0; px < 16; ++px) accp[px] += wv*xa[c][px];
    }
    size_t obase = ((size_t)b*256 + t)*NPX + (size_t)h*128 + w0;
    #pragma unroll
    for (int px = 0; px < 16; ++px) out[obase + px] = accp[px]*scl[px];
  }
  if (b == 0 && tt == 0 && t == 0) out[(size_t)33554432] = 8.0f;   // AVG_K
}

extern "C" void kernel_launch(void* const* d_in, const int* in_sizes, int n_in,
                              void* d_out, int out_size, void* d_ws, size_t ws_size,
                              hipStream_t stream) {
  (void)in_sizes; (void)n_in; (void)out_size; (void)ws_size;
  const float* x     = (const float*)d_in[0];
  const float* qkv_w = (const float*)d_in[1];
  const float* qkv_b = (const float*)d_in[2];
  const float* emb   = (const float*)d_in[3];
  const float* sim_w = (const float*)d_in[4];
  const float* out_w = (const float*)d_in[5];
  float* out = (float*)d_out;
  char* ws = (char*)d_ws;
  double* A    = (double*)(ws + OFF_A);
  double* GP   = (double*)(ws + OFF_GP);
  double* QT   = (double*)(ws + OFF_QT);
  double* SG   = (double*)(ws + OFF_SG);
  double* QNT  = (double*)(ws + OFF_QN);
  double* d_a  = (double*)(ws + OFF_D);
  double* e_a  = (double*)(ws + OFF_E);
  double* tau_a= (double*)(ws + OFF_TAU);
  double* DW   = (double*)(ws + OFF_DW);
  int*    META = (int*)   (ws + OFF_META);
  double* Vg   = (double*)(ws + OFF_VG);
  double* Wg   = (double*)(ws + OFF_WG);
  float*  Vt   = (float*) (ws + OFF_VT);
  float*  xp   = (float*) (ws + OFF_XP);
  float*  qkvm = (float*) (ws + OFF_QKV);
  float*  pool = (float*) (ws + OFF_POOL);
  float*  owt  = (float*) (ws + OFF_OWT);
  float*  noise_out = out + 33554433;

  k_gram <<<dim3(4,4,32), 256, 0, stream>>>(x, GP);
  k_gsum <<<dim3(512),    256, 0, stream>>>(GP, A);
  for (int p = 0; p < 8; ++p) {
    k_panel<<<dim3(8), 1024, 0, stream>>>(p, A, d_a, e_a, tau_a, Vg, Wg);
    if (p < 7) {
      int nt = 256 - 32*(p + 1);
      k_syr2k<<<dim3(nt/32, nt/32, 8), 256, 0, stream>>>(p, Vg, Wg, A);
    }
  }
  k_zeroq  <<<dim3(512),     256,  0, stream>>>(QT);
  k_leaves <<<dim3(8),       1024, 0, stream>>>(d_a, e_a, QT, DW);
  {
    const int n1s[4]   = {16, 32, 64, 128};
    const int nmrgs[4] = {8, 4, 2, 1};
    for (int lv = 0; lv < 4; ++lv) {
      int n1 = n1s[lv], nmrg = nmrgs[lv], nn = 2*n1;
      k_mscan<<<dim3(nmrg, 8), 256, 0, stream>>>(n1, e_a, QT, DW, SG, META);
      k_mgemm<<<dim3(nn/32, (nn + 63)/64, nmrg*8), 256, 0, stream>>>(n1, nmrg, QT, SG, META, QNT);
      k_mperm<<<dim3(nmrg, 8), 256, 0, stream>>>(n1, QNT, META, QT);
    }
  }
  k_backxf <<<dim3(16,8),    256, 0, stream>>>(A, tau_a, QT, Vt);
  k_xproj  <<<dim3(32,8,8),  256, 0, stream>>>(x, Vt, xp, noise_out);
  k_qkv    <<<dim3(4,21,8),  256, 0, stream>>>(xp, qkv_w, qkv_b, qkvm);
  k_attn   <<<dim3(128,7,8), 256, 0, stream>>>(qkvm, emb, xp, pool);
  k_owt    <<<dim3(224),     256, 0, stream>>>(out_w, owt);
  k_final  <<<dim3(1024,8),  256, 0, stream>>>(pool, noise_out, sim_w, owt, out);
}

// Round 14
// 6821.722 us; speedup vs baseline: 1.5693x; 1.1108x over previous
//
#include <hip/hip_runtime.h>
#include <math.h>

#define NB  8
#define NPX 16384   // 128*128
#define PPX 1024    // 32*32
#define PNB 32      // dlatrd panel width

// f32 LAPACK machine constants (SLAMCH) used for branch tolerances
#define EPS32   5.9604644775390625e-8   // 2^-24 (slamch 'E')
#define EPS232  (EPS32*EPS32)
#define SAFMIN32 1.1754943508222875e-38

// ---------------- workspace layout (bytes), phase-aliased ----------------
static constexpr size_t OFF_VT   = 0;                    // f32 [8][256][256] 2MB (lives across phases)
static constexpr size_t U        = 0x200000;
static constexpr size_t OFF_A    = U + 0x400000;         // f64 [8][256][256] 4MB gram -> in-place tridiag / reflectors
static constexpr size_t OFF_GP   = U + 0x800000;         // f64 [32][256][256] 16MB gram k-split partials (dead after gsum)
static constexpr size_t OFF_QT   = U + 0x800000;         // f64 [8][256][256] 4MB (aliases GP; first use after panels)
static constexpr size_t OFF_SG   = U + 0xC00000;         // f64 [8][256][256] 4MB
static constexpr size_t OFF_QN   = U + 0x1000000;        // f64 [8][256][256] 4MB
static constexpr size_t OFF_D    = U + 0x1800000;        // f64 [8][256]
static constexpr size_t OFF_E    = U + 0x1804000;        // f64 [8][256]
static constexpr size_t OFF_TAU  = U + 0x1808000;        // f64 [8][256]
static constexpr size_t OFF_DW   = U + 0x180C000;        // f64 [8][256]
static constexpr size_t OFF_META = U + 0x1810000;        // int [8][8][520]
static constexpr size_t OFF_VG   = U + 0x1900000;        // f64 [8][256][32] 512KB panel V
static constexpr size_t OFF_WG   = U + 0x1980000;        // f64 [8][256][32] 512KB panel W
// phase2 aliases:
static constexpr size_t OFF_XP   = U;                    // f32 [8][256][1024] 8MB
static constexpr size_t OFF_QKV  = U + 0x800000;         // f32 [8][672][1024] 21MB
static constexpr size_t OFF_POOL = U + 0x1D00000;        // f32 [8][224][1024] 7MB
static constexpr size_t OFF_OWT  = U + 0x2400000;        // f32 [224][256]

// ================= gram partials: 64x64 register-tiled f64, 4-way k-split =================
__global__ __launch_bounds__(256) void k_gram(const float* __restrict__ x, double* __restrict__ GP) {
  int jt = blockIdx.x, it = blockIdx.y;
  int z = blockIdx.z;
  int ks = z >> 3, b = z & 7;
  const float* xb = x + (size_t)b*256*NPX;
  int t = threadIdx.x;
  int tx = t & 15, ty = t >> 4;
  __shared__ float xiT[64][68], xjT[64][68];
  double acc[4][4];
  #pragma unroll
  for (int i = 0; i < 4; ++i)
    #pragma unroll
    for (int j = 0; j < 4; ++j) acc[i][j] = 0.0;
  int kb = ks*4096;
  for (int k0 = 0; k0 < 4096; k0 += 64) {
    for (int q = t; q < 1024; q += 256) {
      int c = q & 63, rg = q >> 6;
      const float* pi = xb + (size_t)(it*64 + rg*4)*NPX + kb + k0 + c;
      const float* pj = xb + (size_t)(jt*64 + rg*4)*NPX + kb + k0 + c;
      float4 vi, vj;
      vi.x = pi[0]; vi.y = pi[NPX]; vi.z = pi[2*NPX]; vi.w = pi[3*NPX];
      vj.x = pj[0]; vj.y = pj[NPX]; vj.z = pj[2*NPX]; vj.w = pj[3*NPX];
      *(float4*)&xiT[c][rg*4] = vi;
      *(float4*)&xjT[c][rg*4] = vj;
    }
    __syncthreads();
    for (int k = 0; k < 64; ++k) {
      float4 af = *(const float4*)&xiT[k][ty*4];
      float4 bf = *(const float4*)&xjT[k][tx*4];
      double a0 = (double)af.x, a1 = (double)af.y, a2 = (double)af.z, a3 = (double)af.w;
      double b0 = (double)bf.x, b1 = (double)bf.y, b2 = (double)bf.z, b3 = (double)bf.w;
      acc[0][0] += a0*b0; acc[0][1] += a0*b1; acc[0][2] += a0*b2; acc[0][3] += a0*b3;
      acc[1][0] += a1*b0; acc[1][1] += a1*b1; acc[1][2] += a1*b2; acc[1][3] += a1*b3;
      acc[2][0] += a2*b0; acc[2][1] += a2*b1; acc[2][2] += a2*b2; acc[2][3] += a2*b3;
      acc[3][0] += a3*b0; acc[3][1] += a3*b1; acc[3][2] += a3*b2; acc[3][3] += a3*b3;
    }
    __syncthreads();
  }
  double* gp = GP + (size_t)z*65536;
  #pragma unroll
  for (int ii = 0; ii < 4; ++ii)
    #pragma unroll
    for (int jj = 0; jj < 4; ++jj)
      gp[(size_t)(it*64 + ty*4 + ii)*256 + jt*64 + tx*4 + jj] = acc[ii][jj];
}

// A = sum of 4 k-split partials
__global__ __launch_bounds__(256) void k_gsum(const double* __restrict__ GP, double* __restrict__ A) {
  size_t i = (size_t)blockIdx.x*256 + threadIdx.x;
  size_t T = (size_t)NB*65536;
  for (; i < T; i += (size_t)gridDim.x*256)
    A[i] = (GP[i] + GP[i + T]) + (GP[i + 2*T] + GP[i + 3*T]);
}

__device__ __forceinline__ double blkSum16(double v, double* tmp, int t, int nw) {
  #pragma unroll
  for (int m = 1; m <= 32; m <<= 1) v += __shfl_xor(v, m);
  __syncthreads();
  if ((t & 63) == 0) tmp[t >> 6] = v;
  __syncthreads();
  double s = 0.0;
  for (int w = 0; w < nw; ++w) s += tmp[w];
  return s;
}

// ================= blocked tridiagonalization: dlatrd-style panel (nb=32) =================
__global__ __launch_bounds__(1024) void k_panel(int p, double* __restrict__ A,
        double* __restrict__ d_g, double* __restrict__ e_g, double* __restrict__ tau_g,
        double* __restrict__ Vg, double* __restrict__ Wg) {
  int b = blockIdx.x, t = threadIdx.x;
  int g = t >> 8, c = t & 255;
  double* Ab = A + (size_t)b*65536;
  __shared__ double V[256][33], W[256][33];
  __shared__ double vL[256], wL[256], rowCur[256];
  __shared__ double wpart[4][256];
  __shared__ double c12[64];
  __shared__ double tmp[16];
  int jmax = (p == 7) ? 31 : 32;
  for (int j = 0; j < jmax; ++j) {
    int i = p*PNB + j;
    if (g == 0) {
      double rv = 0.0;
      if (c >= i) {
        rv = Ab[(size_t)i*256 + c];
        for (int k = 0; k < j; ++k)
          rv -= V[i][k]*W[c][k] + W[i][k]*V[c][k];
      }
      rowCur[c] = rv;
    }
    __syncthreads();
    double part = 0.0;
    int rx = i + 2 + t;
    if (rx < 256) { double v = rowCur[rx]; part = v*v; }
    double xn2 = blkSum16(part, tmp, t, 16);
    double alpha = rowCur[i + 1];
    double beta, tauv, scale;
    if (xn2 == 0.0) { beta = alpha; tauv = 0.0; scale = 0.0; }
    else {
      beta  = -copysign(sqrt(alpha*alpha + xn2), alpha);
      tauv  = (beta - alpha)/beta;
      scale = 1.0/(alpha - beta);
    }
    if (t == 0) { e_g[b*256 + i] = beta; tau_g[b*256 + i] = tauv; d_g[b*256 + i] = rowCur[i]; }
    if (g == 0) {
      double v = 0.0;
      if (c == i + 1) v = 1.0;
      else if (c >= i + 2) v = rowCur[c]*scale;
      vL[c] = v;
      V[c][j] = v;
      if (c >= i + 1) Ab[(size_t)i*256 + c] = v;
    }
    __syncthreads();
    {
      double s = 0.0;
      if (c >= i + 1) {
        for (int r = i + 1 + g; r < 256; r += 4) s += Ab[(size_t)r*256 + c]*vL[r];
      }
      wpart[g][c] = s;
    }
    {
      int kk = t >> 5, lane = t & 31;
      if (kk < j) {
        double s = 0.0;
        for (int ci2 = lane; ci2 < 256; ci2 += 32) s += W[ci2][kk]*vL[ci2];
        s += __shfl_xor(s, 1); s += __shfl_xor(s, 2); s += __shfl_xor(s, 4);
        s += __shfl_xor(s, 8); s += __shfl_xor(s, 16);
        if (lane == 0) c12[kk] = s;
        double s2 = 0.0;
        for (int ci2 = lane; ci2 < 256; ci2 += 32) s2 += V[ci2][kk]*vL[ci2];
        s2 += __shfl_xor(s2, 1); s2 += __shfl_xor(s2, 2); s2 += __shfl_xor(s2, 4);
        s2 += __shfl_xor(s2, 8); s2 += __shfl_xor(s2, 16);
        if (lane == 0) c12[32 + kk] = s2;
      }
    }
    __syncthreads();
    double wfull = 0.0, part2 = 0.0;
    if (g == 0 && c >= i + 1) {
      double wr = wpart[0][c] + wpart[1][c] + wpart[2][c] + wpart[3][c];
      for (int k = 0; k < j; ++k) wr -= V[c][k]*c12[k] + W[c][k]*c12[32 + k];
      wfull = tauv*wr;
      part2 = vL[c]*wfull;
    }
    double dot = blkSum16(part2, tmp, t, 16);
    double coef = -0.5*tauv*dot;
    if (g == 0) {
      double wv2 = (c >= i + 1) ? (wfull + coef*vL[c]) : 0.0;
      wL[c] = wv2;
      W[c][j] = wv2;
    }
    __syncthreads();
  }
  if (p < 7) {
    for (int idx = t; idx < 256*32; idx += 1024) {
      int cc = idx >> 5, kk = idx & 31;
      Vg[((size_t)b*256 + cc)*32 + kk] = V[cc][kk];
      Wg[((size_t)b*256 + cc)*32 + kk] = W[cc][kk];
    }
  } else {
    if (t == 0) {
      double dv = Ab[(size_t)255*256 + 255];
      for (int k = 0; k < 31; ++k) dv -= 2.0*V[255][k]*W[255][k];
      d_g[b*256 + 255] = dv;
      e_g[b*256 + 255] = 0.0;
    }
  }
}

// ================= trailing update: A -= V W^T + W V^T =================
__global__ __launch_bounds__(256) void k_syr2k(int p, const double* __restrict__ Vg,
        const double* __restrict__ Wg, double* __restrict__ A) {
  int rt = blockIdx.x, ct = blockIdx.y, b = blockIdx.z;
  int base = (p + 1)*32;
  int r0 = base + rt*32, c0 = base + ct*32;
  int t = threadIdx.x;
  __shared__ double Vr[32][33], Wr[32][33], Vc[32][33], Wc[32][33];
  for (int idx = t; idx < 1024; idx += 256) {
    int rr = idx >> 5, kk = idx & 31;
    Vr[rr][kk] = Vg[((size_t)b*256 + r0 + rr)*32 + kk];
    Wr[rr][kk] = Wg[((size_t)b*256 + r0 + rr)*32 + kk];
    Vc[rr][kk] = Vg[((size_t)b*256 + c0 + rr)*32 + kk];
    Wc[rr][kk] = Wg[((size_t)b*256 + c0 + rr)*32 + kk];
  }
  __syncthreads();
  int cl = t & 31, rg = t >> 5;
  double* Ab = A + (size_t)b*65536;
  #pragma unroll
  for (int q = 0; q < 4; ++q) {
    int rl = rg + 8*q;
    double acc = Ab[(size_t)(r0 + rl)*256 + c0 + cl];
    #pragma unroll
    for (int k = 0; k < 32; ++k)
      acc -= Vr[rl][k]*Wc[cl][k] + Wr[rl][k]*Vc[cl][k];
    Ab[(size_t)(r0 + rl)*256 + c0 + cl] = acc;
  }
}

// ================= LAPACK helpers =================
__device__ __forceinline__ void dlartg_(double f, double g, double& c, double& s, double& r) {
  if (g == 0.0) { c = 1.0; s = 0.0; r = f; }
  else if (f == 0.0) { c = 0.0; s = (g > 0.0) ? 1.0 : -1.0; r = fabs(g); }
  else {
    double d = sqrt(f*f + g*g);
    r = (f >= 0.0) ? d : -d;
    c = f / r;
    s = g / r;
  }
}

__device__ void dlaev2_(double a, double b, double cc, double& rt1, double& rt2, double& cs1, double& sn1) {
  double sm = a + cc, df = a - cc;
  double adf = fabs(df), tb = b + b, ab = fabs(tb);
  double acmx, acmn;
  if (fabs(a) > fabs(cc)) { acmx = a; acmn = cc; } else { acmx = cc; acmn = a; }
  double rt;
  if (adf > ab)      rt = adf*sqrt(1.0 + (ab/adf)*(ab/adf));
  else if (adf < ab) rt = ab*sqrt(1.0 + (adf/ab)*(adf/ab));
  else               rt = ab*sqrt(2.0);
  int sgn1;
  if (sm < 0.0)      { rt1 = 0.5*(sm - rt); sgn1 = -1; rt2 = (acmx/rt1)*acmn - (b/rt1)*b; }
  else if (sm > 0.0) { rt1 = 0.5*(sm + rt); sgn1 = 1;  rt2 = (acmx/rt1)*acmn - (b/rt1)*b; }
  else               { rt1 = 0.5*rt; rt2 = -0.5*rt; sgn1 = 1; }
  double cs; int sgn2;
  if (df >= 0.0) { cs = df + rt; sgn2 = 1; } else { cs = df - rt; sgn2 = -1; }
  double acs = fabs(cs);
  if (acs > ab) {
    double ct = -tb/cs;
    sn1 = 1.0/sqrt(1.0 + ct*ct);
    cs1 = ct*sn1;
  } else {
    if (ab == 0.0) { cs1 = 1.0; sn1 = 0.0; }
    else {
      double tn = -cs/tb;
      cs1 = 1.0/sqrt(1.0 + tn*tn);
      sn1 = tn*cs1;
    }
  }
  if (sgn1 == sgn2) { double tn = cs1; cs1 = -sn1; sn1 = tn; }
}

// ===== wave-parallel faithful dsteqr('I'), n=16: all 64 lanes run the scalar control flow
// redundantly (wave-uniform, lockstep); d/e/cs/sn are lane-distributed registers accessed
// via __shfl (lane j owns element j); Q rotations are row-parallel (lane k owns row k in LDS).
// Arithmetic sequence identical to the serial version -> bit-identical results.
#define D_(i)        __shfl(dv, (i))
#define E_(i)        __shfl(ev, (i))
#define CS_(i)       __shfl(csr, (i))
#define SN_(i)       __shfl(snr, (i))
#define SETD_(i,val) do { double _t = (val); if (lane == (i)) dv = _t; } while(0)
#define SETE_(i,val) do { double _t = (val); if (lane == (i)) ev = _t; } while(0)
#define SETCS_(i,val) do { double _t = (val); if (lane == (i)) csr = _t; } while(0)
#define SETSN_(i,val) do { double _t = (val); if (lane == (i)) snr = _t; } while(0)
__device__ void steqr_wave(double* __restrict__ dsrc, double* __restrict__ esrc,
                           double* __restrict__ q, int ldq, int lane) {
  const int n = 16;
  const double eps = EPS32, eps2 = EPS232, safmin = SAFMIN32;
  double dv = dsrc[lane & 15];
  double ev = ((lane & 15) < 15) ? esrc[lane & 15] : 0.0;
  double csr = 0.0, snr = 0.0;
  if (lane < n) {
    for (int j = 0; j < n; ++j) q[lane*ldq + j] = (lane == j) ? 1.0 : 0.0;
  }
  int nmaxit = n*30, jtot = 0;
  int l1 = 0;
  while (l1 < n) {
    if (l1 > 0) SETE_(l1-1, 0.0);
    int m;
    for (m = l1; m < n-1; ++m) {
      double tst = fabs(E_(m));
      if (tst == 0.0) break;
      if (tst <= (sqrt(fabs(D_(m)))*sqrt(fabs(D_(m+1))))*eps) { SETE_(m, 0.0); break; }
    }
    int l = l1, lend = m;
    l1 = m + 1;
    if (lend == l) continue;
    if (fabs(D_(lend)) < fabs(D_(l))) { int tsw = l; l = lend; lend = tsw; }
    if (lend > l) {
      // QL
      while (true) {
        int mm;
        for (mm = l; mm < lend; ++mm) {
          double tst = E_(mm)*E_(mm);
          if (tst <= (eps2*fabs(D_(mm)))*fabs(D_(mm+1)) + safmin) break;
        }
        if (mm < lend) SETE_(mm, 0.0);
        double p = D_(l);
        if (mm == l) { l = l + 1; if (l > lend) break; continue; }
        if (mm == l+1) {
          double rt1, rt2, c, s;
          dlaev2_(D_(l), E_(l), D_(l+1), rt1, rt2, c, s);
          if (lane < n) {
            double t1 = q[lane*ldq + l+1], t0 = q[lane*ldq + l];
            q[lane*ldq + l+1] = c*t1 - s*t0;
            q[lane*ldq + l]   = s*t1 + c*t0;
          }
          SETD_(l, rt1); SETD_(l+1, rt2); SETE_(l, 0.0);
          l += 2; if (l > lend) break; continue;
        }
        if (jtot == nmaxit) break;
        jtot++;
        double g = (D_(l+1) - p)/(2.0*E_(l));
        double r = sqrt(g*g + 1.0);
        g = D_(mm) - p + E_(l)/(g + copysign(r, g));
        double s = 1.0, c = 1.0; p = 0.0;
        for (int i = mm-1; i >= l; --i) {
          double f = s*E_(i), bb = c*E_(i);
          dlartg_(g, f, c, s, r);
          if (i != mm-1) SETE_(i+1, r);
          g = D_(i+1) - p;
          r = (D_(i) - g)*s + 2.0*c*bb;
          p = s*r;
          SETD_(i+1, g + p);
          g = c*r - bb;
          SETCS_(i, c); SETSN_(i, -s);
        }
        for (int i = mm-1; i >= l; --i) {
          double cc2 = CS_(i), ss2 = SN_(i);
          if (lane < n) {
            double t1 = q[lane*ldq + i+1], t0 = q[lane*ldq + i];
            q[lane*ldq + i+1] = cc2*t1 - ss2*t0;
            q[lane*ldq + i]   = ss2*t1 + cc2*t0;
          }
        }
        SETD_(l, D_(l) - p); SETE_(l, g);
      }
    } else {
      // QR
      while (true) {
        int mm;
        for (mm = l; mm > lend; --mm) {
          double tst = E_(mm-1)*E_(mm-1);
          if (tst <= (eps2*fabs(D_(mm)))*fabs(D_(mm-1)) + safmin) break;
        }
        if (mm > lend) SETE_(mm-1, 0.0);
        double p = D_(l);
        if (mm == l) { l = l - 1; if (l < lend) break; continue; }
        if (mm == l-1) {
          double rt1, rt2, c, s;
          dlaev2_(D_(l-1), E_(l-1), D_(l), rt1, rt2, c, s);
          if (lane < n) {
            double t1 = q[lane*ldq + l], t0 = q[lane*ldq + l-1];
            q[lane*ldq + l]   = c*t1 - s*t0;
            q[lane*ldq + l-1] = s*t1 + c*t0;
          }
          SETD_(l-1, rt1); SETD_(l, rt2); SETE_(l-1, 0.0);
          l -= 2; if (l < lend) break; continue;
        }
        if (jtot == nmaxit) break;
        jtot++;
        double g = (D_(l-1) - p)/(2.0*E_(l-1));
        double r = sqrt(g*g + 1.0);
        g = D_(mm) - p + E_(l-1)/(g + copysign(r, g));
        double s = 1.0, c = 1.0; p = 0.0;
        for (int i = mm; i <= l-1; ++i) {
          double f = s*E_(i), bb = c*E_(i);
          dlartg_(g, f, c, s, r);
          if (i != mm) SETE_(i-1, r);
          g = D_(i) - p;
          r = (D_(i+1) - g)*s + 2.0*c*bb;
          p = s*r;
          SETD_(i, g + p);
          g = c*r - bb;
          SETCS_(i, c); SETSN_(i, s);
        }
        for (int i = mm; i <= l-1; ++i) {
          double cc2 = CS_(i), ss2 = SN_(i);
          if (lane < n) {
            double t1 = q[lane*ldq + i+1], t0 = q[lane*ldq + i];
            q[lane*ldq + i+1] = cc2*t1 - ss2*t0;
            q[lane*ldq + i]   = ss2*t1 + cc2*t0;
          }
        }
        SETD_(l, D_(l) - p); SETE_(l-1, g);
      }
    }
  }
  // dsteqr 'I' final: selection sort ascending, swap columns
  for (int ii = 1; ii < n; ++ii) {
    int k = ii - 1; double p = D_(k);
    for (int j = ii; j < n; ++j) { double dj2 = D_(j); if (dj2 < p) { k = j; p = dj2; } }
    if (k != ii-1) {
      SETD_(k, D_(ii-1)); SETD_(ii-1, p);
      if (lane < n) {
        double tq = q[lane*ldq + ii-1];
        q[lane*ldq + ii-1] = q[lane*ldq + k];
        q[lane*ldq + k] = tq;
      }
    }
  }
  if (lane < 16) dsrc[lane] = dv;
}

__global__ __launch_bounds__(256) void k_zeroq(double* __restrict__ QT) {
  size_t i = (size_t)blockIdx.x*256 + threadIdx.x;
  size_t total = (size_t)NB*65536;
  for (; i < total; i += (size_t)gridDim.x*256) QT[i] = 0.0;
}

// ================= leaves: one wave-parallel ssteqr(16) per WAVE =================
__global__ __launch_bounds__(1024) void k_leaves(const double* __restrict__ d_g, const double* __restrict__ e_g,
        double* __restrict__ QT, double* __restrict__ DW) {
  int b = blockIdx.x, t = threadIdx.x;
  __shared__ double dL[256], eL[256];
  __shared__ double ql[16*272];      // 16 leaves x [16][17]
  if (t < 256) { dL[t] = d_g[b*256 + t]; eL[t] = e_g[b*256 + t]; }
  __syncthreads();
  if (t == 0) {
    for (int cut = 16; cut < 256; cut += 16) {   // dlaed0 tears
      double a = fabs(eL[cut-1]);
      dL[cut-1] -= a; dL[cut] -= a;
    }
  }
  __syncthreads();
  int w = t >> 6, lane = t & 63;
  steqr_wave(dL + 16*w, eL + 16*w, &ql[w*272], 17, lane);
  __syncthreads();
  for (int idx = t; idx < 4096; idx += 1024) {
    int lf = idx >> 8, i = (idx >> 4) & 15, j = idx & 15;
    QT[(size_t)b*65536 + (size_t)(lf*16 + j)*256 + lf*16 + i] = ql[lf*272 + i*17 + j];
  }
  if (t < 256) DW[b*256 + t] = dL[t];
}

// ================= merge phase 1: scan + rotations + secular + S =================
__global__ __launch_bounds__(256) void k_mscan(int n1, const double* __restrict__ e_g,
        double* __restrict__ QT, double* __restrict__ DW, double* __restrict__ SG, int* __restrict__ META) {
  int mrg = blockIdx.x, b = blockIdx.y, t = threadIdx.x;
  int nn = 2*n1, r0 = mrg*nn;
  double* Q = QT + (size_t)b*65536;
  double* Sg = SG + (size_t)b*65536;
  int* meta = META + ((b*8 + mrg)*520);
  __shared__ double dloc[256], zloc[256], dlam[256], wv[256], w2[256], tauv[256], zh[256], dfin[256];
  __shared__ int indx[256], indxp[256], permf[256];
  __shared__ double rotc[256], rots[256];
  __shared__ short rotp[256], rotq[256];
  __shared__ int KK[3];
  __shared__ double sc[2];
  double rho_raw = e_g[b*256 + r0 + n1 - 1];
  if (t < nn) {
    dloc[t] = DW[b*256 + r0 + t];
    double zv = Q[(size_t)(r0 + t)*256 + r0 + ((t < n1) ? (n1 - 1) : n1)];
    if (t >= n1 && rho_raw < 0.0) zv = -zv;
    zloc[t] = zv * 0.70710678118654752440;
  }
  __syncthreads();
  if (t == 0) {
    int i = 0, jj = n1, pos = 0;
    while (i < n1 && jj < nn) { if (dloc[i] <= dloc[jj]) indx[pos++] = i++; else indx[pos++] = jj++; }
    while (i < n1) indx[pos++] = i++;
    while (jj < nn) indx[pos++] = jj++;
    double maxd = 0.0, maxz = 0.0;
    for (int q2 = 0; q2 < nn; ++q2) { maxd = fmax(maxd, fabs(dloc[q2])); maxz = fmax(maxz, fabs(zloc[q2])); }
    double rho = fabs(2.0*rho_raw);
    double tol = 8.0*EPS32*fmax(maxd, maxz);
    int K = 0, K2 = nn, nrot = 0, pj = -1, j = 0;
    for (; j < nn; ++j) {
      int nj = indx[j];
      if (rho*fabs(zloc[nj]) <= tol) { K2--; indxp[K2] = nj; }
      else { pj = nj; break; }
    }
    if (pj >= 0) {
      for (++j; j < nn; ++j) {
        int nj = indx[j];
        if (rho*fabs(zloc[nj]) <= tol) { K2--; indxp[K2] = nj; }
        else {
          double s = zloc[pj], c = zloc[nj];
          double tau = sqrt(c*c + s*s);
          double tdf = dloc[nj] - dloc[pj];
          c /= tau; s = -s/tau;
          if (fabs(tdf*c*s) <= tol) {
            zloc[nj] = tau; zloc[pj] = 0.0;
            rotp[nrot] = (short)pj; rotq[nrot] = (short)nj; rotc[nrot] = c; rots[nrot] = s; nrot++;
            double tt2 = dloc[pj]*c*c + dloc[nj]*s*s;
            dloc[nj] = dloc[pj]*s*s + dloc[nj]*c*c;
            dloc[pj] = tt2;
            K2--;
            int ii2 = 1;
            while (K2 + ii2 <= nn - 1 && dloc[pj] < dloc[indxp[K2 + ii2]]) { indxp[K2+ii2-1] = indxp[K2+ii2]; ii2++; }
            indxp[K2+ii2-1] = pj;
            pj = nj;
          } else {
            dlam[K] = dloc[pj]; wv[K] = zloc[pj]; indxp[K] = pj; K++;
            pj = nj;
          }
        }
      }
      dlam[K] = dloc[pj]; wv[K] = zloc[pj]; indxp[K] = pj; K++;
    }
    double sumw2 = 0.0;
    for (int q2 = 0; q2 < K; ++q2) sumw2 += wv[q2]*wv[q2];
    KK[0] = K; KK[1] = K2; KK[2] = nrot; sc[0] = rho; sc[1] = sumw2;
  }
  __syncthreads();
  int K = KK[0], K2 = KK[1], nrot = KK[2];
  double rho = sc[0], sumw2 = sc[1];
  if (t < nn) {
    for (int k = 0; k < nrot; ++k) {
      int p = rotp[k], q = rotq[k];
      double c = rotc[k], s = rots[k];
      size_t ip = (size_t)(r0 + p)*256 + r0 + t;
      size_t iq = (size_t)(r0 + q)*256 + r0 + t;
      double xq = Q[ip], yq = Q[iq];
      Q[ip] = c*xq + s*yq;
      Q[iq] = c*yq - s*xq;
    }
  }
  if (t < K) w2[t] = rho*wv[t]*wv[t];
  __syncthreads();
  if (t < K) {
    double dj = dlam[t];
    double hi0 = (t < K-1) ? (dlam[t+1] - dj) : rho*sumw2;
    double lo = 0.0, hi = hi0;
    for (int it = 0; it < 64; ++it) {
      double mid = 0.5*(lo + hi);
      double f = 1.0;
      for (int j2 = 0; j2 < K; ++j2) f += w2[j2]/((dlam[j2] - dj) - mid);
      if (f < 0.0) lo = mid; else hi = mid;
    }
    double tl = 0.5*(lo + hi);
    if (tl <= 0.0) tl = hi0*1e-300;
    tauv[t] = tl;
  }
  __syncthreads();
  if (t < K) {
    double dt2 = dlam[t], p = tauv[t];
    for (int i = 0; i < K; ++i) { if (i == t) continue; double del = dlam[i] - dt2; p *= (del + tauv[i])/del; }
    zh[t] = copysign(sqrt(fabs(p)), wv[t]);
  }
  __syncthreads();
  if (t < K) {
    double dj = dlam[t], tj = tauv[t];
    double nrm = 0.0;
    for (int i = 0; i < K; ++i) { double sij = zh[i]/((dlam[i] - dj) - tj); nrm += sij*sij; }
    double inv = 1.0/sqrt(nrm);
    for (int i = 0; i < K; ++i) Sg[(size_t)(r0 + i)*256 + t] = (zh[i]/((dlam[i] - dj) - tj))*inv;
  }
  __syncthreads();
  if (t == 0) {
    int i = 0, p = nn - 1, f = 0;
    while (f < nn) {
      bool takesec;
      if (i < K && p >= K2) takesec = ((dlam[i] + tauv[i]) <= dloc[indxp[p]]);
      else takesec = (i < K);
      if (takesec) { dfin[f] = dlam[i] + tauv[i]; permf[f] = i; i++; }
      else         { dfin[f] = dloc[indxp[p]];    permf[f] = K + (p - K2); p--; }
      f++;
    }
    for (f = 0; f < nn; ++f) DW[b*256 + r0 + f] = dfin[f];
    meta[0] = K; meta[1] = K2;
  }
  __syncthreads();
  if (t < nn) { meta[2 + t] = indxp[t]; meta[258 + t] = permf[t]; }
}

// ================= merge phase 2 =================
__global__ __launch_bounds__(256) void k_mgemm(int n1, int nmrg, const double* __restrict__ QT,
        const double* __restrict__ SG, const int* __restrict__ META, double* __restrict__ QNT) {
  int nn = 2*n1;
  int jt = blockIdx.x, rt = blockIdx.y;
  int z = blockIdx.z;
  int mrg = z % nmrg, b = z / nmrg;
  int r0 = mrg*nn;
  int t = threadIdx.x;
  const int* meta = META + ((b*8 + mrg)*520);
  __shared__ int sindxp[256];
  __shared__ double Gs[32][66];
  __shared__ double Ss[32][33];
  const double* Q = QT + (size_t)b*65536;
  const double* Sg = SG + (size_t)b*65536;
  double* Qn = QNT + (size_t)b*65536;
  int K = meta[0], K2 = meta[1];
  if (t < nn) sindxp[t] = meta[2 + t];
  __syncthreads();
  int jl = t >> 6, rl = t & 63;
  int r = rt*64 + rl;
  double acc[8];
  #pragma unroll
  for (int q = 0; q < 8; ++q) acc[q] = 0.0;
  if (jt*32 < K) {
    for (int i0 = 0; i0 < K; i0 += 32) {
      #pragma unroll
      for (int w = 0; w < 8; ++w) {
        int idx = t + 256*w;
        int ii = idx >> 6, rr = idx & 63;
        double v = 0.0;
        if (i0 + ii < K && rt*64 + rr < nn)
          v = Q[(size_t)(r0 + sindxp[i0 + ii])*256 + r0 + rt*64 + rr];
        Gs[ii][rr] = v;
      }
      #pragma unroll
      for (int w = 0; w < 4; ++w) {
        int idx = t + 256*w;
        int ii2 = idx >> 5, jj = idx & 31;
        double v = 0.0;
        if (i0 + ii2 < K)
          v = Sg[(size_t)(r0 + i0 + ii2)*256 + jt*32 + jj];
        Ss[ii2][jj] = v;
      }
      __syncthreads();
      int kmax = (K - i0 < 32) ? (K - i0) : 32;
      for (int ii = 0; ii < kmax; ++ii) {
        double gv = Gs[ii][rl];
        #pragma unroll
        for (int q = 0; q < 8; ++q) acc[q] += Ss[ii][jl + 4*q] * gv;
      }
      __syncthreads();
    }
  }
  if (r < nn) {
    #pragma unroll
    for (int q = 0; q < 8; ++q) {
      int j = jt*32 + jl + 4*q;
      if (j < K) Qn[(size_t)(r0 + j)*256 + r0 + r] = acc[q];
      else if (j < nn) {
        int p = K2 + (j - K);
        Qn[(size_t)(r0 + j)*256 + r0 + r] = Q[(size_t)(r0 + sindxp[p])*256 + r0 + r];
      }
    }
  }
}

// ================= merge phase 3 =================
__global__ __launch_bounds__(256) void k_mperm(int n1, const double* __restrict__ QNT,
        const int* __restrict__ META, double* __restrict__ QT) {
  int mrg = blockIdx.x, b = blockIdx.y, t = threadIdx.x;
  int nn = 2*n1, r0 = mrg*nn;
  const int* meta = META + ((b*8 + mrg)*520);
  __shared__ int pf[256];
  if (t < nn) pf[t] = meta[258 + t];
  __syncthreads();
  if (t < nn) {
    for (int f = 0; f < nn; ++f)
      QT[(size_t)b*65536 + (size_t)(r0 + f)*256 + r0 + t] =
        QNT[(size_t)b*65536 + (size_t)(r0 + pf[f])*256 + r0 + t];
  }
}

// ================= back-transform, LDS-tiled: emit Vt (f32) directly =================
__global__ __launch_bounds__(256) void k_backxf(const double* __restrict__ A, const double* __restrict__ tau_g,
        const double* __restrict__ QT, float* __restrict__ Vt) {
  int g = blockIdx.x, b = blockIdx.y;
  int t = threadIdx.x;
  int e = t >> 4, l = t & 15;
  __shared__ double zt[16][264];
  __shared__ double vL[256];
  __shared__ double tauL[256];
  const double* Ab = A + (size_t)b*65536;
  const double* Qb = QT + (size_t)b*65536 + (size_t)g*16*256;
  #pragma unroll
  for (int w = 0; w < 16; ++w) {
    int idx = t + 256*w;
    int ee = idx >> 8, rr = idx & 255;
    zt[ee][rr] = Qb[(size_t)ee*256 + rr];
  }
  tauL[t] = tau_g[b*256 + t];
  __syncthreads();
  for (int s = 253; s >= 0; --s) {
    if (t == 0) vL[s+1] = 1.0;
    int rx = s + 2 + t;
    if (rx < 256) vL[rx] = Ab[s*256 + rx];
    __syncthreads();
    double tauv = tauL[s];
    if (tauv != 0.0) {
      double acc = 0.0;
      for (int rr = s + 1 + l; rr < 256; rr += 16) acc += vL[rr]*zt[e][rr];
      acc += __shfl_xor(acc, 1);
      acc += __shfl_xor(acc, 2);
      acc += __shfl_xor(acc, 4);
      acc += __shfl_xor(acc, 8);
      double tw = tauv*acc;
      for (int rr = s + 1 + l; rr < 256; rr += 16) zt[e][rr] -= tw*vL[rr];
    }
    __syncthreads();
  }
  float* vtb = Vt + ((size_t)b*256 + (size_t)g*16)*256;
  #pragma unroll
  for (int w = 0; w < 16; ++w) {
    int idx = t + 256*w;
    int ee = idx >> 8, rr = idx & 255;
    vtb[(size_t)ee*256 + rr] = (float)zt[ee][rr];
  }
}

// ================= x_proj = V x, + x, fused maxpool + noise output =================
__global__ __launch_bounds__(256) void k_xproj(const float* __restrict__ x, const float* __restrict__ Vt,
        float* __restrict__ xp, float* __restrict__ noise_out) {
  int R = blockIdx.x, ct = blockIdx.y, b = blockIdx.z;
  int t = threadIdx.x;
  int cl = t >> 3, l8 = t & 7;
  __shared__ float vsh[32][20];
  __shared__ float xs[16][520];
  const float* xb = x + (size_t)b*256*NPX;
  int s0 = R*512;
  float acc[64];
  #pragma unroll
  for (int p = 0; p < 64; ++p) acc[p] = 0.0f;
  for (int d0 = 0; d0 < 256; d0 += 16) {
    for (int q = t; q < 512; q += 256) {
      int c = q >> 4, dd = q & 15;
      vsh[c][dd] = Vt[((size_t)b*256 + ct*32 + c)*256 + d0 + dd];
    }
    for (int q = t; q < 8192; q += 256) {
      int dd = q >> 9, px = q & 511;
      xs[dd][px] = xb[(size_t)(d0 + dd)*NPX + s0 + px];
    }
    __syncthreads();
    for (int dd = 0; dd < 16; ++dd) {
      float a = vsh[cl][dd];
      const float* xr = &xs[dd][l8];
      #pragma unroll
      for (int p = 0; p < 64; ++p) acc[p] += a*xr[8*p];
    }
    __syncthreads();
  }
  int cg = ct*32 + cl;
  const float* xc = xb + (size_t)cg*NPX + s0;
  float vmax[16];
  #pragma unroll
  for (int j = 0; j < 16; ++j) vmax[j] = -3.0e38f;
  bool isnz = (ct == 0);
  #pragma unroll
  for (int p = 0; p < 64; ++p) {
    int px = l8 + 8*p;
    float val = acc[p] + xc[px];
    vmax[p & 15] = fmaxf(vmax[p & 15], val);
    if (isnz) noise_out[((size_t)b*32 + cl)*NPX + s0 + px] = val;
  }
  #pragma unroll
  for (int j = 0; j < 16; ++j) {
    float v = vmax[j];
    v = fmaxf(v, __shfl_xor(v, 1));
    v = fmaxf(v, __shfl_xor(v, 2));
    vmax[j] = v;
  }
  if ((l8 & 3) == 0) {
    int halfsel = l8 >> 2;
    #pragma unroll
    for (int j = 0; j < 16; ++j)
      xp[((size_t)b*256 + cg)*PPX + R*32 + 2*j + halfsel] = vmax[j];
  }
}

// ================= qkv 1x1 conv (672 needed rows) =================
__global__ __launch_bounds__(256) void k_qkv(const float* __restrict__ xp, const float* __restrict__ wq,
        const float* __restrict__ bq, float* __restrict__ qkvm) {
  int pt = blockIdx.x, ot = blockIdx.y, b = blockIdx.z;
  int t = threadIdx.x;
  int ol = t & 31, pg = t >> 5;
  __shared__ float wsh[32][9];
  __shared__ float xsh[8][260];
  float acc[32];
  #pragma unroll
  for (int j = 0; j < 32; ++j) acc[j] = 0.0f;
  for (int ic0 = 0; ic0 < 256; ic0 += 8) {
    {
      int o = t >> 3, j = t & 7;
      int orow = ot*32 + o;
      int reg = orow/224, rem = orow - reg*224;
      int wrow = 32 + rem + 256*reg;
      wsh[o][j] = wq[(size_t)wrow*256 + ic0 + j];
    }
    for (int q = t; q < 2048; q += 256) {
      int ic = q >> 8, px = q & 255;
      xsh[ic][px] = xp[((size_t)b*256 + ic0 + ic)*PPX + pt*256 + px];
    }
    __syncthreads();
    for (int ic = 0; ic < 8; ++ic) {
      float a = wsh[ol][ic];
      const float* xr = &xsh[ic][pg];
      #pragma unroll
      for (int j = 0; j < 32; ++j) acc[j] += a*xr[8*j];
    }
    __syncthreads();
  }
  int orow = ot*32 + ol;
  int reg = orow/224, rem = orow - reg*224;
  float bv = bq[32 + rem + 256*reg];
  #pragma unroll
  for (int j = 0; j < 32; ++j)
    qkvm[((size_t)b*672 + orow)*PPX + pt*256 + pg + 8*j] = acc[j] + bv;
}

// ================= attention =================
__global__ __launch_bounds__(256) void k_attn(const float* __restrict__ qkvm, const float* __restrict__ emb,
        const float* __restrict__ xp, float* __restrict__ pool) {
  int rt = blockIdx.x, n = blockIdx.y, b = blockIdx.z;
  int t = threadIdx.x;
  int rl = t >> 5, pg = t & 31;
  __shared__ float S[8][1032];
  __shared__ float qsh[8][33];
  __shared__ float kv[4224];
  const float* qb = qkvm + (size_t)b*672*PPX;
  int rg0 = rt*8;
  {
    int rg = rg0 + rl;
    float qv = qb[(size_t)(32*n + (rg >> 5))*PPX + ((rg & 31) << 5) + pg];
    float ev = emb[(((size_t)n*8 + b)*1024 + rg)*32 + pg];
    qsh[rl][pg] = (qv + ev)*0.17677669529663688f;
  }
  __syncthreads();
  const float* kb = qb + (size_t)(224 + 32*n)*PPX;
  for (int p0 = 0; p0 < 1024; p0 += 128) {
    for (int q = t; q < 4096; q += 256) {
      int c = q >> 7, pp = q & 127;
      kv[c*132 + pp] = kb[(size_t)c*PPX + p0 + pp];
    }
    __syncthreads();
    float a0 = 0, a1 = 0, a2 = 0, a3 = 0;
    for (int c = 0; c < 32; ++c) {
      float qv = qsh[rl][c];
      const float* kr = &kv[c*132 + pg];
      a0 += qv*kr[0]; a1 += qv*kr[32]; a2 += qv*kr[64]; a3 += qv*kr[96];
    }
    S[rl][p0 + pg]      = a0;
    S[rl][p0 + pg + 32] = a1;
    S[rl][p0 + pg + 64] = a2;
    S[rl][p0 + pg + 96] = a3;
    __syncthreads();
  }
  float mx = -3.0e38f;
  for (int j = 0; j < 32; ++j) mx = fmaxf(mx, S[rl][pg + 32*j]);
  #pragma unroll
  for (int m = 1; m <= 16; m <<= 1) mx = fmaxf(mx, __shfl_xor(mx, m));
  float sum = 0.0f;
  for (int j = 0; j < 32; ++j) {
    float e = expf(S[rl][pg + 32*j] - mx);
    S[rl][pg + 32*j] = e;
    sum += e;
  }
  #pragma unroll
  for (int m = 1; m <= 16; m <<= 1) sum += __shfl_xor(sum, m);
  float inv = 1.0f/sum;
  for (int j = 0; j < 32; ++j) S[rl][pg + 32*j] *= inv;
  __syncthreads();
  const float* vb = qb + (size_t)(448 + 32*n)*PPX;
  float acc = 0.0f;
  for (int p0 = 0; p0 < 1024; p0 += 128) {
    for (int q = t; q < 4096; q += 256) {
      int pp = q >> 5, c = q & 31;
      int p = p0 + pp;
      kv[pp*33 + c] = vb[(size_t)(p >> 5)*PPX + ((p & 31) << 5) + c];
    }
    __syncthreads();
    for (int pp = 0; pp < 128; ++pp) acc += S[rl][p0 + pp]*kv[pp*33 + pg];
    __syncthreads();
  }
  int rg = rg0 + rl;
  int ch = 32*n + (rg >> 5);
  size_t sp = (size_t)((rg & 31) << 5) + pg;
  pool[((size_t)b*224 + ch)*PPX + sp] = acc + xp[((size_t)b*256 + 32 + ch)*PPX + sp];
}

__global__ void k_owt(const float* __restrict__ ow, float* __restrict__ owt) {
  int t = blockIdx.x*256 + threadIdx.x;
  if (t < 256*224) {
    int oc = t/224, ch = t - oc*224;
    owt[(size_t)ch*256 + oc] = ow[t];
  }
}

// ================= bilinear + sim gating + final conv =================
__global__ __launch_bounds__(256) void k_final(const float* __restrict__ pool, const float* __restrict__ noise,
        const float* __restrict__ sim_w, const float* __restrict__ owt, float* __restrict__ out) {
  int tt = blockIdx.x, b = blockIdx.y;
  int t = threadIdx.x;
  int h = tt >> 3, w0 = (tt & 7)*16;
  __shared__ float xa[224][20];
  __shared__ float nsc[224][20];
  __shared__ float nz[32][20];
  __shared__ float scl[16];
  for (int q = t; q < 512; q += 256) {
    int c = q >> 4, px = q & 15;
    nz[c][px] = noise[((size_t)b*32 + c)*NPX + h*128 + w0 + px];
  }
  float hs = h*0.25f - 0.375f;
  float hf = floorf(hs);
  int h0 = (int)hf;
  float fh = hs - hf;
  int h0c = min(max(h0, 0), 31);
  int h1c = min(max(h0 + 1, 0), 31);
  __syncthreads();
  for (int q = t; q < 3584; q += 256) {
    int c = q >> 4, px = q & 15;
    int w = w0 + px;
    float wsrc = w*0.25f - 0.375f;
    float wf = floorf(wsrc);
    int W0 = (int)wf;
    float fw = wsrc - wf;
    int w0c = min(max(W0, 0), 31);
    int w1c = min(max(W0 + 1, 0), 31);
    const float* pb = pool + ((size_t)b*224 + c)*PPX;
    float v00 = pb[h0c*32 + w0c], v01 = pb[h0c*32 + w1c];
    float v10 = pb[h1c*32 + w0c], v11 = pb[h1c*32 + w1c];
    xa[c][px] = (1.0f - fh)*((1.0f - fw)*v00 + fw*v01) + fh*((1.0f - fw)*v10 + fw*v11);
    float np = 0.0f;
    #pragma unroll
    for (int j = 0; j < 32; ++j) np += sim_w[c*32 + j]*nz[j][px];
    nsc[c][px] = np;
  }
  __syncthreads();
  {
    int px = t >> 4, kk = t & 15;
    float s1 = 0, s2 = 0, s3 = 0;
    for (int c = kk; c < 224; c += 16) {
      float a = xa[c][px], p = nsc[c][px];
      s1 += a*a; s2 += p*p; s3 += a*p;
    }
    #pragma unroll
    for (int m = 1; m <= 8; m <<= 1) {
      s1 += __shfl_xor(s1, m);
      s2 += __shfl_xor(s2, m);
      s3 += __shfl_xor(s3, m);
    }
    if (kk == 0) {
      float n1 = fmaxf(sqrtf(s1), 1e-12f);
      float n2 = fmaxf(sqrtf(s2), 1e-12f);
      float sim = (s3/(n1*n2) + 1.0f)*0.5f;
      scl[px] = 1.0f - sim;
    }
  }
  __syncthreads();
  {
    float accp[16];
    #pragma unroll
    for (int px = 0; px < 16; ++px) accp[px] = 0.0f;
    for (int c = 0; c < 224; ++c) {
      float wv = owt[(size_t)c*256 + t];
      #pragma unroll
      for (int px = 0; px < 16; ++px) accp[px] += wv*xa[c][px];
    }
    size_t obase = ((size_t)b*256 + t)*NPX + (size_t)h*128 + w0;
    #pragma unroll
    for (int px = 0; px < 16; ++px) out[obase + px] = accp[px]*scl[px];
  }
  if (b == 0 && tt == 0 && t == 0) out[(size_t)33554432] = 8.0f;   // AVG_K
}

extern "C" void kernel_launch(void* const* d_in, const int* in_sizes, int n_in,
                              void* d_out, int out_size, void* d_ws, size_t ws_size,
                              hipStream_t stream) {
  (void)in_sizes; (void)n_in; (void)out_size; (void)ws_size;
  const float* x     = (const float*)d_in[0];
  const float* qkv_w = (const float*)d_in[1];
  const float* qkv_b = (const float*)d_in[2];
  const float* emb   = (const float*)d_in[3];
  const float* sim_w = (const float*)d_in[4];
  const float* out_w = (const float*)d_in[5];
  float* out = (float*)d_out;
  char* ws = (char*)d_ws;
  double* A    = (double*)(ws + OFF_A);
  double* GP   = (double*)(ws + OFF_GP);
  double* QT   = (double*)(ws + OFF_QT);
  double* SG   = (double*)(ws + OFF_SG);
  double* QNT  = (double*)(ws + OFF_QN);
  double* d_a  = (double*)(ws + OFF_D);
  double* e_a  = (double*)(ws + OFF_E);
  double* tau_a= (double*)(ws + OFF_TAU);
  double* DW   = (double*)(ws + OFF_DW);
  int*    META = (int*)   (ws + OFF_META);
  double* Vg   = (double*)(ws + OFF_VG);
  double* Wg   = (double*)(ws + OFF_WG);
  float*  Vt   = (float*) (ws + OFF_VT);
  float*  xp   = (float*) (ws + OFF_XP);
  float*  qkvm = (float*) (ws + OFF_QKV);
  float*  pool = (float*) (ws + OFF_POOL);
  float*  owt  = (float*) (ws + OFF_OWT);
  float*  noise_out = out + 33554433;

  k_gram <<<dim3(4,4,32), 256, 0, stream>>>(x, GP);
  k_gsum <<<dim3(512),    256, 0, stream>>>(GP, A);
  for (int p = 0; p < 8; ++p) {
    k_panel<<<dim3(8), 1024, 0, stream>>>(p, A, d_a, e_a, tau_a, Vg, Wg);
    if (p < 7) {
      int nt = 256 - 32*(p + 1);
      k_syr2k<<<dim3(nt/32, nt/32, 8), 256, 0, stream>>>(p, Vg, Wg, A);
    }
  }
  k_zeroq  <<<dim3(512),     256,  0, stream>>>(QT);
  k_leaves <<<dim3(8),       1024, 0, stream>>>(d_a, e_a, QT, DW);
  {
    const int n1s[4]   = {16, 32, 64, 128};
    const int nmrgs[4] = {8, 4, 2, 1};
    for (int lv = 0; lv < 4; ++lv) {
      int n1 = n1s[lv], nmrg = nmrgs[lv], nn = 2*n1;
      k_mscan<<<dim3(nmrg, 8), 256, 0, stream>>>(n1, e_a, QT, DW, SG, META);
      k_mgemm<<<dim3(nn/32, (nn + 63)/64, nmrg*8), 256, 0, stream>>>(n1, nmrg, QT, SG, META, QNT);
      k_mperm<<<dim3(nmrg, 8), 256, 0, stream>>>(n1, QNT, META, QT);
    }
  }
  k_backxf <<<dim3(16,8),    256, 0, stream>>>(A, tau_a, QT, Vt);
  k_xproj  <<<dim3(32,8,8),  256, 0, stream>>>(x, Vt, xp, noise_out);
  k_qkv    <<<dim3(4,21,8),  256, 0, stream>>>(xp, qkv_w, qkv_b, qkvm);
  k_attn   <<<dim3(128,7,8), 256, 0, stream>>>(qkvm, emb, xp, pool);
  k_owt    <<<dim3(224),     256, 0, stream>>>(out_w, owt);
  k_final  <<<dim3(1024,8),  256, 0, stream>>>(pool, noise_out, sim_w, owt, out);
}